// Round 5
// baseline (765.871 us; speedup 1.0000x reference)
//
#include <hip/hip_runtime.h>
#include <math.h>

static constexpr int V_   = 32000;
static constexpr int E_   = 512;
static constexpr int H_   = 1024;
static constexpr int B_   = 32;
static constexpr int TS_  = 50;
static constexpr int TP_  = 32;
static constexpr int VTS  = V_ + TS_;     // 32050
static constexpr int H3   = 3 * H_;       // 3072
static constexpr int GIN_ = E_ + 2 * H_;  // 2560
static constexpr int NS   = 8;            // softmax slices
static constexpr int SLE  = (VTS + NS - 1) / NS;  // 4007

// ---------------------------------------------------------------------------
__global__ void zero_buf(float* __restrict__ p, int n)
{
    const int i = blockIdx.x * 256 + threadIdx.x;
    if (i < n) p[i] = 0.f;
}

__global__ void gather_emb(const float* __restrict__ emb,
                           const int* __restrict__ mt,
                           float* __restrict__ gx)
{
    const int i = blockIdx.x * 256 + threadIdx.x;
    if (i >= B_ * E_) return;
    gx[i] = emb[(size_t)mt[i >> 9] * E_ + (i & 511)];
}

// ---------------------------------------------------------------------------
// m32 tile core: po[m*N + n0+tid] = sum_k A[m*lda + k] * W[(n0+tid)*ldw + wko + k]
// One n per thread (256 n/block), 32-m accumulator. A loads are thread-uniform
// -> scalar (SGPR) loads; W staged in LDS [256][33] (conflict-free b32 r/w).
// ---------------------------------------------------------------------------
__device__ __forceinline__ void m32_tile(
    const float* __restrict__ A, int lda,
    const float* __restrict__ W, int ldw, int wko,
    int klen, int n0, float* __restrict__ po, int N)
{
    __shared__ float Ws[256][33];
    const int tid = threadIdx.x;
    float acc[32];
#pragma unroll
    for (int m = 0; m < 32; ++m) acc[m] = 0.f;

    const float* wrow = W + (size_t)(n0 + tid) * ldw + wko;
    for (int kb = 0; kb < klen; kb += 32) {
        float4 w4[8];
#pragma unroll
        for (int q = 0; q < 8; ++q)
            w4[q] = *reinterpret_cast<const float4*>(wrow + kb + 4 * q);
        __syncthreads();
#pragma unroll
        for (int q = 0; q < 8; ++q) {
            Ws[tid][4 * q + 0] = w4[q].x; Ws[tid][4 * q + 1] = w4[q].y;
            Ws[tid][4 * q + 2] = w4[q].z; Ws[tid][4 * q + 3] = w4[q].w;
        }
        __syncthreads();
#pragma unroll 4
        for (int k = 0; k < 32; ++k) {
            const float wv = Ws[tid][k];
#pragma unroll
            for (int m = 0; m < 32; ++m)
                acc[m] = fmaf(A[(size_t)m * lda + kb + k], wv, acc[m]);
        }
    }
#pragma unroll
    for (int m = 0; m < 32; ++m)
        po[(size_t)m * N + n0 + tid] = acc[m];
}

__global__ __launch_bounds__(256)
void gemm_hid(const float* __restrict__ hid,
              const float* __restrict__ Wa, const float* __restrict__ Wp,
              float* __restrict__ parts)
{
    const int z = blockIdx.z, y = blockIdx.y, n0 = blockIdx.x * 256;
    const float* W = z ? Wp : Wa;
    m32_tile(hid + y * 256, H_, W, 2 * H_, y * 256, 256, n0,
             parts + (size_t)(z * 4 + y) * B_ * H_, H_);
}

__global__ void reduce_hid(const float* __restrict__ parts,
                           const float* __restrict__ ba, const float* __restrict__ bp,
                           float* __restrict__ hA, float* __restrict__ hP)
{
    const int i = blockIdx.x * 256 + threadIdx.x;
    if (i >= 2 * B_ * H_) return;
    const int z = i / (B_ * H_);
    const int r = i - z * B_ * H_;
    const int m = r >> 10, j = r & 1023;
    float s = (z ? bp : ba)[j];
#pragma unroll
    for (int ss = 0; ss < 4; ++ss)
        s += parts[((size_t)(z * 4 + ss) * B_ + m) * H_ + j];
    (z ? hP : hA)[r] = s;
}

__global__ __launch_bounds__(256)
void gemm_gru(const float* __restrict__ gx, const float* __restrict__ ctxa,
              const float* __restrict__ ctxp, const float* __restrict__ hid,
              const float* __restrict__ W_ih, const float* __restrict__ W_hh,
              float* __restrict__ parts)
{
    const int y = blockIdx.y, n0 = blockIdx.x * 256;
    const float* A; int lda; const float* W; int ldw; int wko; int klo;
    if (y < 2)       { klo = y * 256;        A = gx;   lda = E_; W = W_ih; ldw = GIN_; wko = klo; }
    else if (y < 6)  { klo = (y - 2) * 256;  A = ctxa; lda = H_; W = W_ih; ldw = GIN_; wko = 512 + klo; }
    else if (y < 10) { klo = (y - 6) * 256;  A = ctxp; lda = H_; W = W_ih; ldw = GIN_; wko = 1536 + klo; }
    else             { klo = (y - 10) * 256; A = hid;  lda = H_; W = W_hh; ldw = H_;   wko = klo; }
    m32_tile(A + klo, lda, W, ldw, wko, 256, n0,
             parts + (size_t)y * B_ * H3, H3);
}

__global__ void reduce_gru(const float* __restrict__ parts,
                           const float* __restrict__ b_ih, const float* __restrict__ b_hh,
                           const float* __restrict__ hid,
                           float* __restrict__ hnew,
                           float* __restrict__ o2, float* __restrict__ o3)
{
    const int i = blockIdx.x * 256 + threadIdx.x;
    if (i >= B_ * H_) return;
    const int b = i >> 10, j = i & 1023;
    float gi[3], gh[3];
#pragma unroll
    for (int c = 0; c < 3; ++c) {
        float s = b_ih[c * H_ + j];
        for (int y = 0; y < 10; ++y)
            s += parts[((size_t)y * B_ + b) * H3 + c * H_ + j];
        gi[c] = s;
        float t = b_hh[c * H_ + j];
        for (int y = 10; y < 14; ++y)
            t += parts[((size_t)y * B_ + b) * H3 + c * H_ + j];
        gh[c] = t;
    }
    const float r = 1.f / (1.f + expf(-(gi[0] + gh[0])));
    const float z = 1.f / (1.f + expf(-(gi[1] + gh[1])));
    const float n = tanhf(gi[2] + r * gh[2]);
    const float o = (1.f - z) * n + z * hid[i];
    hnew[i] = o; o2[i] = o; o3[i] = o;
}

__global__ __launch_bounds__(256)
void gemm_proj(const float* __restrict__ ctxa, const float* __restrict__ ctxp,
               const float* __restrict__ hnew, const float* __restrict__ W_proj,
               float* __restrict__ parts)
{
    const int y = blockIdx.y, n0 = blockIdx.x * 256;
    const int slice = y >> 1, khalf = y & 1;
    const float* A = (slice == 0) ? ctxa : (slice == 1) ? ctxp : hnew;
    m32_tile(A + khalf * 512, H_, W_proj, H3, slice * 1024 + khalf * 512,
             512, n0, parts + (size_t)y * B_ * V_, V_);
}

__global__ void reduce_parts(const float* __restrict__ part,
                             const float* __restrict__ bias,
                             float* __restrict__ out, int N, int S)
{
    const int i = blockIdx.x * 256 + threadIdx.x;
    if (i >= B_ * N) return;
    float s = 0.f;
    for (int ss = 0; ss < S; ++ss) s += part[(size_t)ss * B_ * N + i];
    out[i] = s + bias[i % N];
}

// ---------------------------------------------------------------------------
// gemm_tall8: C = A @ W^T (+bias), 64x128 tile, 8x8 micro, KC=32, 128 threads.
// z selects {EA, EP, UCp}. LDS: As unswizzled (broadcast-clean), Ws gap-
// swizzled col' = n + 4*(n>>5) -> needs 128 + 4*3 = 140 columns (R4 bug:
// declared 136 -> OOB corruption; fixed).
// ---------------------------------------------------------------------------
__global__ __launch_bounds__(128)
void gemm_tall8(const float* __restrict__ slot_enc, const float* __restrict__ pers_enc,
                const float* __restrict__ W_attn_a, const float* __restrict__ W_attn_p,
                const float* __restrict__ W_c2, const float* __restrict__ b_c2,
                float* __restrict__ EA, float* __restrict__ EP, float* __restrict__ UCp)
{
    __shared__ float As[32][68];
    __shared__ float Ws[32][140];
    const int z = blockIdx.z;
    const float* A; const float* W; const float* bias; float* C; int M, ldw;
    if (z == 0)      { A = slot_enc; W = W_attn_a + H_; bias = nullptr; C = EA;  M = TS_ * B_; ldw = 2 * H_; }
    else if (z == 1) { A = pers_enc; W = W_attn_p + H_; bias = nullptr; C = EP;  M = TP_ * B_; ldw = 2 * H_; }
    else             { A = slot_enc; W = W_c2;          bias = b_c2;    C = UCp; M = TS_ * B_; ldw = H_; }
    const int m0 = blockIdx.x * 64;
    if (m0 >= M) return;
    const int n0 = blockIdx.y * 128;
    const int tid = threadIdx.x;
    const int tym = tid >> 4, txn = tid & 15;
    const int sr = tid & 63, sh = tid >> 6;         // A-stage: row, k-half
    const int arow = (m0 + sr < M) ? (m0 + sr) : (M - 1);
    const int wcol = tid + 4 * (tid >> 5);          // swizzled W col (max 139)
    const int wb = 8 * txn + 4 * (txn >> 2);        // swizzled W frag base (max 132)

    float acc[8][8];
#pragma unroll
    for (int i = 0; i < 8; ++i)
#pragma unroll
        for (int j = 0; j < 8; ++j) acc[i][j] = 0.f;

    for (int kb = 0; kb < H_; kb += 32) {
        float4 a4[4], w4[8];
#pragma unroll
        for (int q = 0; q < 4; ++q)
            a4[q] = *reinterpret_cast<const float4*>(A + (size_t)arow * H_ + kb + sh * 16 + 4 * q);
#pragma unroll
        for (int q = 0; q < 8; ++q)
            w4[q] = *reinterpret_cast<const float4*>(W + (size_t)(n0 + tid) * ldw + kb + 4 * q);
        __syncthreads();
#pragma unroll
        for (int q = 0; q < 4; ++q) {
            As[sh * 16 + 4 * q + 0][sr] = a4[q].x; As[sh * 16 + 4 * q + 1][sr] = a4[q].y;
            As[sh * 16 + 4 * q + 2][sr] = a4[q].z; As[sh * 16 + 4 * q + 3][sr] = a4[q].w;
        }
#pragma unroll
        for (int q = 0; q < 8; ++q) {
            Ws[4 * q + 0][wcol] = w4[q].x; Ws[4 * q + 1][wcol] = w4[q].y;
            Ws[4 * q + 2][wcol] = w4[q].z; Ws[4 * q + 3][wcol] = w4[q].w;
        }
        __syncthreads();
#pragma unroll 8
        for (int k = 0; k < 32; ++k) {
            const float4 a0 = *reinterpret_cast<const float4*>(&As[k][8 * tym]);
            const float4 a1 = *reinterpret_cast<const float4*>(&As[k][8 * tym + 4]);
            const float4 w0 = *reinterpret_cast<const float4*>(&Ws[k][wb]);
            const float4 w1 = *reinterpret_cast<const float4*>(&Ws[k][wb + 4]);
            const float av[8] = {a0.x, a0.y, a0.z, a0.w, a1.x, a1.y, a1.z, a1.w};
            const float wv[8] = {w0.x, w0.y, w0.z, w0.w, w1.x, w1.y, w1.z, w1.w};
#pragma unroll
            for (int i = 0; i < 8; ++i)
#pragma unroll
                for (int j = 0; j < 8; ++j)
                    acc[i][j] = fmaf(av[i], wv[j], acc[i][j]);
        }
    }
#pragma unroll
    for (int i = 0; i < 8; ++i) {
        const int row = m0 + 8 * tym + i;
        if (row < M) {
            float4 o0, o1;
            o0.x = acc[i][0]; o0.y = acc[i][1]; o0.z = acc[i][2]; o0.w = acc[i][3];
            o1.x = acc[i][4]; o1.y = acc[i][5]; o1.z = acc[i][6]; o1.w = acc[i][7];
            if (bias) {
                const float4 b0 = *reinterpret_cast<const float4*>(bias + n0 + 8 * txn);
                const float4 b1 = *reinterpret_cast<const float4*>(bias + n0 + 8 * txn + 4);
                o0.x += b0.x; o0.y += b0.y; o0.z += b0.z; o0.w += b0.w;
                o1.x += b1.x; o1.y += b1.y; o1.z += b1.z; o1.w += b1.w;
            }
            *reinterpret_cast<float4*>(C + (size_t)row * H_ + n0 + 8 * txn) = o0;
            *reinterpret_cast<float4*>(C + (size_t)row * H_ + n0 + 8 * txn + 4) = o1;
        }
    }
}

// ---------------------------------------------------------------------------
__global__ __launch_bounds__(512)
void attn_fused(const float* __restrict__ hA, const float* __restrict__ hP,
                const float* __restrict__ EA, const float* __restrict__ EP,
                const float* __restrict__ slot_enc, const float* __restrict__ pers_enc,
                const float* __restrict__ v_a, const float* __restrict__ v_p,
                float* __restrict__ ctxa, float* __restrict__ ctxp)
{
    const int b = blockIdx.x, z = blockIdx.y;
    const int T = z ? TP_ : TS_;
    const float* hX  = z ? hP : hA;
    const float* EX  = z ? EP : EA;
    const float* enc = z ? pers_enc : slot_enc;
    const float* v   = z ? v_p : v_a;
    float* ctx       = z ? ctxp : ctxa;

    const int tid  = threadIdx.x;
    const int wave = tid >> 6;
    const int lane = tid & 63;
    __shared__ float sc[64];
    __shared__ float aw[64];

    const float* ha = hX + (size_t)b * H_;
    for (int t = wave; t < T; t += 8) {
        const float* e = EX + ((size_t)t * B_ + b) * H_;
        float p = 0.f;
        for (int j = lane; j < H_; j += 64)
            p += v[j] * tanhf(ha[j] + e[j]);
#pragma unroll
        for (int off = 32; off > 0; off >>= 1) p += __shfl_down(p, off);
        if (lane == 0) sc[t] = p;
    }
    __syncthreads();
    if (tid < 64) {
        const float x = (tid < T) ? sc[tid] : -3.4e38f;
        float mx = x;
#pragma unroll
        for (int off = 32; off > 0; off >>= 1) mx = fmaxf(mx, __shfl_xor(mx, off));
        const float ex = (tid < T) ? expf(x - mx) : 0.f;
        float sm = ex;
#pragma unroll
        for (int off = 32; off > 0; off >>= 1) sm += __shfl_xor(sm, off);
        aw[tid] = ex / sm;
    }
    __syncthreads();
    for (int k = tid; k < H_; k += 512) {
        float c = 0.f;
        for (int t = 0; t < T; ++t)
            c += aw[t] * enc[((size_t)t * B_ + b) * H_ + k];
        ctx[(size_t)b * H_ + k] = c;
    }
}

// ---------------------------------------------------------------------------
__global__ __launch_bounds__(512)
void u_prep_scatter(const float* __restrict__ UCp, const float* __restrict__ hn,
                    const int* __restrict__ slot_np,
                    float* __restrict__ mS, float* __restrict__ extra)
{
    const int b    = blockIdx.x;
    const int tid  = threadIdx.x;
    const int wave = tid >> 6;
    const int lane = tid & 63;
    __shared__ float su[64];
    __shared__ float eu_s[64];

    const float* h = hn + (size_t)b * H_;
    for (int t = wave; t < TS_; t += 8) {
        const float* r = UCp + ((size_t)t * B_ + b) * H_;
        float p = 0.f;
        for (int j = lane; j < H_; j += 64)
            p += tanhf(r[j]) * h[j];
#pragma unroll
        for (int off = 32; off > 0; off >>= 1) p += __shfl_down(p, off);
        if (lane == 0) su[t] = p;
    }
    __syncthreads();
    if (tid < 64) {
        const float x = (tid < TS_) ? su[tid] : -3.4e38f;
        float mx = x;
#pragma unroll
        for (int off = 32; off > 0; off >>= 1) mx = fmaxf(mx, __shfl_xor(mx, off));
        const float ex = (tid < TS_) ? expf(x - mx) : 0.f;
        float sm = ex;
#pragma unroll
        for (int off = 32; off > 0; off >>= 1) sm += __shfl_xor(sm, off);
        eu_s[tid] = ex;
        if (tid == 0) { mS[b * 2] = mx; mS[b * 2 + 1] = sm; }
    }
    __syncthreads();
    if (tid < TS_) {
        const int sv = slot_np[tid * B_ + b];
        const float e = eu_s[tid];
        const bool copy = (sv == 2) || (sv >= V_);
        const bool add  = (sv != 0) && !copy;
        if (add)  atomicAdd(&extra[(size_t)b * VTS + sv], e);
        if (copy) atomicAdd(&extra[(size_t)b * VTS + V_ + tid], 5.0f * e);
    }
}

// ---------------------------------------------------------------------------
__device__ __forceinline__ float blk_reduce(float v, float* red, int tid, bool ismax)
{
    red[tid] = v; __syncthreads();
    for (int s = 128; s > 0; s >>= 1) {
        if (tid < s) red[tid] = ismax ? fmaxf(red[tid], red[tid + s]) : (red[tid] + red[tid + s]);
        __syncthreads();
    }
    const float r = red[0]; __syncthreads();
    return r;
}

__global__ __launch_bounds__(256)
void ph_max2(const float* __restrict__ gen, const float* __restrict__ extra,
             float* __restrict__ pgm, float* __restrict__ pzs,
             float* __restrict__ pem, float* __restrict__ pes)
{
    const int b = blockIdx.x, s = blockIdx.y, tid = threadIdx.x;
    __shared__ float red[256];
    const float* g  = gen + (size_t)b * V_;
    const float* ex = extra + (size_t)b * VTS;

    const int g0 = s * (V_ / NS);
    float gm = -3.4e38f;
    for (int i = g0 + tid; i < g0 + V_ / NS; i += 256) gm = fmaxf(gm, g[i]);
    gm = blk_reduce(gm, red, tid, true);
    float zs = 0.f;
    for (int i = g0 + tid; i < g0 + V_ / NS; i += 256) zs += expf(g[i] - gm);
    zs = blk_reduce(zs, red, tid, false);

    const int e0 = s * SLE;
    const int e1 = (e0 + SLE < VTS) ? e0 + SLE : VTS;
    float em = 0.f, es = 0.f;
    for (int i = e0 + tid; i < e1; i += 256) { const float v = ex[i]; em = fmaxf(em, v); es += v; }
    em = blk_reduce(em, red, tid, true);
    es = blk_reduce(es, red, tid, false);
    if (tid == 0) {
        pgm[b * NS + s] = gm; pzs[b * NS + s] = zs;
        pem[b * NS + s] = em; pes[b * NS + s] = es;
    }
}

__global__ __launch_bounds__(256)
void ph_write2(const float* __restrict__ gen, const float* __restrict__ extra,
               const float* __restrict__ pgm, const float* __restrict__ pzs,
               const float* __restrict__ pem, const float* __restrict__ pes,
               const float* __restrict__ mS, float* __restrict__ proba)
{
    const int b = blockIdx.x, s = blockIdx.y, tid = threadIdx.x;
    const float mb   = mS[b * 2];
    const float Sb   = mS[b * 2 + 1];
    const float base = 1e-10f * Sb;

    float gm = -3.4e38f, em = 0.f;
#pragma unroll
    for (int k = 0; k < NS; ++k) {
        gm = fmaxf(gm, pgm[b * NS + k]);
        em = fmaxf(em, pem[b * NS + k]);
    }
    const float M = fmaxf(gm, mb + logf(base + em));
    float s1 = 0.f, s2 = 0.f;
#pragma unroll
    for (int k = 0; k < NS; ++k) {
        s1 += pzs[b * NS + k] * expf(pgm[b * NS + k] - M);
        s2 += pes[b * NS + k];
    }
    const float cs  = expf(mb - M);
    const float inv = 1.f / (s1 + cs * (base * VTS + s2));

    const float* g  = gen + (size_t)b * V_;
    const float* ex = extra + (size_t)b * VTS;
    float* o = proba + (size_t)b * VTS;
    const int e0 = s * SLE;
    const int e1 = (e0 + SLE < VTS) ? e0 + SLE : VTS;
    for (int i = e0 + tid; i < e1; i += 256) {
        const float cp = cs * (base + ex[i]) * inv;
        o[i] = (i < V_) ? (expf(g[i] - M) * inv + cp) : cp;
    }
}

// ---------------------------------------------------------------------------
extern "C" void kernel_launch(void* const* d_in, const int* in_sizes, int n_in,
                              void* d_out, int out_size, void* d_ws, size_t ws_size,
                              hipStream_t stream)
{
    const float* slot_enc = (const float*)d_in[0];
    const float* pers_enc = (const float*)d_in[1];
    const float* hid      = (const float*)d_in[2];
    const int*   mt       = (const int*)d_in[3];
    const int*   slot_np  = (const int*)d_in[4];
    // d_in[5] sparse_u_input: reconstructed from slot_np (205 MB skipped)
    const float* emb      = (const float*)d_in[6];
    const float* W_attn_a = (const float*)d_in[7];
    const float* b_attn_a = (const float*)d_in[8];
    const float* v_a      = (const float*)d_in[9];
    const float* W_attn_p = (const float*)d_in[10];
    const float* b_attn_p = (const float*)d_in[11];
    const float* v_p      = (const float*)d_in[12];
    const float* W_ih     = (const float*)d_in[13];
    const float* W_hh     = (const float*)d_in[14];
    const float* b_ih     = (const float*)d_in[15];
    const float* b_hh     = (const float*)d_in[16];
    const float* W_proj   = (const float*)d_in[17];
    const float* b_proj   = (const float*)d_in[18];
    const float* W_c2     = (const float*)d_in[19];
    const float* b_c2     = (const float*)d_in[20];
    float* out = (float*)d_out;

    float* w = (float*)d_ws;
    size_t off = 0;
    auto alloc = [&](size_t n) { float* p = w + off; off += n; return p; };
    float* hA    = alloc((size_t)B_ * H_);
    float* hP    = alloc((size_t)B_ * H_);
    float* EA    = alloc((size_t)TS_ * B_ * H_);
    float* EP    = alloc((size_t)TP_ * B_ * H_);
    float* UCp   = alloc((size_t)TS_ * B_ * H_);
    float* ctxa  = alloc((size_t)B_ * H_);
    float* ctxp  = alloc((size_t)B_ * H_);
    float* gx    = alloc((size_t)B_ * E_);
    float* hnew  = alloc((size_t)B_ * H_);
    float* gen   = alloc((size_t)B_ * V_);
    float* mS    = alloc((size_t)2 * B_);
    float* extra = alloc((size_t)B_ * VTS);
    float* pgm   = alloc((size_t)B_ * NS);
    float* pzs   = alloc((size_t)B_ * NS);
    float* pem   = alloc((size_t)B_ * NS);
    float* pes   = alloc((size_t)B_ * NS);
    float* parts = w + off;

    const int o2 = B_ * VTS;
    const int o3 = o2 + B_ * H_;

    zero_buf<<<(B_ * VTS + 255) / 256, 256, 0, stream>>>(extra, B_ * VTS);
    gather_emb<<<(B_ * E_ + 255) / 256, 256, 0, stream>>>(emb, mt, gx);

    // hidden projections: z in {a,p}, K split 4x256
    gemm_hid<<<dim3(4, 4, 2), 256, 0, stream>>>(hid, W_attn_a, W_attn_p, parts);
    reduce_hid<<<(2 * B_ * H_ + 255) / 256, 256, 0, stream>>>(parts, b_attn_a, b_attn_p, hA, hP);

    // encoder projections: EA/EP/UCp fused, 8x8 micro
    gemm_tall8<<<dim3(25, 8, 3), 128, 0, stream>>>(
        slot_enc, pers_enc, W_attn_a, W_attn_p, W_c2, b_c2, EA, EP, UCp);

    // attention contexts (both in one launch)
    attn_fused<<<dim3(B_, 2), 512, 0, stream>>>(hA, hP, EA, EP, slot_enc, pers_enc, v_a, v_p, ctxa, ctxp);

    // GRU: 14-slice fused gemm + fused reduce/elementwise
    gemm_gru<<<dim3(12, 14), 256, 0, stream>>>(gx, ctxa, ctxp, hid, W_ih, W_hh, parts);
    reduce_gru<<<(B_ * H_ + 255) / 256, 256, 0, stream>>>(parts, b_ih, b_hh, hid, hnew, out + o2, out + o3);

    // vocab projection: 3 K-slices (ctxa|ctxp|hnew) x 2 K-halves
    gemm_proj<<<dim3(125, 6), 256, 0, stream>>>(ctxa, ctxp, hnew, W_proj, parts);
    reduce_parts<<<(B_ * V_ + 255) / 256, 256, 0, stream>>>(parts, b_proj, gen, V_, 6);

    // copy scores + scatter + joint softmax
    u_prep_scatter<<<B_, 512, 0, stream>>>(UCp, hnew, slot_np, mS, extra);
    ph_max2<<<dim3(B_, NS), 256, 0, stream>>>(gen, extra, pgm, pzs, pem, pes);
    ph_write2<<<dim3(B_, NS), 256, 0, stream>>>(gen, extra, pgm, pzs, pem, pes, mS, out);
}

// Round 6
// 550.221 us; speedup vs baseline: 1.3919x; 1.3919x over previous
//
#include <hip/hip_runtime.h>
#include <math.h>

static constexpr int V_   = 32000;
static constexpr int E_   = 512;
static constexpr int H_   = 1024;
static constexpr int B_   = 32;
static constexpr int TS_  = 50;
static constexpr int TP_  = 32;
static constexpr int VTS  = V_ + TS_;     // 32050
static constexpr int H3   = 3 * H_;       // 3072
static constexpr int GIN_ = E_ + 2 * H_;  // 2560
static constexpr int NS   = 8;            // softmax slices
static constexpr int SLE  = (VTS + NS - 1) / NS;  // 4007

// ---------------------------------------------------------------------------
__global__ void zero_buf(float* __restrict__ p, int n)
{
    const int i = blockIdx.x * 256 + threadIdx.x;
    if (i < n) p[i] = 0.f;
}

__global__ void gather_emb(const float* __restrict__ emb,
                           const int* __restrict__ mt,
                           float* __restrict__ gx)
{
    const int i = blockIdx.x * 256 + threadIdx.x;
    if (i >= B_ * E_) return;
    gx[i] = emb[(size_t)mt[i >> 9] * E_ + (i & 511)];
}

// ---------------------------------------------------------------------------
// m32v2 tile core: po[m*N + n] = sum_k A[m][klo+k] * W[n][wko+k]
// Tile 32m x 256n, KC=32, 256 threads (4 waves). Wave w owns m-rows 8w..8w+7
// (A frag = 2x ds_read_b128 at wave-uniform addr -> broadcast, conflict-free);
// lane l owns n-cols {l, l+64, l+128, l+192} (W frag = 4x ds_read_b32,
// 2 lanes/bank = free). No scalar loads in the hot loop -> no lgkmcnt(0)
// serialization (the R5 gemm_proj pathology: s_load + ds_read conflation).
// ---------------------------------------------------------------------------
__device__ __forceinline__ void m32v2_tile(
    const float* __restrict__ A, int lda,
    const float* __restrict__ W, int ldw, int wko,
    int klen, int n0, float* __restrict__ po, int N)
{
    __shared__ float As[32][36];    // [k][m]; 16B-aligned b128 rows
    __shared__ float Ws[32][257];   // [k][n]; pad 257 -> b32 r/w 2-way (free)

    const int tid  = threadIdx.x;
    const int lane = tid & 63;
    const int wv   = tid >> 6;           // wave id = m-group
    const int wq   = lane & 7;           // W-stage: k-quad
    const int wg   = lane >> 3;          // W-stage: row-in-8
    const int am   = tid >> 3;           // A-stage: m row (0..31)
    const int aq   = tid & 7;            // A-stage: k-quad

    float acc[8][4];
#pragma unroll
    for (int i = 0; i < 8; ++i)
#pragma unroll
        for (int j = 0; j < 4; ++j) acc[i][j] = 0.f;

    for (int kb = 0; kb < klen; kb += 32) {
        const float4 a4 = *reinterpret_cast<const float4*>(A + (size_t)am * lda + kb + 4 * aq);
        float4 w4[8];
#pragma unroll
        for (int i = 0; i < 8; ++i)
            w4[i] = *reinterpret_cast<const float4*>(
                W + (size_t)(n0 + wv * 64 + i * 8 + wg) * ldw + wko + kb + 4 * wq);
        __syncthreads();
        As[4 * aq + 0][am] = a4.x; As[4 * aq + 1][am] = a4.y;
        As[4 * aq + 2][am] = a4.z; As[4 * aq + 3][am] = a4.w;
#pragma unroll
        for (int i = 0; i < 8; ++i) {
            const int col = wv * 64 + i * 8 + wg;
            Ws[4 * wq + 0][col] = w4[i].x; Ws[4 * wq + 1][col] = w4[i].y;
            Ws[4 * wq + 2][col] = w4[i].z; Ws[4 * wq + 3][col] = w4[i].w;
        }
        __syncthreads();
#pragma unroll 8
        for (int k = 0; k < 32; ++k) {
            const float4 a0 = *reinterpret_cast<const float4*>(&As[k][wv * 8]);
            const float4 a1 = *reinterpret_cast<const float4*>(&As[k][wv * 8 + 4]);
            const float av[8] = {a0.x, a0.y, a0.z, a0.w, a1.x, a1.y, a1.z, a1.w};
            const float w0 = Ws[k][lane];
            const float w1 = Ws[k][lane + 64];
            const float w2 = Ws[k][lane + 128];
            const float w3 = Ws[k][lane + 192];
#pragma unroll
            for (int i = 0; i < 8; ++i) {
                acc[i][0] = fmaf(av[i], w0, acc[i][0]);
                acc[i][1] = fmaf(av[i], w1, acc[i][1]);
                acc[i][2] = fmaf(av[i], w2, acc[i][2]);
                acc[i][3] = fmaf(av[i], w3, acc[i][3]);
            }
        }
    }
#pragma unroll
    for (int i = 0; i < 8; ++i) {
        float* op = po + (size_t)(wv * 8 + i) * N + n0;
#pragma unroll
        for (int j = 0; j < 4; ++j)
            op[lane + 64 * j] = acc[i][j];
    }
}

__global__ __launch_bounds__(256)
void gemm_hid(const float* __restrict__ hid,
              const float* __restrict__ Wa, const float* __restrict__ Wp,
              float* __restrict__ parts)
{
    const int z = blockIdx.z, y = blockIdx.y, n0 = blockIdx.x * 256;
    const float* W = z ? Wp : Wa;
    m32v2_tile(hid + y * 256, H_, W, 2 * H_, y * 256, 256, n0,
               parts + (size_t)(z * 4 + y) * B_ * H_, H_);
}

__global__ void reduce_hid(const float* __restrict__ parts,
                           const float* __restrict__ ba, const float* __restrict__ bp,
                           float* __restrict__ hA, float* __restrict__ hP)
{
    const int i = blockIdx.x * 256 + threadIdx.x;
    if (i >= 2 * B_ * H_) return;
    const int z = i / (B_ * H_);
    const int r = i - z * B_ * H_;
    const int m = r >> 10, j = r & 1023;
    float s = (z ? bp : ba)[j];
#pragma unroll
    for (int ss = 0; ss < 4; ++ss)
        s += parts[((size_t)(z * 4 + ss) * B_ + m) * H_ + j];
    (z ? hP : hA)[r] = s;
}

__global__ __launch_bounds__(256)
void gemm_gru(const float* __restrict__ gx, const float* __restrict__ ctxa,
              const float* __restrict__ ctxp, const float* __restrict__ hid,
              const float* __restrict__ W_ih, const float* __restrict__ W_hh,
              float* __restrict__ parts)
{
    const int y = blockIdx.y, n0 = blockIdx.x * 256;
    const float* A; int lda; const float* W; int ldw; int wko; int klo;
    if (y < 2)       { klo = y * 256;        A = gx;   lda = E_; W = W_ih; ldw = GIN_; wko = klo; }
    else if (y < 6)  { klo = (y - 2) * 256;  A = ctxa; lda = H_; W = W_ih; ldw = GIN_; wko = 512 + klo; }
    else if (y < 10) { klo = (y - 6) * 256;  A = ctxp; lda = H_; W = W_ih; ldw = GIN_; wko = 1536 + klo; }
    else             { klo = (y - 10) * 256; A = hid;  lda = H_; W = W_hh; ldw = H_;   wko = klo; }
    m32v2_tile(A + klo, lda, W, ldw, wko, 256, n0,
               parts + (size_t)y * B_ * H3, H3);
}

__global__ void reduce_gru(const float* __restrict__ parts,
                           const float* __restrict__ b_ih, const float* __restrict__ b_hh,
                           const float* __restrict__ hid,
                           float* __restrict__ hnew,
                           float* __restrict__ o2, float* __restrict__ o3)
{
    const int i = blockIdx.x * 256 + threadIdx.x;
    if (i >= B_ * H_) return;
    const int b = i >> 10, j = i & 1023;
    float gi[3], gh[3];
#pragma unroll
    for (int c = 0; c < 3; ++c) {
        float s = b_ih[c * H_ + j];
        for (int y = 0; y < 10; ++y)
            s += parts[((size_t)y * B_ + b) * H3 + c * H_ + j];
        gi[c] = s;
        float t = b_hh[c * H_ + j];
        for (int y = 10; y < 14; ++y)
            t += parts[((size_t)y * B_ + b) * H3 + c * H_ + j];
        gh[c] = t;
    }
    const float r = 1.f / (1.f + expf(-(gi[0] + gh[0])));
    const float z = 1.f / (1.f + expf(-(gi[1] + gh[1])));
    const float n = tanhf(gi[2] + r * gh[2]);
    const float o = (1.f - z) * n + z * hid[i];
    hnew[i] = o; o2[i] = o; o3[i] = o;
}

__global__ __launch_bounds__(256)
void gemm_proj(const float* __restrict__ ctxa, const float* __restrict__ ctxp,
               const float* __restrict__ hnew, const float* __restrict__ W_proj,
               float* __restrict__ parts)
{
    const int y = blockIdx.y, n0 = blockIdx.x * 256;
    const int slice = y >> 1, khalf = y & 1;
    const float* A = (slice == 0) ? ctxa : (slice == 1) ? ctxp : hnew;
    m32v2_tile(A + khalf * 512, H_, W_proj, H3, slice * 1024 + khalf * 512,
               512, n0, parts + (size_t)y * B_ * V_, V_);
}

__global__ void reduce_parts(const float* __restrict__ part,
                             const float* __restrict__ bias,
                             float* __restrict__ out, int N, int S)
{
    const int i = blockIdx.x * 256 + threadIdx.x;
    if (i >= B_ * N) return;
    float s = 0.f;
    for (int ss = 0; ss < S; ++ss) s += part[(size_t)ss * B_ * N + i];
    out[i] = s + bias[i % N];
}

// ---------------------------------------------------------------------------
// gemm_tall8: C = A @ W^T (+bias), 64x128 tile, 8x8 micro, KC=32, 128 threads.
// z selects {EA, EP, UCp}. Ws gap-swizzled col' = n + 4*(n>>5) (140 cols).
// ---------------------------------------------------------------------------
__global__ __launch_bounds__(128)
void gemm_tall8(const float* __restrict__ slot_enc, const float* __restrict__ pers_enc,
                const float* __restrict__ W_attn_a, const float* __restrict__ W_attn_p,
                const float* __restrict__ W_c2, const float* __restrict__ b_c2,
                float* __restrict__ EA, float* __restrict__ EP, float* __restrict__ UCp)
{
    __shared__ float As[32][68];
    __shared__ float Ws[32][140];
    const int z = blockIdx.z;
    const float* A; const float* W; const float* bias; float* C; int M, ldw;
    if (z == 0)      { A = slot_enc; W = W_attn_a + H_; bias = nullptr; C = EA;  M = TS_ * B_; ldw = 2 * H_; }
    else if (z == 1) { A = pers_enc; W = W_attn_p + H_; bias = nullptr; C = EP;  M = TP_ * B_; ldw = 2 * H_; }
    else             { A = slot_enc; W = W_c2;          bias = b_c2;    C = UCp; M = TS_ * B_; ldw = H_; }
    const int m0 = blockIdx.x * 64;
    if (m0 >= M) return;
    const int n0 = blockIdx.y * 128;
    const int tid = threadIdx.x;
    const int tym = tid >> 4, txn = tid & 15;
    const int sr = tid & 63, sh = tid >> 6;
    const int arow = (m0 + sr < M) ? (m0 + sr) : (M - 1);
    const int wcol = tid + 4 * (tid >> 5);
    const int wb = 8 * txn + 4 * (txn >> 2);

    float acc[8][8];
#pragma unroll
    for (int i = 0; i < 8; ++i)
#pragma unroll
        for (int j = 0; j < 8; ++j) acc[i][j] = 0.f;

    for (int kb = 0; kb < H_; kb += 32) {
        float4 a4[4], w4[8];
#pragma unroll
        for (int q = 0; q < 4; ++q)
            a4[q] = *reinterpret_cast<const float4*>(A + (size_t)arow * H_ + kb + sh * 16 + 4 * q);
#pragma unroll
        for (int q = 0; q < 8; ++q)
            w4[q] = *reinterpret_cast<const float4*>(W + (size_t)(n0 + tid) * ldw + kb + 4 * q);
        __syncthreads();
#pragma unroll
        for (int q = 0; q < 4; ++q) {
            As[sh * 16 + 4 * q + 0][sr] = a4[q].x; As[sh * 16 + 4 * q + 1][sr] = a4[q].y;
            As[sh * 16 + 4 * q + 2][sr] = a4[q].z; As[sh * 16 + 4 * q + 3][sr] = a4[q].w;
        }
#pragma unroll
        for (int q = 0; q < 8; ++q) {
            Ws[4 * q + 0][wcol] = w4[q].x; Ws[4 * q + 1][wcol] = w4[q].y;
            Ws[4 * q + 2][wcol] = w4[q].z; Ws[4 * q + 3][wcol] = w4[q].w;
        }
        __syncthreads();
#pragma unroll 8
        for (int k = 0; k < 32; ++k) {
            const float4 a0 = *reinterpret_cast<const float4*>(&As[k][8 * tym]);
            const float4 a1 = *reinterpret_cast<const float4*>(&As[k][8 * tym + 4]);
            const float4 w0 = *reinterpret_cast<const float4*>(&Ws[k][wb]);
            const float4 w1 = *reinterpret_cast<const float4*>(&Ws[k][wb + 4]);
            const float av[8] = {a0.x, a0.y, a0.z, a0.w, a1.x, a1.y, a1.z, a1.w};
            const float wv[8] = {w0.x, w0.y, w0.z, w0.w, w1.x, w1.y, w1.z, w1.w};
#pragma unroll
            for (int i = 0; i < 8; ++i)
#pragma unroll
                for (int j = 0; j < 8; ++j)
                    acc[i][j] = fmaf(av[i], wv[j], acc[i][j]);
        }
    }
#pragma unroll
    for (int i = 0; i < 8; ++i) {
        const int row = m0 + 8 * tym + i;
        if (row < M) {
            float4 o0, o1;
            o0.x = acc[i][0]; o0.y = acc[i][1]; o0.z = acc[i][2]; o0.w = acc[i][3];
            o1.x = acc[i][4]; o1.y = acc[i][5]; o1.z = acc[i][6]; o1.w = acc[i][7];
            if (bias) {
                const float4 b0 = *reinterpret_cast<const float4*>(bias + n0 + 8 * txn);
                const float4 b1 = *reinterpret_cast<const float4*>(bias + n0 + 8 * txn + 4);
                o0.x += b0.x; o0.y += b0.y; o0.z += b0.z; o0.w += b0.w;
                o1.x += b1.x; o1.y += b1.y; o1.z += b1.z; o1.w += b1.w;
            }
            *reinterpret_cast<float4*>(C + (size_t)row * H_ + n0 + 8 * txn) = o0;
            *reinterpret_cast<float4*>(C + (size_t)row * H_ + n0 + 8 * txn + 4) = o1;
        }
    }
}

// ---------------------------------------------------------------------------
__global__ __launch_bounds__(512)
void attn_fused(const float* __restrict__ hA, const float* __restrict__ hP,
                const float* __restrict__ EA, const float* __restrict__ EP,
                const float* __restrict__ slot_enc, const float* __restrict__ pers_enc,
                const float* __restrict__ v_a, const float* __restrict__ v_p,
                float* __restrict__ ctxa, float* __restrict__ ctxp)
{
    const int b = blockIdx.x, z = blockIdx.y;
    const int T = z ? TP_ : TS_;
    const float* hX  = z ? hP : hA;
    const float* EX  = z ? EP : EA;
    const float* enc = z ? pers_enc : slot_enc;
    const float* v   = z ? v_p : v_a;
    float* ctx       = z ? ctxp : ctxa;

    const int tid  = threadIdx.x;
    const int wave = tid >> 6;
    const int lane = tid & 63;
    __shared__ float sc[64];
    __shared__ float aw[64];

    const float* ha = hX + (size_t)b * H_;
    for (int t = wave; t < T; t += 8) {
        const float* e = EX + ((size_t)t * B_ + b) * H_;
        float p = 0.f;
        for (int j = lane; j < H_; j += 64)
            p += v[j] * tanhf(ha[j] + e[j]);
#pragma unroll
        for (int off = 32; off > 0; off >>= 1) p += __shfl_down(p, off);
        if (lane == 0) sc[t] = p;
    }
    __syncthreads();
    if (tid < 64) {
        const float x = (tid < T) ? sc[tid] : -3.4e38f;
        float mx = x;
#pragma unroll
        for (int off = 32; off > 0; off >>= 1) mx = fmaxf(mx, __shfl_xor(mx, off));
        const float ex = (tid < T) ? expf(x - mx) : 0.f;
        float sm = ex;
#pragma unroll
        for (int off = 32; off > 0; off >>= 1) sm += __shfl_xor(sm, off);
        aw[tid] = ex / sm;
    }
    __syncthreads();
    for (int k = tid; k < H_; k += 512) {
        float c = 0.f;
        for (int t = 0; t < T; ++t)
            c += aw[t] * enc[((size_t)t * B_ + b) * H_ + k];
        ctx[(size_t)b * H_ + k] = c;
    }
}

// ---------------------------------------------------------------------------
__global__ __launch_bounds__(512)
void u_prep_scatter(const float* __restrict__ UCp, const float* __restrict__ hn,
                    const int* __restrict__ slot_np,
                    float* __restrict__ mS, float* __restrict__ extra)
{
    const int b    = blockIdx.x;
    const int tid  = threadIdx.x;
    const int wave = tid >> 6;
    const int lane = tid & 63;
    __shared__ float su[64];
    __shared__ float eu_s[64];

    const float* h = hn + (size_t)b * H_;
    for (int t = wave; t < TS_; t += 8) {
        const float* r = UCp + ((size_t)t * B_ + b) * H_;
        float p = 0.f;
        for (int j = lane; j < H_; j += 64)
            p += tanhf(r[j]) * h[j];
#pragma unroll
        for (int off = 32; off > 0; off >>= 1) p += __shfl_down(p, off);
        if (lane == 0) su[t] = p;
    }
    __syncthreads();
    if (tid < 64) {
        const float x = (tid < TS_) ? su[tid] : -3.4e38f;
        float mx = x;
#pragma unroll
        for (int off = 32; off > 0; off >>= 1) mx = fmaxf(mx, __shfl_xor(mx, off));
        const float ex = (tid < TS_) ? expf(x - mx) : 0.f;
        float sm = ex;
#pragma unroll
        for (int off = 32; off > 0; off >>= 1) sm += __shfl_xor(sm, off);
        eu_s[tid] = ex;
        if (tid == 0) { mS[b * 2] = mx; mS[b * 2 + 1] = sm; }
    }
    __syncthreads();
    if (tid < TS_) {
        const int sv = slot_np[tid * B_ + b];
        const float e = eu_s[tid];
        const bool copy = (sv == 2) || (sv >= V_);
        const bool add  = (sv != 0) && !copy;
        if (add)  atomicAdd(&extra[(size_t)b * VTS + sv], e);
        if (copy) atomicAdd(&extra[(size_t)b * VTS + V_ + tid], 5.0f * e);
    }
}

// ---------------------------------------------------------------------------
__device__ __forceinline__ float blk_reduce(float v, float* red, int tid, bool ismax)
{
    red[tid] = v; __syncthreads();
    for (int s = 128; s > 0; s >>= 1) {
        if (tid < s) red[tid] = ismax ? fmaxf(red[tid], red[tid + s]) : (red[tid] + red[tid + s]);
        __syncthreads();
    }
    const float r = red[0]; __syncthreads();
    return r;
}

__global__ __launch_bounds__(256)
void ph_max2(const float* __restrict__ gen, const float* __restrict__ extra,
             float* __restrict__ pgm, float* __restrict__ pzs,
             float* __restrict__ pem, float* __restrict__ pes)
{
    const int b = blockIdx.x, s = blockIdx.y, tid = threadIdx.x;
    __shared__ float red[256];
    const float* g  = gen + (size_t)b * V_;
    const float* ex = extra + (size_t)b * VTS;

    const int g0 = s * (V_ / NS);
    float gm = -3.4e38f;
    for (int i = g0 + tid; i < g0 + V_ / NS; i += 256) gm = fmaxf(gm, g[i]);
    gm = blk_reduce(gm, red, tid, true);
    float zs = 0.f;
    for (int i = g0 + tid; i < g0 + V_ / NS; i += 256) zs += expf(g[i] - gm);
    zs = blk_reduce(zs, red, tid, false);

    const int e0 = s * SLE;
    const int e1 = (e0 + SLE < VTS) ? e0 + SLE : VTS;
    float em = 0.f, es = 0.f;
    for (int i = e0 + tid; i < e1; i += 256) { const float v = ex[i]; em = fmaxf(em, v); es += v; }
    em = blk_reduce(em, red, tid, true);
    es = blk_reduce(es, red, tid, false);
    if (tid == 0) {
        pgm[b * NS + s] = gm; pzs[b * NS + s] = zs;
        pem[b * NS + s] = em; pes[b * NS + s] = es;
    }
}

__global__ __launch_bounds__(256)
void ph_write2(const float* __restrict__ gen, const float* __restrict__ extra,
               const float* __restrict__ pgm, const float* __restrict__ pzs,
               const float* __restrict__ pem, const float* __restrict__ pes,
               const float* __restrict__ mS, float* __restrict__ proba)
{
    const int b = blockIdx.x, s = blockIdx.y, tid = threadIdx.x;
    const float mb   = mS[b * 2];
    const float Sb   = mS[b * 2 + 1];
    const float base = 1e-10f * Sb;

    float gm = -3.4e38f, em = 0.f;
#pragma unroll
    for (int k = 0; k < NS; ++k) {
        gm = fmaxf(gm, pgm[b * NS + k]);
        em = fmaxf(em, pem[b * NS + k]);
    }
    const float M = fmaxf(gm, mb + logf(base + em));
    float s1 = 0.f, s2 = 0.f;
#pragma unroll
    for (int k = 0; k < NS; ++k) {
        s1 += pzs[b * NS + k] * expf(pgm[b * NS + k] - M);
        s2 += pes[b * NS + k];
    }
    const float cs  = expf(mb - M);
    const float inv = 1.f / (s1 + cs * (base * VTS + s2));

    const float* g  = gen + (size_t)b * V_;
    const float* ex = extra + (size_t)b * VTS;
    float* o = proba + (size_t)b * VTS;
    const int e0 = s * SLE;
    const int e1 = (e0 + SLE < VTS) ? e0 + SLE : VTS;
    for (int i = e0 + tid; i < e1; i += 256) {
        const float cp = cs * (base + ex[i]) * inv;
        o[i] = (i < V_) ? (expf(g[i] - M) * inv + cp) : cp;
    }
}

// ---------------------------------------------------------------------------
extern "C" void kernel_launch(void* const* d_in, const int* in_sizes, int n_in,
                              void* d_out, int out_size, void* d_ws, size_t ws_size,
                              hipStream_t stream)
{
    const float* slot_enc = (const float*)d_in[0];
    const float* pers_enc = (const float*)d_in[1];
    const float* hid      = (const float*)d_in[2];
    const int*   mt       = (const int*)d_in[3];
    const int*   slot_np  = (const int*)d_in[4];
    // d_in[5] sparse_u_input: reconstructed from slot_np (205 MB skipped)
    const float* emb      = (const float*)d_in[6];
    const float* W_attn_a = (const float*)d_in[7];
    const float* b_attn_a = (const float*)d_in[8];
    const float* v_a      = (const float*)d_in[9];
    const float* W_attn_p = (const float*)d_in[10];
    const float* b_attn_p = (const float*)d_in[11];
    const float* v_p      = (const float*)d_in[12];
    const float* W_ih     = (const float*)d_in[13];
    const float* W_hh     = (const float*)d_in[14];
    const float* b_ih     = (const float*)d_in[15];
    const float* b_hh     = (const float*)d_in[16];
    const float* W_proj   = (const float*)d_in[17];
    const float* b_proj   = (const float*)d_in[18];
    const float* W_c2     = (const float*)d_in[19];
    const float* b_c2     = (const float*)d_in[20];
    float* out = (float*)d_out;

    float* w = (float*)d_ws;
    size_t off = 0;
    auto alloc = [&](size_t n) { float* p = w + off; off += n; return p; };
    float* hA    = alloc((size_t)B_ * H_);
    float* hP    = alloc((size_t)B_ * H_);
    float* EA    = alloc((size_t)TS_ * B_ * H_);
    float* EP    = alloc((size_t)TP_ * B_ * H_);
    float* UCp   = alloc((size_t)TS_ * B_ * H_);
    float* ctxa  = alloc((size_t)B_ * H_);
    float* ctxp  = alloc((size_t)B_ * H_);
    float* gx    = alloc((size_t)B_ * E_);
    float* hnew  = alloc((size_t)B_ * H_);
    float* gen   = alloc((size_t)B_ * V_);
    float* mS    = alloc((size_t)2 * B_);
    float* extra = alloc((size_t)B_ * VTS);
    float* pgm   = alloc((size_t)B_ * NS);
    float* pzs   = alloc((size_t)B_ * NS);
    float* pem   = alloc((size_t)B_ * NS);
    float* pes   = alloc((size_t)B_ * NS);
    float* parts = w + off;

    const int o2 = B_ * VTS;
    const int o3 = o2 + B_ * H_;

    zero_buf<<<(B_ * VTS + 255) / 256, 256, 0, stream>>>(extra, B_ * VTS);
    gather_emb<<<(B_ * E_ + 255) / 256, 256, 0, stream>>>(emb, mt, gx);

    // hidden projections: z in {a,p}, K split 4x256
    gemm_hid<<<dim3(4, 4, 2), 256, 0, stream>>>(hid, W_attn_a, W_attn_p, parts);
    reduce_hid<<<(2 * B_ * H_ + 255) / 256, 256, 0, stream>>>(parts, b_attn_a, b_attn_p, hA, hP);

    // encoder projections: EA/EP/UCp fused, 8x8 micro
    gemm_tall8<<<dim3(25, 8, 3), 128, 0, stream>>>(
        slot_enc, pers_enc, W_attn_a, W_attn_p, W_c2, b_c2, EA, EP, UCp);

    // attention contexts (both in one launch)
    attn_fused<<<dim3(B_, 2), 512, 0, stream>>>(hA, hP, EA, EP, slot_enc, pers_enc, v_a, v_p, ctxa, ctxp);

    // GRU: 14-slice fused gemm + fused reduce/elementwise
    gemm_gru<<<dim3(12, 14), 256, 0, stream>>>(gx, ctxa, ctxp, hid, W_ih, W_hh, parts);
    reduce_gru<<<(B_ * H_ + 255) / 256, 256, 0, stream>>>(parts, b_ih, b_hh, hid, hnew, out + o2, out + o3);

    // vocab projection: 3 K-slices (ctxa|ctxp|hnew) x 2 K-halves
    gemm_proj<<<dim3(125, 6), 256, 0, stream>>>(ctxa, ctxp, hnew, W_proj, parts);
    reduce_parts<<<(B_ * V_ + 255) / 256, 256, 0, stream>>>(parts, b_proj, gen, V_, 6);

    // copy scores + scatter + joint softmax
    u_prep_scatter<<<B_, 512, 0, stream>>>(UCp, hnew, slot_np, mS, extra);
    ph_max2<<<dim3(B_, NS), 256, 0, stream>>>(gen, extra, pgm, pzs, pem, pes);
    ph_write2<<<dim3(B_, NS), 256, 0, stream>>>(gen, extra, pgm, pzs, pem, pes, mS, out);
}

// Round 7
// 481.819 us; speedup vs baseline: 1.5895x; 1.1420x over previous
//
#include <hip/hip_runtime.h>
#include <math.h>

static constexpr int V_   = 32000;
static constexpr int E_   = 512;
static constexpr int H_   = 1024;
static constexpr int B_   = 32;
static constexpr int TS_  = 50;
static constexpr int TP_  = 32;
static constexpr int VTS  = V_ + TS_;     // 32050
static constexpr int H3   = 3 * H_;       // 3072
static constexpr int GIN_ = E_ + 2 * H_;  // 2560
static constexpr int NS   = 8;            // softmax slices
static constexpr int SLE  = (VTS + NS - 1) / NS;  // 4007
static constexpr int GSL  = V_ / NS;      // 4000 gen cols per slice

// ---------------------------------------------------------------------------
__global__ void zero_gather(float* __restrict__ extra,
                            const float* __restrict__ emb,
                            const int* __restrict__ mt,
                            float* __restrict__ gx)
{
    const int i = blockIdx.x * 256 + threadIdx.x;
    if (i < B_ * VTS) extra[i] = 0.f;
    if (i < B_ * E_) gx[i] = emb[(size_t)mt[i >> 9] * E_ + (i & 511)];
}

// ---------------------------------------------------------------------------
// m32v2 tile core (proven in R6): 32m x 256n, KC=32, 4 waves. A broadcast via
// b128; W via 4 free b32; no scalar loads in hot loop.
// ---------------------------------------------------------------------------
__device__ __forceinline__ void m32v2_tile(
    const float* __restrict__ A, int lda,
    const float* __restrict__ W, int ldw, int wko,
    int klen, int n0, float* __restrict__ po, int N)
{
    __shared__ float As[32][36];
    __shared__ float Ws[32][257];

    const int tid  = threadIdx.x;
    const int lane = tid & 63;
    const int wv   = tid >> 6;
    const int wq   = lane & 7;
    const int wg   = lane >> 3;
    const int am   = tid >> 3;
    const int aq   = tid & 7;

    float acc[8][4];
#pragma unroll
    for (int i = 0; i < 8; ++i)
#pragma unroll
        for (int j = 0; j < 4; ++j) acc[i][j] = 0.f;

    for (int kb = 0; kb < klen; kb += 32) {
        const float4 a4 = *reinterpret_cast<const float4*>(A + (size_t)am * lda + kb + 4 * aq);
        float4 w4[8];
#pragma unroll
        for (int i = 0; i < 8; ++i)
            w4[i] = *reinterpret_cast<const float4*>(
                W + (size_t)(n0 + wv * 64 + i * 8 + wg) * ldw + wko + kb + 4 * wq);
        __syncthreads();
        As[4 * aq + 0][am] = a4.x; As[4 * aq + 1][am] = a4.y;
        As[4 * aq + 2][am] = a4.z; As[4 * aq + 3][am] = a4.w;
#pragma unroll
        for (int i = 0; i < 8; ++i) {
            const int col = wv * 64 + i * 8 + wg;
            Ws[4 * wq + 0][col] = w4[i].x; Ws[4 * wq + 1][col] = w4[i].y;
            Ws[4 * wq + 2][col] = w4[i].z; Ws[4 * wq + 3][col] = w4[i].w;
        }
        __syncthreads();
#pragma unroll 8
        for (int k = 0; k < 32; ++k) {
            const float4 a0 = *reinterpret_cast<const float4*>(&As[k][wv * 8]);
            const float4 a1 = *reinterpret_cast<const float4*>(&As[k][wv * 8 + 4]);
            const float av[8] = {a0.x, a0.y, a0.z, a0.w, a1.x, a1.y, a1.z, a1.w};
            const float w0 = Ws[k][lane];
            const float w1 = Ws[k][lane + 64];
            const float w2 = Ws[k][lane + 128];
            const float w3 = Ws[k][lane + 192];
#pragma unroll
            for (int i = 0; i < 8; ++i) {
                acc[i][0] = fmaf(av[i], w0, acc[i][0]);
                acc[i][1] = fmaf(av[i], w1, acc[i][1]);
                acc[i][2] = fmaf(av[i], w2, acc[i][2]);
                acc[i][3] = fmaf(av[i], w3, acc[i][3]);
            }
        }
    }
#pragma unroll
    for (int i = 0; i < 8; ++i) {
        float* op = po + (size_t)(wv * 8 + i) * N + n0;
#pragma unroll
        for (int j = 0; j < 4; ++j)
            op[lane + 64 * j] = acc[i][j];
    }
}

__global__ __launch_bounds__(256)
void gemm_hid(const float* __restrict__ hid,
              const float* __restrict__ Wa, const float* __restrict__ Wp,
              float* __restrict__ parts)
{
    const int z = blockIdx.z, y = blockIdx.y, n0 = blockIdx.x * 256;
    const float* W = z ? Wp : Wa;
    m32v2_tile(hid + y * 256, H_, W, 2 * H_, y * 256, 256, n0,
               parts + (size_t)(z * 4 + y) * B_ * H_, H_);
}

__global__ __launch_bounds__(256)
void gemm_gru(const float* __restrict__ gx, const float* __restrict__ ctxa,
              const float* __restrict__ ctxp, const float* __restrict__ hid,
              const float* __restrict__ W_ih, const float* __restrict__ W_hh,
              float* __restrict__ parts)
{
    const int y = blockIdx.y, n0 = blockIdx.x * 256;
    const float* A; int lda; const float* W; int ldw; int wko; int klo;
    if (y < 2)       { klo = y * 256;        A = gx;   lda = E_; W = W_ih; ldw = GIN_; wko = klo; }
    else if (y < 6)  { klo = (y - 2) * 256;  A = ctxa; lda = H_; W = W_ih; ldw = GIN_; wko = 512 + klo; }
    else if (y < 10) { klo = (y - 6) * 256;  A = ctxp; lda = H_; W = W_ih; ldw = GIN_; wko = 1536 + klo; }
    else             { klo = (y - 10) * 256; A = hid;  lda = H_; W = W_hh; ldw = H_;   wko = klo; }
    m32v2_tile(A + klo, lda, W, ldw, wko, 256, n0,
               parts + (size_t)y * B_ * H3, H3);
}

__global__ void reduce_gru(const float* __restrict__ parts,
                           const float* __restrict__ b_ih, const float* __restrict__ b_hh,
                           const float* __restrict__ hid,
                           float* __restrict__ hnew,
                           float* __restrict__ o2, float* __restrict__ o3)
{
    const int i = blockIdx.x * 256 + threadIdx.x;
    if (i >= B_ * H_) return;
    const int b = i >> 10, j = i & 1023;
    float gi[3], gh[3];
#pragma unroll
    for (int c = 0; c < 3; ++c) {
        float s = b_ih[c * H_ + j];
        for (int y = 0; y < 10; ++y)
            s += parts[((size_t)y * B_ + b) * H3 + c * H_ + j];
        gi[c] = s;
        float t = b_hh[c * H_ + j];
        for (int y = 10; y < 14; ++y)
            t += parts[((size_t)y * B_ + b) * H3 + c * H_ + j];
        gh[c] = t;
    }
    const float r = 1.f / (1.f + expf(-(gi[0] + gh[0])));
    const float z = 1.f / (1.f + expf(-(gi[1] + gh[1])));
    const float n = tanhf(gi[2] + r * gh[2]);
    const float o = (1.f - z) * n + z * hid[i];
    hnew[i] = o; o2[i] = o; o3[i] = o;
}

__global__ __launch_bounds__(256)
void gemm_proj(const float* __restrict__ ctxa, const float* __restrict__ ctxp,
               const float* __restrict__ hnew, const float* __restrict__ W_proj,
               float* __restrict__ parts)
{
    const int y = blockIdx.y, n0 = blockIdx.x * 256;
    const int slice = y >> 1, khalf = y & 1;
    const float* A = (slice == 0) ? ctxa : (slice == 1) ? ctxp : hnew;
    m32v2_tile(A + khalf * 512, H_, W_proj, H3, slice * 1024 + khalf * 512,
               512, n0, parts + (size_t)y * B_ * V_, V_);
}

// ---------------------------------------------------------------------------
// gemm_tall84: 64x128 tile, 8m x 4n micro, 256 threads (4 waves), KC=32.
// z=0: SA = tanh(slot_enc@Wa2^T + ha_a) * v_a   (ha folded from gemm_hid parts)
// z=1: SP = tanh(pers_enc@Wp2^T + ha_p) * v_p
// z=2: UCt = tanh(slot_enc@W_c2^T + b_c2)
// Bank audit: A-read 2x b128 broadcast; W-read 4x b32 cols {txn,+32,+64,+96}
// -> 32 distinct banks; all staging writes 2-way (free).
// ---------------------------------------------------------------------------
__global__ __launch_bounds__(256)
void gemm_tall84(const float* __restrict__ slot_enc, const float* __restrict__ pers_enc,
                 const float* __restrict__ W_attn_a, const float* __restrict__ W_attn_p,
                 const float* __restrict__ W_c2,
                 const float* __restrict__ b_attn_a, const float* __restrict__ b_attn_p,
                 const float* __restrict__ b_c2,
                 const float* __restrict__ v_a, const float* __restrict__ v_p,
                 const float* __restrict__ parts,
                 float* __restrict__ SA, float* __restrict__ SP, float* __restrict__ UCt)
{
    __shared__ float As[32][68];
    __shared__ float Ws[32][132];
    const int z = blockIdx.z;
    const float* A; const float* W; float* C; int M, ldw;
    if (z == 0)      { A = slot_enc; W = W_attn_a + H_; C = SA;  M = TS_ * B_; ldw = 2 * H_; }
    else if (z == 1) { A = pers_enc; W = W_attn_p + H_; C = SP;  M = TP_ * B_; ldw = 2 * H_; }
    else             { A = slot_enc; W = W_c2;          C = UCt; M = TS_ * B_; ldw = H_; }
    const int m0 = blockIdx.x * 64;
    if (m0 >= M) return;
    const int n0 = blockIdx.y * 128;
    const int tid = threadIdx.x;
    const int tym = tid >> 5;            // 0..7 (m-group of 8 rows)
    const int txn = tid & 31;            // n within group
    const int sr = tid & 63, sh = tid >> 6;     // A-stage: row, k-eighth
    const int wr = tid & 127, wh = tid >> 7;    // W-stage: col, k-half

    float acc[8][4];
#pragma unroll
    for (int i = 0; i < 8; ++i)
#pragma unroll
        for (int j = 0; j < 4; ++j) acc[i][j] = 0.f;

    for (int kb = 0; kb < H_; kb += 32) {
        float4 a4[2], w4[4];
#pragma unroll
        for (int q = 0; q < 2; ++q)
            a4[q] = *reinterpret_cast<const float4*>(A + (size_t)(m0 + sr) * H_ + kb + 8 * sh + 4 * q);
#pragma unroll
        for (int q = 0; q < 4; ++q)
            w4[q] = *reinterpret_cast<const float4*>(W + (size_t)(n0 + wr) * ldw + kb + 16 * wh + 4 * q);
        __syncthreads();
#pragma unroll
        for (int q = 0; q < 2; ++q) {
            As[8 * sh + 4 * q + 0][sr] = a4[q].x; As[8 * sh + 4 * q + 1][sr] = a4[q].y;
            As[8 * sh + 4 * q + 2][sr] = a4[q].z; As[8 * sh + 4 * q + 3][sr] = a4[q].w;
        }
#pragma unroll
        for (int q = 0; q < 4; ++q) {
            Ws[16 * wh + 4 * q + 0][wr] = w4[q].x; Ws[16 * wh + 4 * q + 1][wr] = w4[q].y;
            Ws[16 * wh + 4 * q + 2][wr] = w4[q].z; Ws[16 * wh + 4 * q + 3][wr] = w4[q].w;
        }
        __syncthreads();
#pragma unroll 8
        for (int k = 0; k < 32; ++k) {
            const float4 a0 = *reinterpret_cast<const float4*>(&As[k][8 * tym]);
            const float4 a1 = *reinterpret_cast<const float4*>(&As[k][8 * tym + 4]);
            const float av[8] = {a0.x, a0.y, a0.z, a0.w, a1.x, a1.y, a1.z, a1.w};
            const float w0 = Ws[k][txn];
            const float w1 = Ws[k][txn + 32];
            const float w2 = Ws[k][txn + 64];
            const float w3 = Ws[k][txn + 96];
#pragma unroll
            for (int i = 0; i < 8; ++i) {
                acc[i][0] = fmaf(av[i], w0, acc[i][0]);
                acc[i][1] = fmaf(av[i], w1, acc[i][1]);
                acc[i][2] = fmaf(av[i], w2, acc[i][2]);
                acc[i][3] = fmaf(av[i], w3, acc[i][3]);
            }
        }
    }

    if (z < 2) {
        const float* bvec = z ? b_attn_p : b_attn_a;
        const float* vvec = z ? v_p : v_a;
        const float* pp = parts + (size_t)(z * 4) * B_ * H_;
#pragma unroll
        for (int i = 0; i < 8; ++i) {
            const int row = m0 + 8 * tym + i;
            const int b = row & 31;                 // row = t*B + b, B=32
#pragma unroll
            for (int j = 0; j < 4; ++j) {
                const int col = n0 + txn + 32 * j;
                float ha = bvec[col];
#pragma unroll
                for (int ss = 0; ss < 4; ++ss)
                    ha += pp[((size_t)ss * B_ + b) * H_ + col];
                C[(size_t)row * H_ + col] = tanhf(acc[i][j] + ha) * vvec[col];
            }
        }
    } else {
#pragma unroll
        for (int i = 0; i < 8; ++i) {
            const int row = m0 + 8 * tym + i;
#pragma unroll
            for (int j = 0; j < 4; ++j) {
                const int col = n0 + txn + 32 * j;
                C[(size_t)row * H_ + col] = tanhf(acc[i][j] + b_c2[col]);
            }
        }
    }
}

// ---------------------------------------------------------------------------
// Attention: scores are now plain sums over the precomputed S = tanh(.)*v.
// ---------------------------------------------------------------------------
__global__ __launch_bounds__(512)
void attn_fused2(const float* __restrict__ SA, const float* __restrict__ SP,
                 const float* __restrict__ slot_enc, const float* __restrict__ pers_enc,
                 float* __restrict__ ctxa, float* __restrict__ ctxp)
{
    const int b = blockIdx.x, z = blockIdx.y;
    const int T = z ? TP_ : TS_;
    const float* S   = z ? SP : SA;
    const float* enc = z ? pers_enc : slot_enc;
    float* ctx       = z ? ctxp : ctxa;

    const int tid  = threadIdx.x;
    const int wave = tid >> 6;
    const int lane = tid & 63;
    __shared__ float sc[64];
    __shared__ float aw[64];

    for (int t = wave; t < T; t += 8) {
        const float* e = S + ((size_t)t * B_ + b) * H_;
        float p = 0.f;
        for (int j = lane; j < H_; j += 64) p += e[j];
#pragma unroll
        for (int off = 32; off > 0; off >>= 1) p += __shfl_down(p, off);
        if (lane == 0) sc[t] = p;
    }
    __syncthreads();
    if (tid < 64) {
        const float x = (tid < T) ? sc[tid] : -3.4e38f;
        float mx = x;
#pragma unroll
        for (int off = 32; off > 0; off >>= 1) mx = fmaxf(mx, __shfl_xor(mx, off));
        const float ex = (tid < T) ? expf(x - mx) : 0.f;
        float sm = ex;
#pragma unroll
        for (int off = 32; off > 0; off >>= 1) sm += __shfl_xor(sm, off);
        aw[tid] = ex / sm;
    }
    __syncthreads();
    for (int k = tid; k < H_; k += 512) {
        float c = 0.f;
        for (int t = 0; t < T; ++t)
            c += aw[t] * enc[((size_t)t * B_ + b) * H_ + k];
        ctx[(size_t)b * H_ + k] = c;
    }
}

// ---------------------------------------------------------------------------
__global__ __launch_bounds__(512)
void u_prep_scatter2(const float* __restrict__ UCt, const float* __restrict__ hn,
                     const int* __restrict__ slot_np,
                     float* __restrict__ mS, float* __restrict__ extra)
{
    const int b    = blockIdx.x;
    const int tid  = threadIdx.x;
    const int wave = tid >> 6;
    const int lane = tid & 63;
    __shared__ float su[64];
    __shared__ float eu_s[64];

    const float* h = hn + (size_t)b * H_;
    for (int t = wave; t < TS_; t += 8) {
        const float* r = UCt + ((size_t)t * B_ + b) * H_;
        float p = 0.f;
        for (int j = lane; j < H_; j += 64)
            p += r[j] * h[j];
#pragma unroll
        for (int off = 32; off > 0; off >>= 1) p += __shfl_down(p, off);
        if (lane == 0) su[t] = p;
    }
    __syncthreads();
    if (tid < 64) {
        const float x = (tid < TS_) ? su[tid] : -3.4e38f;
        float mx = x;
#pragma unroll
        for (int off = 32; off > 0; off >>= 1) mx = fmaxf(mx, __shfl_xor(mx, off));
        const float ex = (tid < TS_) ? expf(x - mx) : 0.f;
        float sm = ex;
#pragma unroll
        for (int off = 32; off > 0; off >>= 1) sm += __shfl_xor(sm, off);
        eu_s[tid] = ex;
        if (tid == 0) { mS[b * 2] = mx; mS[b * 2 + 1] = sm; }
    }
    __syncthreads();
    if (tid < TS_) {
        const int sv = slot_np[tid * B_ + b];
        const float e = eu_s[tid];
        const bool copy = (sv == 2) || (sv >= V_);
        const bool add  = (sv != 0) && !copy;
        if (add)  atomicAdd(&extra[(size_t)b * VTS + sv], e);
        if (copy) atomicAdd(&extra[(size_t)b * VTS + V_ + tid], 5.0f * e);
    }
}

// ---------------------------------------------------------------------------
__device__ __forceinline__ float blk_reduce(float v, float* red, int tid, bool ismax)
{
    red[tid] = v; __syncthreads();
    for (int s = 128; s > 0; s >>= 1) {
        if (tid < s) red[tid] = ismax ? fmaxf(red[tid], red[tid + s]) : (red[tid] + red[tid + s]);
        __syncthreads();
    }
    const float r = red[0]; __syncthreads();
    return r;
}

// ph_max2g: fused reduce_parts (gen = sum parts + b_proj) + slice max/expsum
// over gen (values held in registers) + extra slice max/sum.
__global__ __launch_bounds__(256)
void ph_max2g(const float* __restrict__ parts, const float* __restrict__ b_proj,
              const float* __restrict__ extra,
              float* __restrict__ gen,
              float* __restrict__ pgm, float* __restrict__ pzs,
              float* __restrict__ pem, float* __restrict__ pes)
{
    const int b = blockIdx.x, s = blockIdx.y, tid = threadIdx.x;
    __shared__ float red[256];
    const int g0 = s * GSL;

    float gv[16];
    float gm = -3.4e38f;
#pragma unroll
    for (int u = 0; u < 16; ++u) {
        const int loc = tid + 256 * u;
        float val = -3.4e38f;
        if (loc < GSL) {
            const int idx = g0 + loc;
            float ssum = 0.f;
#pragma unroll
            for (int ss = 0; ss < 6; ++ss)
                ssum += parts[((size_t)ss * B_ + b) * V_ + idx];
            val = ssum + b_proj[idx];
            gen[(size_t)b * V_ + idx] = val;
            gm = fmaxf(gm, val);
        }
        gv[u] = val;
    }
    gm = blk_reduce(gm, red, tid, true);
    float zs = 0.f;
#pragma unroll
    for (int u = 0; u < 16; ++u)
        zs += expf(gv[u] - gm);                 // -3.4e38 rows contribute 0
    zs = blk_reduce(zs, red, tid, false);

    const float* ex = extra + (size_t)b * VTS;
    const int e0 = s * SLE;
    const int e1 = (e0 + SLE < VTS) ? e0 + SLE : VTS;
    float em = 0.f, es = 0.f;
    for (int i = e0 + tid; i < e1; i += 256) { const float v = ex[i]; em = fmaxf(em, v); es += v; }
    em = blk_reduce(em, red, tid, true);
    es = blk_reduce(es, red, tid, false);
    if (tid == 0) {
        pgm[b * NS + s] = gm; pzs[b * NS + s] = zs;
        pem[b * NS + s] = em; pes[b * NS + s] = es;
    }
}

__global__ __launch_bounds__(256)
void ph_write2(const float* __restrict__ gen, const float* __restrict__ extra,
               const float* __restrict__ pgm, const float* __restrict__ pzs,
               const float* __restrict__ pem, const float* __restrict__ pes,
               const float* __restrict__ mS, float* __restrict__ proba)
{
    const int b = blockIdx.x, s = blockIdx.y, tid = threadIdx.x;
    const float mb   = mS[b * 2];
    const float Sb   = mS[b * 2 + 1];
    const float base = 1e-10f * Sb;

    float gm = -3.4e38f, em = 0.f;
#pragma unroll
    for (int k = 0; k < NS; ++k) {
        gm = fmaxf(gm, pgm[b * NS + k]);
        em = fmaxf(em, pem[b * NS + k]);
    }
    const float M = fmaxf(gm, mb + logf(base + em));
    float s1 = 0.f, s2 = 0.f;
#pragma unroll
    for (int k = 0; k < NS; ++k) {
        s1 += pzs[b * NS + k] * expf(pgm[b * NS + k] - M);
        s2 += pes[b * NS + k];
    }
    const float cs  = expf(mb - M);
    const float inv = 1.f / (s1 + cs * (base * VTS + s2));

    const float* g  = gen + (size_t)b * V_;
    const float* ex = extra + (size_t)b * VTS;
    float* o = proba + (size_t)b * VTS;
    const int e0 = s * SLE;
    const int e1 = (e0 + SLE < VTS) ? e0 + SLE : VTS;
    for (int i = e0 + tid; i < e1; i += 256) {
        const float cp = cs * (base + ex[i]) * inv;
        o[i] = (i < V_) ? (expf(g[i] - M) * inv + cp) : cp;
    }
}

// ---------------------------------------------------------------------------
extern "C" void kernel_launch(void* const* d_in, const int* in_sizes, int n_in,
                              void* d_out, int out_size, void* d_ws, size_t ws_size,
                              hipStream_t stream)
{
    const float* slot_enc = (const float*)d_in[0];
    const float* pers_enc = (const float*)d_in[1];
    const float* hid      = (const float*)d_in[2];
    const int*   mt       = (const int*)d_in[3];
    const int*   slot_np  = (const int*)d_in[4];
    // d_in[5] sparse_u_input: reconstructed from slot_np (205 MB skipped)
    const float* emb      = (const float*)d_in[6];
    const float* W_attn_a = (const float*)d_in[7];
    const float* b_attn_a = (const float*)d_in[8];
    const float* v_a      = (const float*)d_in[9];
    const float* W_attn_p = (const float*)d_in[10];
    const float* b_attn_p = (const float*)d_in[11];
    const float* v_p      = (const float*)d_in[12];
    const float* W_ih     = (const float*)d_in[13];
    const float* W_hh     = (const float*)d_in[14];
    const float* b_ih     = (const float*)d_in[15];
    const float* b_hh     = (const float*)d_in[16];
    const float* W_proj   = (const float*)d_in[17];
    const float* b_proj   = (const float*)d_in[18];
    const float* W_c2     = (const float*)d_in[19];
    const float* b_c2     = (const float*)d_in[20];
    float* out = (float*)d_out;

    float* w = (float*)d_ws;
    size_t off = 0;
    auto alloc = [&](size_t n) { float* p = w + off; off += n; return p; };
    float* SA    = alloc((size_t)TS_ * B_ * H_);
    float* SP    = alloc((size_t)TP_ * B_ * H_);
    float* UCt   = alloc((size_t)TS_ * B_ * H_);
    float* ctxa  = alloc((size_t)B_ * H_);
    float* ctxp  = alloc((size_t)B_ * H_);
    float* gx    = alloc((size_t)B_ * E_);
    float* hnew  = alloc((size_t)B_ * H_);
    float* gen   = alloc((size_t)B_ * V_);
    float* mS    = alloc((size_t)2 * B_);
    float* extra = alloc((size_t)B_ * VTS);
    float* pgm   = alloc((size_t)B_ * NS);
    float* pzs   = alloc((size_t)B_ * NS);
    float* pem   = alloc((size_t)B_ * NS);
    float* pes   = alloc((size_t)B_ * NS);
    float* parts = w + off;

    const int o2 = B_ * VTS;
    const int o3 = o2 + B_ * H_;

    // 1. zero extra + gather embedding
    zero_gather<<<(B_ * VTS + 255) / 256, 256, 0, stream>>>(extra, emb, mt, gx);

    // 2. hidden projections -> parts[0..8)
    gemm_hid<<<dim3(4, 4, 2), 256, 0, stream>>>(hid, W_attn_a, W_attn_p, parts);

    // 3. encoder projections fused with ha-add + tanh(+*v) epilogues
    gemm_tall84<<<dim3(25, 8, 3), 256, 0, stream>>>(
        slot_enc, pers_enc, W_attn_a, W_attn_p, W_c2,
        b_attn_a, b_attn_p, b_c2, v_a, v_p, parts, SA, SP, UCt);

    // 4. attention contexts
    attn_fused2<<<dim3(B_, 2), 512, 0, stream>>>(SA, SP, slot_enc, pers_enc, ctxa, ctxp);

    // 5/6. GRU
    gemm_gru<<<dim3(12, 14), 256, 0, stream>>>(gx, ctxa, ctxp, hid, W_ih, W_hh, parts);
    reduce_gru<<<(B_ * H_ + 255) / 256, 256, 0, stream>>>(parts, b_ih, b_hh, hid, hnew, out + o2, out + o3);

    // 7. vocab projection -> parts[0..6)
    gemm_proj<<<dim3(125, 6), 256, 0, stream>>>(ctxa, ctxp, hnew, W_proj, parts);

    // 8. copy scores + scatter
    u_prep_scatter2<<<B_, 512, 0, stream>>>(UCt, hnew, slot_np, mS, extra);

    // 9/10. joint softmax (gen materialized from parts inside ph_max2g)
    ph_max2g<<<dim3(B_, NS), 256, 0, stream>>>(parts, b_proj, extra, gen, pgm, pzs, pem, pes);
    ph_write2<<<dim3(B_, NS), 256, 0, stream>>>(gen, extra, pgm, pzs, pem, pes, mS, out);
}

// Round 8
// 471.220 us; speedup vs baseline: 1.6253x; 1.0225x over previous
//
#include <hip/hip_runtime.h>
#include <math.h>

static constexpr int V_   = 32000;
static constexpr int E_   = 512;
static constexpr int H_   = 1024;
static constexpr int B_   = 32;
static constexpr int TS_  = 50;
static constexpr int TP_  = 32;
static constexpr int VTS  = V_ + TS_;     // 32050
static constexpr int H3   = 3 * H_;       // 3072
static constexpr int GIN_ = E_ + 2 * H_;  // 2560
static constexpr int NS   = 8;            // softmax slices
static constexpr int SLE  = (VTS + NS - 1) / NS;  // 4007
static constexpr int GSL  = V_ / NS;      // 4000 gen cols per slice
static constexpr int PSK  = 12;           // proj K-slices

// ---------------------------------------------------------------------------
__global__ void zero_gather(float* __restrict__ extra,
                            const float* __restrict__ emb,
                            const int* __restrict__ mt,
                            float* __restrict__ gx)
{
    const int i = blockIdx.x * 256 + threadIdx.x;
    if (i < B_ * VTS) extra[i] = 0.f;
    if (i < B_ * E_) gx[i] = emb[(size_t)mt[i >> 9] * E_ + (i & 511)];
}

// ---------------------------------------------------------------------------
// m32v2 tile core with register double-buffer: 32m x 256n, KC=32, 4 waves.
// Next KC's global loads are issued right after the stage barrier so HBM
// latency hides under the 2048-cycle FMA burst (matters at ~3 blocks/CU).
// ---------------------------------------------------------------------------
__device__ __forceinline__ void m32v2_tile(
    const float* __restrict__ A, int lda,
    const float* __restrict__ W, int ldw, int wko,
    int klen, int n0, float* __restrict__ po, int N)
{
    __shared__ float As[32][36];
    __shared__ float Ws[32][257];

    const int tid  = threadIdx.x;
    const int lane = tid & 63;
    const int wv   = tid >> 6;
    const int wq   = lane & 7;
    const int wg   = lane >> 3;
    const int am   = tid >> 3;
    const int aq   = tid & 7;

    float acc[8][4];
#pragma unroll
    for (int i = 0; i < 8; ++i)
#pragma unroll
        for (int j = 0; j < 4; ++j) acc[i][j] = 0.f;

    float4 a4 = *reinterpret_cast<const float4*>(A + (size_t)am * lda + 4 * aq);
    float4 w4[8];
#pragma unroll
    for (int i = 0; i < 8; ++i)
        w4[i] = *reinterpret_cast<const float4*>(
            W + (size_t)(n0 + wv * 64 + i * 8 + wg) * ldw + wko + 4 * wq);

    for (int kb = 0; kb < klen; kb += 32) {
        __syncthreads();                       // previous compute done
        As[4 * aq + 0][am] = a4.x; As[4 * aq + 1][am] = a4.y;
        As[4 * aq + 2][am] = a4.z; As[4 * aq + 3][am] = a4.w;
#pragma unroll
        for (int i = 0; i < 8; ++i) {
            const int col = wv * 64 + i * 8 + wg;
            Ws[4 * wq + 0][col] = w4[i].x; Ws[4 * wq + 1][col] = w4[i].y;
            Ws[4 * wq + 2][col] = w4[i].z; Ws[4 * wq + 3][col] = w4[i].w;
        }
        __syncthreads();
        if (kb + 32 < klen) {                  // prefetch next KC under compute
            a4 = *reinterpret_cast<const float4*>(A + (size_t)am * lda + kb + 32 + 4 * aq);
#pragma unroll
            for (int i = 0; i < 8; ++i)
                w4[i] = *reinterpret_cast<const float4*>(
                    W + (size_t)(n0 + wv * 64 + i * 8 + wg) * ldw + wko + kb + 32 + 4 * wq);
        }
#pragma unroll 8
        for (int k = 0; k < 32; ++k) {
            const float4 a0 = *reinterpret_cast<const float4*>(&As[k][wv * 8]);
            const float4 a1 = *reinterpret_cast<const float4*>(&As[k][wv * 8 + 4]);
            const float av[8] = {a0.x, a0.y, a0.z, a0.w, a1.x, a1.y, a1.z, a1.w};
            const float w0 = Ws[k][lane];
            const float w1 = Ws[k][lane + 64];
            const float w2 = Ws[k][lane + 128];
            const float w3 = Ws[k][lane + 192];
#pragma unroll
            for (int i = 0; i < 8; ++i) {
                acc[i][0] = fmaf(av[i], w0, acc[i][0]);
                acc[i][1] = fmaf(av[i], w1, acc[i][1]);
                acc[i][2] = fmaf(av[i], w2, acc[i][2]);
                acc[i][3] = fmaf(av[i], w3, acc[i][3]);
            }
        }
    }
#pragma unroll
    for (int i = 0; i < 8; ++i) {
        float* op = po + (size_t)(wv * 8 + i) * N + n0;
#pragma unroll
        for (int j = 0; j < 4; ++j)
            op[lane + 64 * j] = acc[i][j];
    }
}

__global__ __launch_bounds__(256)
void gemm_hid(const float* __restrict__ hid,
              const float* __restrict__ Wa, const float* __restrict__ Wp,
              float* __restrict__ parts)
{
    const int z = blockIdx.z, y = blockIdx.y, n0 = blockIdx.x * 256;
    const float* W = z ? Wp : Wa;
    m32v2_tile(hid + y * 256, H_, W, 2 * H_, y * 256, 256, n0,
               parts + (size_t)(z * 4 + y) * B_ * H_, H_);
}

__global__ __launch_bounds__(256)
void gemm_gru(const float* __restrict__ gx, const float* __restrict__ ctxa,
              const float* __restrict__ ctxp, const float* __restrict__ hid,
              const float* __restrict__ W_ih, const float* __restrict__ W_hh,
              float* __restrict__ parts)
{
    const int y = blockIdx.y, n0 = blockIdx.x * 256;
    const float* A; int lda; const float* W; int ldw; int wko; int klo;
    if (y < 2)       { klo = y * 256;        A = gx;   lda = E_; W = W_ih; ldw = GIN_; wko = klo; }
    else if (y < 6)  { klo = (y - 2) * 256;  A = ctxa; lda = H_; W = W_ih; ldw = GIN_; wko = 512 + klo; }
    else if (y < 10) { klo = (y - 6) * 256;  A = ctxp; lda = H_; W = W_ih; ldw = GIN_; wko = 1536 + klo; }
    else             { klo = (y - 10) * 256; A = hid;  lda = H_; W = W_hh; ldw = H_;   wko = klo; }
    m32v2_tile(A + klo, lda, W, ldw, wko, 256, n0,
               parts + (size_t)y * B_ * H3, H3);
}

__global__ void reduce_gru(const float* __restrict__ parts,
                           const float* __restrict__ b_ih, const float* __restrict__ b_hh,
                           const float* __restrict__ hid,
                           float* __restrict__ hnew,
                           float* __restrict__ o2, float* __restrict__ o3)
{
    const int i = blockIdx.x * 256 + threadIdx.x;
    if (i >= B_ * H_) return;
    const int b = i >> 10, j = i & 1023;
    float gi[3], gh[3];
#pragma unroll
    for (int c = 0; c < 3; ++c) {
        float s = b_ih[c * H_ + j];
        for (int y = 0; y < 10; ++y)
            s += parts[((size_t)y * B_ + b) * H3 + c * H_ + j];
        gi[c] = s;
        float t = b_hh[c * H_ + j];
        for (int y = 10; y < 14; ++y)
            t += parts[((size_t)y * B_ + b) * H3 + c * H_ + j];
        gh[c] = t;
    }
    const float r = 1.f / (1.f + expf(-(gi[0] + gh[0])));
    const float z = 1.f / (1.f + expf(-(gi[1] + gh[1])));
    const float n = tanhf(gi[2] + r * gh[2]);
    const float o = (1.f - z) * n + z * hid[i];
    hnew[i] = o; o2[i] = o; o3[i] = o;
}

// proj: 12 K-slices of 256 (3 A-sources x 4 quarters) -> 1500 blocks
__global__ __launch_bounds__(256)
void gemm_proj(const float* __restrict__ ctxa, const float* __restrict__ ctxp,
               const float* __restrict__ hnew, const float* __restrict__ W_proj,
               float* __restrict__ parts)
{
    const int y = blockIdx.y, n0 = blockIdx.x * 256;
    const int slice = y >> 2, kq = y & 3;
    const float* A = (slice == 0) ? ctxa : (slice == 1) ? ctxp : hnew;
    m32v2_tile(A + kq * 256, H_, W_proj, H3, slice * 1024 + kq * 256,
               256, n0, parts + (size_t)y * B_ * V_, V_);
}

// ---------------------------------------------------------------------------
// gemm_tall84 (R7-proven) + register double-buffer prefetch.
// ---------------------------------------------------------------------------
__global__ __launch_bounds__(256)
void gemm_tall84(const float* __restrict__ slot_enc, const float* __restrict__ pers_enc,
                 const float* __restrict__ W_attn_a, const float* __restrict__ W_attn_p,
                 const float* __restrict__ W_c2,
                 const float* __restrict__ b_attn_a, const float* __restrict__ b_attn_p,
                 const float* __restrict__ b_c2,
                 const float* __restrict__ v_a, const float* __restrict__ v_p,
                 const float* __restrict__ parts,
                 float* __restrict__ SA, float* __restrict__ SP, float* __restrict__ UCt)
{
    __shared__ float As[32][68];
    __shared__ float Ws[32][132];
    const int z = blockIdx.z;
    const float* A; const float* W; float* C; int M, ldw;
    if (z == 0)      { A = slot_enc; W = W_attn_a + H_; C = SA;  M = TS_ * B_; ldw = 2 * H_; }
    else if (z == 1) { A = pers_enc; W = W_attn_p + H_; C = SP;  M = TP_ * B_; ldw = 2 * H_; }
    else             { A = slot_enc; W = W_c2;          C = UCt; M = TS_ * B_; ldw = H_; }
    const int m0 = blockIdx.x * 64;
    if (m0 >= M) return;
    const int n0 = blockIdx.y * 128;
    const int tid = threadIdx.x;
    const int tym = tid >> 5;
    const int txn = tid & 31;
    const int sr = tid & 63, sh = tid >> 6;
    const int wr = tid & 127, wh = tid >> 7;

    float acc[8][4];
#pragma unroll
    for (int i = 0; i < 8; ++i)
#pragma unroll
        for (int j = 0; j < 4; ++j) acc[i][j] = 0.f;

    float4 a4[2], w4[4];
#pragma unroll
    for (int q = 0; q < 2; ++q)
        a4[q] = *reinterpret_cast<const float4*>(A + (size_t)(m0 + sr) * H_ + 8 * sh + 4 * q);
#pragma unroll
    for (int q = 0; q < 4; ++q)
        w4[q] = *reinterpret_cast<const float4*>(W + (size_t)(n0 + wr) * ldw + 16 * wh + 4 * q);

    for (int kb = 0; kb < H_; kb += 32) {
        __syncthreads();
#pragma unroll
        for (int q = 0; q < 2; ++q) {
            As[8 * sh + 4 * q + 0][sr] = a4[q].x; As[8 * sh + 4 * q + 1][sr] = a4[q].y;
            As[8 * sh + 4 * q + 2][sr] = a4[q].z; As[8 * sh + 4 * q + 3][sr] = a4[q].w;
        }
#pragma unroll
        for (int q = 0; q < 4; ++q) {
            Ws[16 * wh + 4 * q + 0][wr] = w4[q].x; Ws[16 * wh + 4 * q + 1][wr] = w4[q].y;
            Ws[16 * wh + 4 * q + 2][wr] = w4[q].z; Ws[16 * wh + 4 * q + 3][wr] = w4[q].w;
        }
        __syncthreads();
        if (kb + 32 < H_) {
#pragma unroll
            for (int q = 0; q < 2; ++q)
                a4[q] = *reinterpret_cast<const float4*>(A + (size_t)(m0 + sr) * H_ + kb + 32 + 8 * sh + 4 * q);
#pragma unroll
            for (int q = 0; q < 4; ++q)
                w4[q] = *reinterpret_cast<const float4*>(W + (size_t)(n0 + wr) * ldw + kb + 32 + 16 * wh + 4 * q);
        }
#pragma unroll 8
        for (int k = 0; k < 32; ++k) {
            const float4 a0 = *reinterpret_cast<const float4*>(&As[k][8 * tym]);
            const float4 a1 = *reinterpret_cast<const float4*>(&As[k][8 * tym + 4]);
            const float av[8] = {a0.x, a0.y, a0.z, a0.w, a1.x, a1.y, a1.z, a1.w};
            const float w0 = Ws[k][txn];
            const float w1 = Ws[k][txn + 32];
            const float w2 = Ws[k][txn + 64];
            const float w3 = Ws[k][txn + 96];
#pragma unroll
            for (int i = 0; i < 8; ++i) {
                acc[i][0] = fmaf(av[i], w0, acc[i][0]);
                acc[i][1] = fmaf(av[i], w1, acc[i][1]);
                acc[i][2] = fmaf(av[i], w2, acc[i][2]);
                acc[i][3] = fmaf(av[i], w3, acc[i][3]);
            }
        }
    }

    if (z < 2) {
        const float* bvec = z ? b_attn_p : b_attn_a;
        const float* vvec = z ? v_p : v_a;
        const float* pp = parts + (size_t)(z * 4) * B_ * H_;
#pragma unroll
        for (int i = 0; i < 8; ++i) {
            const int row = m0 + 8 * tym + i;
            const int b = row & 31;
#pragma unroll
            for (int j = 0; j < 4; ++j) {
                const int col = n0 + txn + 32 * j;
                float ha = bvec[col];
#pragma unroll
                for (int ss = 0; ss < 4; ++ss)
                    ha += pp[((size_t)ss * B_ + b) * H_ + col];
                C[(size_t)row * H_ + col] = tanhf(acc[i][j] + ha) * vvec[col];
            }
        }
    } else {
#pragma unroll
        for (int i = 0; i < 8; ++i) {
            const int row = m0 + 8 * tym + i;
#pragma unroll
            for (int j = 0; j < 4; ++j) {
                const int col = n0 + txn + 32 * j;
                C[(size_t)row * H_ + col] = tanhf(acc[i][j] + b_c2[col]);
            }
        }
    }
}

// ---------------------------------------------------------------------------
__global__ __launch_bounds__(512)
void attn_fused2(const float* __restrict__ SA, const float* __restrict__ SP,
                 const float* __restrict__ slot_enc, const float* __restrict__ pers_enc,
                 float* __restrict__ ctxa, float* __restrict__ ctxp)
{
    const int b = blockIdx.x, z = blockIdx.y;
    const int T = z ? TP_ : TS_;
    const float* S   = z ? SP : SA;
    const float* enc = z ? pers_enc : slot_enc;
    float* ctx       = z ? ctxp : ctxa;

    const int tid  = threadIdx.x;
    const int wave = tid >> 6;
    const int lane = tid & 63;
    __shared__ float sc[64];
    __shared__ float aw[64];

    for (int t = wave; t < T; t += 8) {
        const float* e = S + ((size_t)t * B_ + b) * H_;
        float p = 0.f;
        for (int j = lane; j < H_; j += 64) p += e[j];
#pragma unroll
        for (int off = 32; off > 0; off >>= 1) p += __shfl_down(p, off);
        if (lane == 0) sc[t] = p;
    }
    __syncthreads();
    if (tid < 64) {
        const float x = (tid < T) ? sc[tid] : -3.4e38f;
        float mx = x;
#pragma unroll
        for (int off = 32; off > 0; off >>= 1) mx = fmaxf(mx, __shfl_xor(mx, off));
        const float ex = (tid < T) ? expf(x - mx) : 0.f;
        float sm = ex;
#pragma unroll
        for (int off = 32; off > 0; off >>= 1) sm += __shfl_xor(sm, off);
        aw[tid] = ex / sm;
    }
    __syncthreads();
    for (int k = tid; k < H_; k += 512) {
        float c = 0.f;
        for (int t = 0; t < T; ++t)
            c += aw[t] * enc[((size_t)t * B_ + b) * H_ + k];
        ctx[(size_t)b * H_ + k] = c;
    }
}

// ---------------------------------------------------------------------------
__global__ __launch_bounds__(512)
void u_prep_scatter2(const float* __restrict__ UCt, const float* __restrict__ hn,
                     const int* __restrict__ slot_np,
                     float* __restrict__ mS, float* __restrict__ extra)
{
    const int b    = blockIdx.x;
    const int tid  = threadIdx.x;
    const int wave = tid >> 6;
    const int lane = tid & 63;
    __shared__ float su[64];
    __shared__ float eu_s[64];

    const float* h = hn + (size_t)b * H_;
    for (int t = wave; t < TS_; t += 8) {
        const float* r = UCt + ((size_t)t * B_ + b) * H_;
        float p = 0.f;
        for (int j = lane; j < H_; j += 64)
            p += r[j] * h[j];
#pragma unroll
        for (int off = 32; off > 0; off >>= 1) p += __shfl_down(p, off);
        if (lane == 0) su[t] = p;
    }
    __syncthreads();
    if (tid < 64) {
        const float x = (tid < TS_) ? su[tid] : -3.4e38f;
        float mx = x;
#pragma unroll
        for (int off = 32; off > 0; off >>= 1) mx = fmaxf(mx, __shfl_xor(mx, off));
        const float ex = (tid < TS_) ? expf(x - mx) : 0.f;
        float sm = ex;
#pragma unroll
        for (int off = 32; off > 0; off >>= 1) sm += __shfl_xor(sm, off);
        eu_s[tid] = ex;
        if (tid == 0) { mS[b * 2] = mx; mS[b * 2 + 1] = sm; }
    }
    __syncthreads();
    if (tid < TS_) {
        const int sv = slot_np[tid * B_ + b];
        const float e = eu_s[tid];
        const bool copy = (sv == 2) || (sv >= V_);
        const bool add  = (sv != 0) && !copy;
        if (add)  atomicAdd(&extra[(size_t)b * VTS + sv], e);
        if (copy) atomicAdd(&extra[(size_t)b * VTS + V_ + tid], 5.0f * e);
    }
}

// ---------------------------------------------------------------------------
__device__ __forceinline__ float blk_reduce(float v, float* red, int tid, bool ismax)
{
    red[tid] = v; __syncthreads();
    for (int s = 128; s > 0; s >>= 1) {
        if (tid < s) red[tid] = ismax ? fmaxf(red[tid], red[tid + s]) : (red[tid] + red[tid + s]);
        __syncthreads();
    }
    const float r = red[0]; __syncthreads();
    return r;
}

__global__ __launch_bounds__(256)
void ph_max2g(const float* __restrict__ parts, const float* __restrict__ b_proj,
              const float* __restrict__ extra,
              float* __restrict__ gen,
              float* __restrict__ pgm, float* __restrict__ pzs,
              float* __restrict__ pem, float* __restrict__ pes)
{
    const int b = blockIdx.x, s = blockIdx.y, tid = threadIdx.x;
    __shared__ float red[256];
    const int g0 = s * GSL;

    float gv[16];
    float gm = -3.4e38f;
#pragma unroll
    for (int u = 0; u < 16; ++u) {
        const int loc = tid + 256 * u;
        float val = -3.4e38f;
        if (loc < GSL) {
            const int idx = g0 + loc;
            float ssum = 0.f;
#pragma unroll
            for (int ss = 0; ss < PSK; ++ss)
                ssum += parts[((size_t)ss * B_ + b) * V_ + idx];
            val = ssum + b_proj[idx];
            gen[(size_t)b * V_ + idx] = val;
            gm = fmaxf(gm, val);
        }
        gv[u] = val;
    }
    gm = blk_reduce(gm, red, tid, true);
    float zs = 0.f;
#pragma unroll
    for (int u = 0; u < 16; ++u)
        zs += expf(gv[u] - gm);
    zs = blk_reduce(zs, red, tid, false);

    const float* ex = extra + (size_t)b * VTS;
    const int e0 = s * SLE;
    const int e1 = (e0 + SLE < VTS) ? e0 + SLE : VTS;
    float em = 0.f, es = 0.f;
    for (int i = e0 + tid; i < e1; i += 256) { const float v = ex[i]; em = fmaxf(em, v); es += v; }
    em = blk_reduce(em, red, tid, true);
    es = blk_reduce(es, red, tid, false);
    if (tid == 0) {
        pgm[b * NS + s] = gm; pzs[b * NS + s] = zs;
        pem[b * NS + s] = em; pes[b * NS + s] = es;
    }
}

__global__ __launch_bounds__(256)
void ph_write2(const float* __restrict__ gen, const float* __restrict__ extra,
               const float* __restrict__ pgm, const float* __restrict__ pzs,
               const float* __restrict__ pem, const float* __restrict__ pes,
               const float* __restrict__ mS, float* __restrict__ proba)
{
    const int b = blockIdx.x, s = blockIdx.y, tid = threadIdx.x;
    const float mb   = mS[b * 2];
    const float Sb   = mS[b * 2 + 1];
    const float base = 1e-10f * Sb;

    float gm = -3.4e38f, em = 0.f;
#pragma unroll
    for (int k = 0; k < NS; ++k) {
        gm = fmaxf(gm, pgm[b * NS + k]);
        em = fmaxf(em, pem[b * NS + k]);
    }
    const float M = fmaxf(gm, mb + logf(base + em));
    float s1 = 0.f, s2 = 0.f;
#pragma unroll
    for (int k = 0; k < NS; ++k) {
        s1 += pzs[b * NS + k] * expf(pgm[b * NS + k] - M);
        s2 += pes[b * NS + k];
    }
    const float cs  = expf(mb - M);
    const float inv = 1.f / (s1 + cs * (base * VTS + s2));

    const float* g  = gen + (size_t)b * V_;
    const float* ex = extra + (size_t)b * VTS;
    float* o = proba + (size_t)b * VTS;
    const int e0 = s * SLE;
    const int e1 = (e0 + SLE < VTS) ? e0 + SLE : VTS;
    for (int i = e0 + tid; i < e1; i += 256) {
        const float cp = cs * (base + ex[i]) * inv;
        o[i] = (i < V_) ? (expf(g[i] - M) * inv + cp) : cp;
    }
}

// ---------------------------------------------------------------------------
extern "C" void kernel_launch(void* const* d_in, const int* in_sizes, int n_in,
                              void* d_out, int out_size, void* d_ws, size_t ws_size,
                              hipStream_t stream)
{
    const float* slot_enc = (const float*)d_in[0];
    const float* pers_enc = (const float*)d_in[1];
    const float* hid      = (const float*)d_in[2];
    const int*   mt       = (const int*)d_in[3];
    const int*   slot_np  = (const int*)d_in[4];
    // d_in[5] sparse_u_input: reconstructed from slot_np (205 MB skipped)
    const float* emb      = (const float*)d_in[6];
    const float* W_attn_a = (const float*)d_in[7];
    const float* b_attn_a = (const float*)d_in[8];
    const float* v_a      = (const float*)d_in[9];
    const float* W_attn_p = (const float*)d_in[10];
    const float* b_attn_p = (const float*)d_in[11];
    const float* v_p      = (const float*)d_in[12];
    const float* W_ih     = (const float*)d_in[13];
    const float* W_hh     = (const float*)d_in[14];
    const float* b_ih     = (const float*)d_in[15];
    const float* b_hh     = (const float*)d_in[16];
    const float* W_proj   = (const float*)d_in[17];
    const float* b_proj   = (const float*)d_in[18];
    const float* W_c2     = (const float*)d_in[19];
    const float* b_c2     = (const float*)d_in[20];
    float* out = (float*)d_out;

    float* w = (float*)d_ws;
    size_t off = 0;
    auto alloc = [&](size_t n) { float* p = w + off; off += n; return p; };
    float* SA    = alloc((size_t)TS_ * B_ * H_);
    float* SP    = alloc((size_t)TP_ * B_ * H_);
    float* UCt   = alloc((size_t)TS_ * B_ * H_);
    float* ctxa  = alloc((size_t)B_ * H_);
    float* ctxp  = alloc((size_t)B_ * H_);
    float* gx    = alloc((size_t)B_ * E_);
    float* hnew  = alloc((size_t)B_ * H_);
    float* gen   = alloc((size_t)B_ * V_);
    float* mS    = alloc((size_t)2 * B_);
    float* extra = alloc((size_t)B_ * VTS);
    float* pgm   = alloc((size_t)B_ * NS);
    float* pzs   = alloc((size_t)B_ * NS);
    float* pem   = alloc((size_t)B_ * NS);
    float* pes   = alloc((size_t)B_ * NS);
    float* parts = w + off;

    const int o2 = B_ * VTS;
    const int o3 = o2 + B_ * H_;

    // 1. zero extra + gather embedding
    zero_gather<<<(B_ * VTS + 255) / 256, 256, 0, stream>>>(extra, emb, mt, gx);

    // 2. hidden projections -> parts[0..8)
    gemm_hid<<<dim3(4, 4, 2), 256, 0, stream>>>(hid, W_attn_a, W_attn_p, parts);

    // 3. encoder projections fused with ha-add + tanh(+*v) epilogues
    gemm_tall84<<<dim3(25, 8, 3), 256, 0, stream>>>(
        slot_enc, pers_enc, W_attn_a, W_attn_p, W_c2,
        b_attn_a, b_attn_p, b_c2, v_a, v_p, parts, SA, SP, UCt);

    // 4. attention contexts
    attn_fused2<<<dim3(B_, 2), 512, 0, stream>>>(SA, SP, slot_enc, pers_enc, ctxa, ctxp);

    // 5/6. GRU
    gemm_gru<<<dim3(12, 14), 256, 0, stream>>>(gx, ctxa, ctxp, hid, W_ih, W_hh, parts);
    reduce_gru<<<(B_ * H_ + 255) / 256, 256, 0, stream>>>(parts, b_ih, b_hh, hid, hnew, out + o2, out + o3);

    // 7. vocab projection, 12 K-slices -> 1500 blocks
    gemm_proj<<<dim3(125, PSK), 256, 0, stream>>>(ctxa, ctxp, hnew, W_proj, parts);

    // 8. copy scores + scatter
    u_prep_scatter2<<<B_, 512, 0, stream>>>(UCt, hnew, slot_np, mS, extra);

    // 9/10. joint softmax
    ph_max2g<<<dim3(B_, NS), 256, 0, stream>>>(parts, b_proj, extra, gen, pgm, pzs, pem, pes);
    ph_write2<<<dim3(B_, NS), 256, 0, stream>>>(gen, extra, pgm, pzs, pem, pes, mS, out);
}

// Round 9
// 403.664 us; speedup vs baseline: 1.8973x; 1.1674x over previous
//
#include <hip/hip_runtime.h>
#include <math.h>

static constexpr int V_   = 32000;
static constexpr int E_   = 512;
static constexpr int H_   = 1024;
static constexpr int B_   = 32;
static constexpr int TS_  = 50;
static constexpr int TP_  = 32;
static constexpr int VTS  = V_ + TS_;     // 32050
static constexpr int H3   = 3 * H_;       // 3072
static constexpr int GIN_ = E_ + 2 * H_;  // 2560
static constexpr int NS   = 8;            // softmax slices
static constexpr int SLE  = (VTS + NS - 1) / NS;  // 4007
static constexpr int GSL  = V_ / NS;      // 4000 gen cols per slice
static constexpr int PSK  = 12;           // proj K-slices

// ---------------------------------------------------------------------------
__global__ void zero_gather(float* __restrict__ extra,
                            const float* __restrict__ emb,
                            const int* __restrict__ mt,
                            float* __restrict__ gx)
{
    const int i = blockIdx.x * 256 + threadIdx.x;
    if (i < B_ * VTS) extra[i] = 0.f;
    if (i < B_ * E_) gx[i] = emb[(size_t)mt[i >> 9] * E_ + (i & 511)];
}

// ---------------------------------------------------------------------------
// m32v2 tile core (R6-proven) + reg double-buffer (R8): 32m x 256n, KC=32.
// ---------------------------------------------------------------------------
__device__ __forceinline__ void m32v2_tile(
    const float* __restrict__ A, int lda,
    const float* __restrict__ W, int ldw, int wko,
    int klen, int n0, float* __restrict__ po, int N)
{
    __shared__ float As[32][36];
    __shared__ float Ws[32][257];

    const int tid  = threadIdx.x;
    const int lane = tid & 63;
    const int wv   = tid >> 6;
    const int wq   = lane & 7;
    const int wg   = lane >> 3;
    const int am   = tid >> 3;
    const int aq   = tid & 7;

    float acc[8][4];
#pragma unroll
    for (int i = 0; i < 8; ++i)
#pragma unroll
        for (int j = 0; j < 4; ++j) acc[i][j] = 0.f;

    float4 a4 = *reinterpret_cast<const float4*>(A + (size_t)am * lda + 4 * aq);
    float4 w4[8];
#pragma unroll
    for (int i = 0; i < 8; ++i)
        w4[i] = *reinterpret_cast<const float4*>(
            W + (size_t)(n0 + wv * 64 + i * 8 + wg) * ldw + wko + 4 * wq);

    for (int kb = 0; kb < klen; kb += 32) {
        __syncthreads();
        As[4 * aq + 0][am] = a4.x; As[4 * aq + 1][am] = a4.y;
        As[4 * aq + 2][am] = a4.z; As[4 * aq + 3][am] = a4.w;
#pragma unroll
        for (int i = 0; i < 8; ++i) {
            const int col = wv * 64 + i * 8 + wg;
            Ws[4 * wq + 0][col] = w4[i].x; Ws[4 * wq + 1][col] = w4[i].y;
            Ws[4 * wq + 2][col] = w4[i].z; Ws[4 * wq + 3][col] = w4[i].w;
        }
        __syncthreads();
        if (kb + 32 < klen) {
            a4 = *reinterpret_cast<const float4*>(A + (size_t)am * lda + kb + 32 + 4 * aq);
#pragma unroll
            for (int i = 0; i < 8; ++i)
                w4[i] = *reinterpret_cast<const float4*>(
                    W + (size_t)(n0 + wv * 64 + i * 8 + wg) * ldw + wko + kb + 32 + 4 * wq);
        }
#pragma unroll 8
        for (int k = 0; k < 32; ++k) {
            const float4 a0 = *reinterpret_cast<const float4*>(&As[k][wv * 8]);
            const float4 a1 = *reinterpret_cast<const float4*>(&As[k][wv * 8 + 4]);
            const float av[8] = {a0.x, a0.y, a0.z, a0.w, a1.x, a1.y, a1.z, a1.w};
            const float w0 = Ws[k][lane];
            const float w1 = Ws[k][lane + 64];
            const float w2 = Ws[k][lane + 128];
            const float w3 = Ws[k][lane + 192];
#pragma unroll
            for (int i = 0; i < 8; ++i) {
                acc[i][0] = fmaf(av[i], w0, acc[i][0]);
                acc[i][1] = fmaf(av[i], w1, acc[i][1]);
                acc[i][2] = fmaf(av[i], w2, acc[i][2]);
                acc[i][3] = fmaf(av[i], w3, acc[i][3]);
            }
        }
    }
#pragma unroll
    for (int i = 0; i < 8; ++i) {
        float* op = po + (size_t)(wv * 8 + i) * N + n0;
#pragma unroll
        for (int j = 0; j < 4; ++j)
            op[lane + 64 * j] = acc[i][j];
    }
}

__global__ __launch_bounds__(256)
void gemm_hid(const float* __restrict__ hid,
              const float* __restrict__ Wa, const float* __restrict__ Wp,
              float* __restrict__ parts)
{
    const int z = blockIdx.z, y = blockIdx.y, n0 = blockIdx.x * 256;
    const float* W = z ? Wp : Wa;
    m32v2_tile(hid + y * 256, H_, W, 2 * H_, y * 256, 256, n0,
               parts + (size_t)(z * 4 + y) * B_ * H_, H_);
}

// ---------------------------------------------------------------------------
// gemm_pcg: merged launch — proj K-slices 0..7 (ctxa/ctxp, no hnew dep;
// 1000 blocks) + all 14 GRU slices (168 blocks). GRU rides in the grid tail
// instead of a separate serialized launch.
// ---------------------------------------------------------------------------
__global__ __launch_bounds__(256)
void gemm_pcg(const float* __restrict__ ctxa, const float* __restrict__ ctxp,
              const float* __restrict__ hid, const float* __restrict__ gx,
              const float* __restrict__ W_proj,
              const float* __restrict__ W_ih, const float* __restrict__ W_hh,
              float* __restrict__ partsP, float* __restrict__ partsG)
{
    const int bid = blockIdx.x;
    if (bid < 1000) {
        const int y = bid / 125, n0 = (bid % 125) * 256;   // y in 0..7
        const int slice = y >> 2, kq = y & 3;              // slice 0=ctxa,1=ctxp
        const float* A = slice ? ctxp : ctxa;
        m32v2_tile(A + kq * 256, H_, W_proj, H3, slice * 1024 + kq * 256,
                   256, n0, partsP + (size_t)y * B_ * V_, V_);
    } else {
        const int idx = bid - 1000;
        const int y = idx / 12, n0 = (idx % 12) * 256;     // y in 0..13
        const float* A; int lda; const float* W; int ldw; int wko; int klo;
        if (y < 2)       { klo = y * 256;        A = gx;   lda = E_; W = W_ih; ldw = GIN_; wko = klo; }
        else if (y < 6)  { klo = (y - 2) * 256;  A = ctxa; lda = H_; W = W_ih; ldw = GIN_; wko = 512 + klo; }
        else if (y < 10) { klo = (y - 6) * 256;  A = ctxp; lda = H_; W = W_ih; ldw = GIN_; wko = 1536 + klo; }
        else             { klo = (y - 10) * 256; A = hid;  lda = H_; W = W_hh; ldw = H_;   wko = klo; }
        m32v2_tile(A + klo, lda, W, ldw, wko, 256, n0,
                   partsG + (size_t)y * B_ * H3, H3);
    }
}

// proj K-slices 8..11 (hnew source), after reduce_gru.
__global__ __launch_bounds__(256)
void gemm_projh(const float* __restrict__ hnew, const float* __restrict__ W_proj,
                float* __restrict__ partsP)
{
    const int y = blockIdx.y, n0 = blockIdx.x * 256;
    m32v2_tile(hnew + y * 256, H_, W_proj, H3, 2048 + y * 256,
               256, n0, partsP + (size_t)(8 + y) * B_ * V_, V_);
}

__global__ void reduce_gru(const float* __restrict__ parts,
                           const float* __restrict__ b_ih, const float* __restrict__ b_hh,
                           const float* __restrict__ hid,
                           float* __restrict__ hnew,
                           float* __restrict__ o2, float* __restrict__ o3)
{
    const int i = blockIdx.x * 256 + threadIdx.x;
    if (i >= B_ * H_) return;
    const int b = i >> 10, j = i & 1023;
    float gi[3], gh[3];
#pragma unroll
    for (int c = 0; c < 3; ++c) {
        float s = b_ih[c * H_ + j];
        for (int y = 0; y < 10; ++y)
            s += parts[((size_t)y * B_ + b) * H3 + c * H_ + j];
        gi[c] = s;
        float t = b_hh[c * H_ + j];
        for (int y = 10; y < 14; ++y)
            t += parts[((size_t)y * B_ + b) * H3 + c * H_ + j];
        gh[c] = t;
    }
    const float r = 1.f / (1.f + expf(-(gi[0] + gh[0])));
    const float z = 1.f / (1.f + expf(-(gi[1] + gh[1])));
    const float n = tanhf(gi[2] + r * gh[2]);
    const float o = (1.f - z) * n + z * hid[i];
    hnew[i] = o; o2[i] = o; o3[i] = o;
}

// ---------------------------------------------------------------------------
// gemm_tall84 (R7-proven) + reg double-buffer (R8).
// ---------------------------------------------------------------------------
__global__ __launch_bounds__(256)
void gemm_tall84(const float* __restrict__ slot_enc, const float* __restrict__ pers_enc,
                 const float* __restrict__ W_attn_a, const float* __restrict__ W_attn_p,
                 const float* __restrict__ W_c2,
                 const float* __restrict__ b_attn_a, const float* __restrict__ b_attn_p,
                 const float* __restrict__ b_c2,
                 const float* __restrict__ v_a, const float* __restrict__ v_p,
                 const float* __restrict__ parts,
                 float* __restrict__ SA, float* __restrict__ SP, float* __restrict__ UCt)
{
    __shared__ float As[32][68];
    __shared__ float Ws[32][132];
    const int z = blockIdx.z;
    const float* A; const float* W; float* C; int M, ldw;
    if (z == 0)      { A = slot_enc; W = W_attn_a + H_; C = SA;  M = TS_ * B_; ldw = 2 * H_; }
    else if (z == 1) { A = pers_enc; W = W_attn_p + H_; C = SP;  M = TP_ * B_; ldw = 2 * H_; }
    else             { A = slot_enc; W = W_c2;          C = UCt; M = TS_ * B_; ldw = H_; }
    const int m0 = blockIdx.x * 64;
    if (m0 >= M) return;
    const int n0 = blockIdx.y * 128;
    const int tid = threadIdx.x;
    const int tym = tid >> 5;
    const int txn = tid & 31;
    const int sr = tid & 63, sh = tid >> 6;
    const int wr = tid & 127, wh = tid >> 7;

    float acc[8][4];
#pragma unroll
    for (int i = 0; i < 8; ++i)
#pragma unroll
        for (int j = 0; j < 4; ++j) acc[i][j] = 0.f;

    float4 a4[2], w4[4];
#pragma unroll
    for (int q = 0; q < 2; ++q)
        a4[q] = *reinterpret_cast<const float4*>(A + (size_t)(m0 + sr) * H_ + 8 * sh + 4 * q);
#pragma unroll
    for (int q = 0; q < 4; ++q)
        w4[q] = *reinterpret_cast<const float4*>(W + (size_t)(n0 + wr) * ldw + 16 * wh + 4 * q);

    for (int kb = 0; kb < H_; kb += 32) {
        __syncthreads();
#pragma unroll
        for (int q = 0; q < 2; ++q) {
            As[8 * sh + 4 * q + 0][sr] = a4[q].x; As[8 * sh + 4 * q + 1][sr] = a4[q].y;
            As[8 * sh + 4 * q + 2][sr] = a4[q].z; As[8 * sh + 4 * q + 3][sr] = a4[q].w;
        }
#pragma unroll
        for (int q = 0; q < 4; ++q) {
            Ws[16 * wh + 4 * q + 0][wr] = w4[q].x; Ws[16 * wh + 4 * q + 1][wr] = w4[q].y;
            Ws[16 * wh + 4 * q + 2][wr] = w4[q].z; Ws[16 * wh + 4 * q + 3][wr] = w4[q].w;
        }
        __syncthreads();
        if (kb + 32 < H_) {
#pragma unroll
            for (int q = 0; q < 2; ++q)
                a4[q] = *reinterpret_cast<const float4*>(A + (size_t)(m0 + sr) * H_ + kb + 32 + 8 * sh + 4 * q);
#pragma unroll
            for (int q = 0; q < 4; ++q)
                w4[q] = *reinterpret_cast<const float4*>(W + (size_t)(n0 + wr) * ldw + kb + 32 + 16 * wh + 4 * q);
        }
#pragma unroll 8
        for (int k = 0; k < 32; ++k) {
            const float4 a0 = *reinterpret_cast<const float4*>(&As[k][8 * tym]);
            const float4 a1 = *reinterpret_cast<const float4*>(&As[k][8 * tym + 4]);
            const float av[8] = {a0.x, a0.y, a0.z, a0.w, a1.x, a1.y, a1.z, a1.w};
            const float w0 = Ws[k][txn];
            const float w1 = Ws[k][txn + 32];
            const float w2 = Ws[k][txn + 64];
            const float w3 = Ws[k][txn + 96];
#pragma unroll
            for (int i = 0; i < 8; ++i) {
                acc[i][0] = fmaf(av[i], w0, acc[i][0]);
                acc[i][1] = fmaf(av[i], w1, acc[i][1]);
                acc[i][2] = fmaf(av[i], w2, acc[i][2]);
                acc[i][3] = fmaf(av[i], w3, acc[i][3]);
            }
        }
    }

    if (z < 2) {
        const float* bvec = z ? b_attn_p : b_attn_a;
        const float* vvec = z ? v_p : v_a;
        const float* pp = parts + (size_t)(z * 4) * B_ * H_;
#pragma unroll
        for (int i = 0; i < 8; ++i) {
            const int row = m0 + 8 * tym + i;
            const int b = row & 31;
#pragma unroll
            for (int j = 0; j < 4; ++j) {
                const int col = n0 + txn + 32 * j;
                float ha = bvec[col];
#pragma unroll
                for (int ss = 0; ss < 4; ++ss)
                    ha += pp[((size_t)ss * B_ + b) * H_ + col];
                C[(size_t)row * H_ + col] = tanhf(acc[i][j] + ha) * vvec[col];
            }
        }
    } else {
#pragma unroll
        for (int i = 0; i < 8; ++i) {
            const int row = m0 + 8 * tym + i;
#pragma unroll
            for (int j = 0; j < 4; ++j) {
                const int col = n0 + txn + 32 * j;
                C[(size_t)row * H_ + col] = tanhf(acc[i][j] + b_c2[col]);
            }
        }
    }
}

// ---------------------------------------------------------------------------
// Attention with compile-time T (enables load pipelining in the ctx loop).
// ---------------------------------------------------------------------------
template <int T>
__device__ __forceinline__ void attn_body(const float* __restrict__ S,
                                          const float* __restrict__ enc,
                                          float* __restrict__ ctx, int b)
{
    const int tid  = threadIdx.x;
    const int wave = tid >> 6;
    const int lane = tid & 63;
    __shared__ float sc[64];
    __shared__ float aw[64];

    for (int t = wave; t < T; t += 8) {
        const float* e = S + ((size_t)t * B_ + b) * H_;
        float p = 0.f;
#pragma unroll
        for (int j = 0; j < H_ / 64; ++j) p += e[lane + 64 * j];
#pragma unroll
        for (int off = 32; off > 0; off >>= 1) p += __shfl_down(p, off);
        if (lane == 0) sc[t] = p;
    }
    __syncthreads();
    if (tid < 64) {
        const float x = (tid < T) ? sc[tid] : -3.4e38f;
        float mx = x;
#pragma unroll
        for (int off = 32; off > 0; off >>= 1) mx = fmaxf(mx, __shfl_xor(mx, off));
        const float ex = (tid < T) ? expf(x - mx) : 0.f;
        float sm = ex;
#pragma unroll
        for (int off = 32; off > 0; off >>= 1) sm += __shfl_xor(sm, off);
        aw[tid] = ex / sm;
    }
    __syncthreads();
    for (int k = tid; k < H_; k += 512) {
        float c = 0.f;
#pragma unroll 10
        for (int t = 0; t < T; ++t)
            c += aw[t] * enc[((size_t)t * B_ + b) * H_ + k];
        ctx[(size_t)b * H_ + k] = c;
    }
}

__global__ __launch_bounds__(512)
void attn_fused3(const float* __restrict__ SA, const float* __restrict__ SP,
                 const float* __restrict__ slot_enc, const float* __restrict__ pers_enc,
                 float* __restrict__ ctxa, float* __restrict__ ctxp)
{
    const int b = blockIdx.x;
    if (blockIdx.y == 0) attn_body<TS_>(SA, slot_enc, ctxa, b);
    else                 attn_body<TP_>(SP, pers_enc, ctxp, b);
}

// ---------------------------------------------------------------------------
__global__ __launch_bounds__(512)
void u_prep_scatter2(const float* __restrict__ UCt, const float* __restrict__ hn,
                     const int* __restrict__ slot_np,
                     float* __restrict__ mS, float* __restrict__ extra)
{
    const int b    = blockIdx.x;
    const int tid  = threadIdx.x;
    const int wave = tid >> 6;
    const int lane = tid & 63;
    __shared__ float su[64];
    __shared__ float eu_s[64];

    const float* h = hn + (size_t)b * H_;
    for (int t = wave; t < TS_; t += 8) {
        const float* r = UCt + ((size_t)t * B_ + b) * H_;
        float p = 0.f;
#pragma unroll
        for (int j = 0; j < H_ / 64; ++j)
            p += r[lane + 64 * j] * h[lane + 64 * j];
#pragma unroll
        for (int off = 32; off > 0; off >>= 1) p += __shfl_down(p, off);
        if (lane == 0) su[t] = p;
    }
    __syncthreads();
    if (tid < 64) {
        const float x = (tid < TS_) ? su[tid] : -3.4e38f;
        float mx = x;
#pragma unroll
        for (int off = 32; off > 0; off >>= 1) mx = fmaxf(mx, __shfl_xor(mx, off));
        const float ex = (tid < TS_) ? expf(x - mx) : 0.f;
        float sm = ex;
#pragma unroll
        for (int off = 32; off > 0; off >>= 1) sm += __shfl_xor(sm, off);
        eu_s[tid] = ex;
        if (tid == 0) { mS[b * 2] = mx; mS[b * 2 + 1] = sm; }
    }
    __syncthreads();
    if (tid < TS_) {
        const int sv = slot_np[tid * B_ + b];
        const float e = eu_s[tid];
        const bool copy = (sv == 2) || (sv >= V_);
        const bool add  = (sv != 0) && !copy;
        if (add)  atomicAdd(&extra[(size_t)b * VTS + sv], e);
        if (copy) atomicAdd(&extra[(size_t)b * VTS + V_ + tid], 5.0f * e);
    }
}

// ---------------------------------------------------------------------------
__device__ __forceinline__ float blk_reduce(float v, float* red, int tid, bool ismax)
{
    red[tid] = v; __syncthreads();
    for (int s = 128; s > 0; s >>= 1) {
        if (tid < s) red[tid] = ismax ? fmaxf(red[tid], red[tid + s]) : (red[tid] + red[tid + s]);
        __syncthreads();
    }
    const float r = red[0]; __syncthreads();
    return r;
}

__global__ __launch_bounds__(256)
void ph_max2g(const float* __restrict__ parts, const float* __restrict__ b_proj,
              const float* __restrict__ extra,
              float* __restrict__ gen,
              float* __restrict__ pgm, float* __restrict__ pzs,
              float* __restrict__ pem, float* __restrict__ pes)
{
    const int b = blockIdx.x, s = blockIdx.y, tid = threadIdx.x;
    __shared__ float red[256];
    const int g0 = s * GSL;

    float gv[16];
    float gm = -3.4e38f;
#pragma unroll
    for (int u = 0; u < 16; ++u) {
        const int loc = tid + 256 * u;
        float val = -3.4e38f;
        if (loc < GSL) {
            const int idx = g0 + loc;
            float ssum = 0.f;
#pragma unroll
            for (int ss = 0; ss < PSK; ++ss)
                ssum += parts[((size_t)ss * B_ + b) * V_ + idx];
            val = ssum + b_proj[idx];
            gen[(size_t)b * V_ + idx] = val;
            gm = fmaxf(gm, val);
        }
        gv[u] = val;
    }
    gm = blk_reduce(gm, red, tid, true);
    float zs = 0.f;
#pragma unroll
    for (int u = 0; u < 16; ++u)
        zs += expf(gv[u] - gm);
    zs = blk_reduce(zs, red, tid, false);

    const float* ex = extra + (size_t)b * VTS;
    const int e0 = s * SLE;
    const int e1 = (e0 + SLE < VTS) ? e0 + SLE : VTS;
    float em = 0.f, es = 0.f;
    for (int i = e0 + tid; i < e1; i += 256) { const float v = ex[i]; em = fmaxf(em, v); es += v; }
    em = blk_reduce(em, red, tid, true);
    es = blk_reduce(es, red, tid, false);
    if (tid == 0) {
        pgm[b * NS + s] = gm; pzs[b * NS + s] = zs;
        pem[b * NS + s] = em; pes[b * NS + s] = es;
    }
}

__global__ __launch_bounds__(256)
void ph_write2(const float* __restrict__ gen, const float* __restrict__ extra,
               const float* __restrict__ pgm, const float* __restrict__ pzs,
               const float* __restrict__ pem, const float* __restrict__ pes,
               const float* __restrict__ mS, float* __restrict__ proba)
{
    const int b = blockIdx.x, s = blockIdx.y, tid = threadIdx.x;
    const float mb   = mS[b * 2];
    const float Sb   = mS[b * 2 + 1];
    const float base = 1e-10f * Sb;

    float gm = -3.4e38f, em = 0.f;
#pragma unroll
    for (int k = 0; k < NS; ++k) {
        gm = fmaxf(gm, pgm[b * NS + k]);
        em = fmaxf(em, pem[b * NS + k]);
    }
    const float M = fmaxf(gm, mb + logf(base + em));
    float s1 = 0.f, s2 = 0.f;
#pragma unroll
    for (int k = 0; k < NS; ++k) {
        s1 += pzs[b * NS + k] * expf(pgm[b * NS + k] - M);
        s2 += pes[b * NS + k];
    }
    const float cs  = expf(mb - M);
    const float inv = 1.f / (s1 + cs * (base * VTS + s2));

    const float* g  = gen + (size_t)b * V_;
    const float* ex = extra + (size_t)b * VTS;
    float* o = proba + (size_t)b * VTS;
    const int e0 = s * SLE;
    const int e1 = (e0 + SLE < VTS) ? e0 + SLE : VTS;
    for (int i = e0 + tid; i < e1; i += 256) {
        const float cp = cs * (base + ex[i]) * inv;
        o[i] = (i < V_) ? (expf(g[i] - M) * inv + cp) : cp;
    }
}

// ---------------------------------------------------------------------------
extern "C" void kernel_launch(void* const* d_in, const int* in_sizes, int n_in,
                              void* d_out, int out_size, void* d_ws, size_t ws_size,
                              hipStream_t stream)
{
    const float* slot_enc = (const float*)d_in[0];
    const float* pers_enc = (const float*)d_in[1];
    const float* hid      = (const float*)d_in[2];
    const int*   mt       = (const int*)d_in[3];
    const int*   slot_np  = (const int*)d_in[4];
    // d_in[5] sparse_u_input: reconstructed from slot_np (205 MB skipped)
    const float* emb      = (const float*)d_in[6];
    const float* W_attn_a = (const float*)d_in[7];
    const float* b_attn_a = (const float*)d_in[8];
    const float* v_a      = (const float*)d_in[9];
    const float* W_attn_p = (const float*)d_in[10];
    const float* b_attn_p = (const float*)d_in[11];
    const float* v_p      = (const float*)d_in[12];
    const float* W_ih     = (const float*)d_in[13];
    const float* W_hh     = (const float*)d_in[14];
    const float* b_ih     = (const float*)d_in[15];
    const float* b_hh     = (const float*)d_in[16];
    const float* W_proj   = (const float*)d_in[17];
    const float* b_proj   = (const float*)d_in[18];
    const float* W_c2     = (const float*)d_in[19];
    const float* b_c2     = (const float*)d_in[20];
    float* out = (float*)d_out;

    float* w = (float*)d_ws;
    size_t off = 0;
    auto alloc = [&](size_t n) { float* p = w + off; off += n; return p; };
    float* SA    = alloc((size_t)TS_ * B_ * H_);
    float* SP    = alloc((size_t)TP_ * B_ * H_);
    float* UCt   = alloc((size_t)TS_ * B_ * H_);
    float* ctxa  = alloc((size_t)B_ * H_);
    float* ctxp  = alloc((size_t)B_ * H_);
    float* gx    = alloc((size_t)B_ * E_);
    float* hnew  = alloc((size_t)B_ * H_);
    float* gen   = alloc((size_t)B_ * V_);
    float* mS    = alloc((size_t)2 * B_);
    float* extra = alloc((size_t)B_ * VTS);
    float* pgm   = alloc((size_t)B_ * NS);
    float* pzs   = alloc((size_t)B_ * NS);
    float* pem   = alloc((size_t)B_ * NS);
    float* pes   = alloc((size_t)B_ * NS);
    float* partsP = alloc((size_t)PSK * B_ * V_);   // proj partials
    float* partsG = alloc((size_t)14 * B_ * H3);    // gru partials (disjoint!)
    float* partsH = partsG;                          // hid partials reuse gru region? NO:
    // hid parts must survive until tall84; gru runs later -> separate region:
    float* partsHd = alloc((size_t)8 * B_ * H_);

    const int o2 = B_ * VTS;
    const int o3 = o2 + B_ * H_;
    (void)partsH;

    // 1. zero extra + gather embedding
    zero_gather<<<(B_ * VTS + 255) / 256, 256, 0, stream>>>(extra, emb, mt, gx);

    // 2. hidden projections -> partsHd[0..8)
    gemm_hid<<<dim3(4, 4, 2), 256, 0, stream>>>(hid, W_attn_a, W_attn_p, partsHd);

    // 3. encoder projections fused with ha-add + tanh(+*v) epilogues
    gemm_tall84<<<dim3(25, 8, 3), 256, 0, stream>>>(
        slot_enc, pers_enc, W_attn_a, W_attn_p, W_c2,
        b_attn_a, b_attn_p, b_c2, v_a, v_p, partsHd, SA, SP, UCt);

    // 4. attention contexts (compile-time T)
    attn_fused3<<<dim3(B_, 2), 512, 0, stream>>>(SA, SP, slot_enc, pers_enc, ctxa, ctxp);

    // 5. merged: proj ctx-slices (1000 blocks) + GRU slices (168 blocks)
    gemm_pcg<<<1168, 256, 0, stream>>>(ctxa, ctxp, hid, gx, W_proj, W_ih, W_hh, partsP, partsG);

    // 6. GRU reduce + elementwise
    reduce_gru<<<(B_ * H_ + 255) / 256, 256, 0, stream>>>(partsG, b_ih, b_hh, hid, hnew, out + o2, out + o3);

    // 7. proj hnew-slices (500 blocks)
    gemm_projh<<<dim3(125, 4), 256, 0, stream>>>(hnew, W_proj, partsP);

    // 8. copy scores + scatter
    u_prep_scatter2<<<B_, 512, 0, stream>>>(UCt, hnew, slot_np, mS, extra);

    // 9/10. joint softmax
    ph_max2g<<<dim3(B_, NS), 256, 0, stream>>>(partsP, b_proj, extra, gen, pgm, pzs, pem, pes);
    ph_write2<<<dim3(B_, NS), 256, 0, stream>>>(gen, extra, pgm, pzs, pem, pes, mS, out);
}

// Round 10
// 403.249 us; speedup vs baseline: 1.8992x; 1.0010x over previous
//
#include <hip/hip_runtime.h>
#include <math.h>

static constexpr int V_   = 32000;
static constexpr int E_   = 512;
static constexpr int H_   = 1024;
static constexpr int B_   = 32;
static constexpr int TS_  = 50;
static constexpr int TP_  = 32;
static constexpr int VTS  = V_ + TS_;     // 32050
static constexpr int H3   = 3 * H_;       // 3072
static constexpr int GIN_ = E_ + 2 * H_;  // 2560
static constexpr int NS   = 8;            // softmax slices
static constexpr int SLE  = (VTS + NS - 1) / NS;  // 4007
static constexpr int GSL  = V_ / NS;      // 4000
static constexpr int PSK  = 12;           // proj K-slices
static constexpr int NZB  = (B_ * VTS + 255) / 256;  // 4007 zero/gather blocks

// ---------------------------------------------------------------------------
// m32v2 tile core v3: 32m x 256n, KC=32, 4 waves, reg double-buffer.
// A frag: 2x ds_read_b128 at wave-uniform addr (true broadcast).
// W frag: 1x ds_read_b128 (thread owns 4 consecutive cols; Ws[32][256]
// unpadded -> 16B-aligned rows, reads 2-way = free). float4 output stores.
// Per-output k-summation order identical to R9 -> bit-identical results.
// ---------------------------------------------------------------------------
__device__ __forceinline__ void m32v2_tile(
    const float* __restrict__ A, int lda,
    const float* __restrict__ W, int ldw, int wko,
    int klen, int n0, float* __restrict__ po, int N)
{
    __shared__ float As[32][36];
    __shared__ float Ws[32][256];

    const int tid  = threadIdx.x;
    const int lane = tid & 63;
    const int wv   = tid >> 6;
    const int wq   = lane & 7;
    const int wg   = lane >> 3;
    const int am   = tid >> 3;
    const int aq   = tid & 7;

    float acc[8][4];
#pragma unroll
    for (int i = 0; i < 8; ++i)
#pragma unroll
        for (int j = 0; j < 4; ++j) acc[i][j] = 0.f;

    float4 a4 = *reinterpret_cast<const float4*>(A + (size_t)am * lda + 4 * aq);
    float4 w4[8];
#pragma unroll
    for (int i = 0; i < 8; ++i)
        w4[i] = *reinterpret_cast<const float4*>(
            W + (size_t)(n0 + wv * 64 + i * 8 + wg) * ldw + wko + 4 * wq);

    for (int kb = 0; kb < klen; kb += 32) {
        __syncthreads();
        As[4 * aq + 0][am] = a4.x; As[4 * aq + 1][am] = a4.y;
        As[4 * aq + 2][am] = a4.z; As[4 * aq + 3][am] = a4.w;
#pragma unroll
        for (int i = 0; i < 8; ++i) {
            const int col = wv * 64 + i * 8 + wg;
            Ws[4 * wq + 0][col] = w4[i].x; Ws[4 * wq + 1][col] = w4[i].y;
            Ws[4 * wq + 2][col] = w4[i].z; Ws[4 * wq + 3][col] = w4[i].w;
        }
        __syncthreads();
        if (kb + 32 < klen) {
            a4 = *reinterpret_cast<const float4*>(A + (size_t)am * lda + kb + 32 + 4 * aq);
#pragma unroll
            for (int i = 0; i < 8; ++i)
                w4[i] = *reinterpret_cast<const float4*>(
                    W + (size_t)(n0 + wv * 64 + i * 8 + wg) * ldw + wko + kb + 32 + 4 * wq);
        }
#pragma unroll 8
        for (int k = 0; k < 32; ++k) {
            const float4 a0 = *reinterpret_cast<const float4*>(&As[k][wv * 8]);
            const float4 a1 = *reinterpret_cast<const float4*>(&As[k][wv * 8 + 4]);
            const float av[8] = {a0.x, a0.y, a0.z, a0.w, a1.x, a1.y, a1.z, a1.w};
            const float4 wf = *reinterpret_cast<const float4*>(&Ws[k][4 * lane]);
            const float wvv[4] = {wf.x, wf.y, wf.z, wf.w};
#pragma unroll
            for (int i = 0; i < 8; ++i)
#pragma unroll
                for (int j = 0; j < 4; ++j)
                    acc[i][j] = fmaf(av[i], wvv[j], acc[i][j]);
        }
    }
#pragma unroll
    for (int i = 0; i < 8; ++i) {
        float4 o; o.x = acc[i][0]; o.y = acc[i][1]; o.z = acc[i][2]; o.w = acc[i][3];
        *reinterpret_cast<float4*>(po + (size_t)(wv * 8 + i) * N + n0 + 4 * lane) = o;
    }
}

// ---------------------------------------------------------------------------
// zg_hid: zero extra + gather emb (blocks < NZB) + hidden projections
// (last 32 blocks). Single m32v2 call site.
// ---------------------------------------------------------------------------
__global__ __launch_bounds__(256)
void zg_hid(float* __restrict__ extra, const float* __restrict__ emb,
            const int* __restrict__ mt, float* __restrict__ gx,
            const float* __restrict__ hid,
            const float* __restrict__ Wa, const float* __restrict__ Wp,
            float* __restrict__ partsHd)
{
    const int bid = blockIdx.x;
    if (bid < NZB) {
        const int i = bid * 256 + threadIdx.x;
        if (i < B_ * VTS) extra[i] = 0.f;
        if (i < B_ * E_) gx[i] = emb[(size_t)mt[i >> 9] * E_ + (i & 511)];
        return;
    }
    const int idx = bid - NZB;              // 0..31
    const int z = idx >> 4, y = (idx >> 2) & 3, bx = idx & 3;
    m32v2_tile(hid + y * 256, H_, z ? Wp : Wa, 2 * H_, y * 256, 256, bx * 256,
               partsHd + (size_t)(z * 4 + y) * B_ * H_, H_);
}

// ---------------------------------------------------------------------------
// gemm_pcg: proj ctx-slices (1000 blocks) + GRU slices (168 blocks).
// SINGLE m32v2 call site (R9 bug: two sites doubled static LDS -> 2 blk/CU).
// ---------------------------------------------------------------------------
__global__ __launch_bounds__(256)
void gemm_pcg(const float* __restrict__ ctxa, const float* __restrict__ ctxp,
              const float* __restrict__ hid, const float* __restrict__ gx,
              const float* __restrict__ W_proj,
              const float* __restrict__ W_ih, const float* __restrict__ W_hh,
              float* __restrict__ partsP, float* __restrict__ partsG)
{
    const int bid = blockIdx.x;
    const float* A; int lda; const float* W; int ldw; int wko;
    float* po; int N; int n0;
    if (bid < 1000) {
        const int y = bid / 125; n0 = (bid % 125) * 256;
        const int slice = y >> 2, kq = y & 3;
        A = (slice ? ctxp : ctxa) + kq * 256; lda = H_;
        W = W_proj; ldw = H3; wko = slice * 1024 + kq * 256;
        po = partsP + (size_t)y * B_ * V_; N = V_;
    } else {
        const int idx = bid - 1000;
        const int y = idx / 12; n0 = (idx % 12) * 256;
        int klo;
        if (y < 2)       { klo = y * 256;        A = gx;   lda = E_; W = W_ih; ldw = GIN_; wko = klo; }
        else if (y < 6)  { klo = (y - 2) * 256;  A = ctxa; lda = H_; W = W_ih; ldw = GIN_; wko = 512 + klo; }
        else if (y < 10) { klo = (y - 6) * 256;  A = ctxp; lda = H_; W = W_ih; ldw = GIN_; wko = 1536 + klo; }
        else             { klo = (y - 10) * 256; A = hid;  lda = H_; W = W_hh; ldw = H_;   wko = klo; }
        A += klo;
        po = partsG + (size_t)y * B_ * H3; N = H3;
    }
    m32v2_tile(A, lda, W, ldw, wko, 256, n0, po, N);
}

__global__ void reduce_gru(const float* __restrict__ parts,
                           const float* __restrict__ b_ih, const float* __restrict__ b_hh,
                           const float* __restrict__ hid,
                           float* __restrict__ hnew,
                           float* __restrict__ o2, float* __restrict__ o3)
{
    const int i = blockIdx.x * 256 + threadIdx.x;
    if (i >= B_ * H_) return;
    const int b = i >> 10, j = i & 1023;
    float gi[3], gh[3];
#pragma unroll
    for (int c = 0; c < 3; ++c) {
        float s = b_ih[c * H_ + j];
        for (int y = 0; y < 10; ++y)
            s += parts[((size_t)y * B_ + b) * H3 + c * H_ + j];
        gi[c] = s;
        float t = b_hh[c * H_ + j];
        for (int y = 10; y < 14; ++y)
            t += parts[((size_t)y * B_ + b) * H3 + c * H_ + j];
        gh[c] = t;
    }
    const float r = 1.f / (1.f + expf(-(gi[0] + gh[0])));
    const float z = 1.f / (1.f + expf(-(gi[1] + gh[1])));
    const float n = tanhf(gi[2] + r * gh[2]);
    const float o = (1.f - z) * n + z * hid[i];
    hnew[i] = o; o2[i] = o; o3[i] = o;
}

// ---------------------------------------------------------------------------
// gemm_tall84 v2: W frag 1x ds_read_b128 (cols 4*txn, Ws[32][128] unpadded,
// reads 2-way free, staging writes 2-way free), float4 epilogue.
// ---------------------------------------------------------------------------
__global__ __launch_bounds__(256)
void gemm_tall84(const float* __restrict__ slot_enc, const float* __restrict__ pers_enc,
                 const float* __restrict__ W_attn_a, const float* __restrict__ W_attn_p,
                 const float* __restrict__ W_c2,
                 const float* __restrict__ b_attn_a, const float* __restrict__ b_attn_p,
                 const float* __restrict__ b_c2,
                 const float* __restrict__ v_a, const float* __restrict__ v_p,
                 const float* __restrict__ parts,
                 float* __restrict__ SA, float* __restrict__ SP, float* __restrict__ UCt)
{
    __shared__ float As[32][68];
    __shared__ float Ws[32][128];
    const int z = blockIdx.z;
    const float* A; const float* W; float* C; int M, ldw;
    if (z == 0)      { A = slot_enc; W = W_attn_a + H_; C = SA;  M = TS_ * B_; ldw = 2 * H_; }
    else if (z == 1) { A = pers_enc; W = W_attn_p + H_; C = SP;  M = TP_ * B_; ldw = 2 * H_; }
    else             { A = slot_enc; W = W_c2;          C = UCt; M = TS_ * B_; ldw = H_; }
    const int m0 = blockIdx.x * 64;
    if (m0 >= M) return;
    const int n0 = blockIdx.y * 128;
    const int tid = threadIdx.x;
    const int tym = tid >> 5;                    // m-group (8 rows)
    const int txn = tid & 31;                    // col-quad: cols 4*txn..+3
    const int sr = tid & 63, sh = tid >> 6;
    const int wr = tid & 127, wh = tid >> 7;

    float acc[8][4];
#pragma unroll
    for (int i = 0; i < 8; ++i)
#pragma unroll
        for (int j = 0; j < 4; ++j) acc[i][j] = 0.f;

    float4 a4[2], w4[4];
#pragma unroll
    for (int q = 0; q < 2; ++q)
        a4[q] = *reinterpret_cast<const float4*>(A + (size_t)(m0 + sr) * H_ + 8 * sh + 4 * q);
#pragma unroll
    for (int q = 0; q < 4; ++q)
        w4[q] = *reinterpret_cast<const float4*>(W + (size_t)(n0 + wr) * ldw + 16 * wh + 4 * q);

    for (int kb = 0; kb < H_; kb += 32) {
        __syncthreads();
#pragma unroll
        for (int q = 0; q < 2; ++q) {
            As[8 * sh + 4 * q + 0][sr] = a4[q].x; As[8 * sh + 4 * q + 1][sr] = a4[q].y;
            As[8 * sh + 4 * q + 2][sr] = a4[q].z; As[8 * sh + 4 * q + 3][sr] = a4[q].w;
        }
#pragma unroll
        for (int q = 0; q < 4; ++q) {
            Ws[16 * wh + 4 * q + 0][wr] = w4[q].x; Ws[16 * wh + 4 * q + 1][wr] = w4[q].y;
            Ws[16 * wh + 4 * q + 2][wr] = w4[q].z; Ws[16 * wh + 4 * q + 3][wr] = w4[q].w;
        }
        __syncthreads();
        if (kb + 32 < H_) {
#pragma unroll
            for (int q = 0; q < 2; ++q)
                a4[q] = *reinterpret_cast<const float4*>(A + (size_t)(m0 + sr) * H_ + kb + 32 + 8 * sh + 4 * q);
#pragma unroll
            for (int q = 0; q < 4; ++q)
                w4[q] = *reinterpret_cast<const float4*>(W + (size_t)(n0 + wr) * ldw + kb + 32 + 16 * wh + 4 * q);
        }
#pragma unroll 8
        for (int k = 0; k < 32; ++k) {
            const float4 a0 = *reinterpret_cast<const float4*>(&As[k][8 * tym]);
            const float4 a1 = *reinterpret_cast<const float4*>(&As[k][8 * tym + 4]);
            const float av[8] = {a0.x, a0.y, a0.z, a0.w, a1.x, a1.y, a1.z, a1.w};
            const float4 wf = *reinterpret_cast<const float4*>(&Ws[k][4 * txn]);
            const float wvv[4] = {wf.x, wf.y, wf.z, wf.w};
#pragma unroll
            for (int i = 0; i < 8; ++i)
#pragma unroll
                for (int j = 0; j < 4; ++j)
                    acc[i][j] = fmaf(av[i], wvv[j], acc[i][j]);
        }
    }

    const int colb = n0 + 4 * txn;
    if (z < 2) {
        const float* bvec = z ? b_attn_p : b_attn_a;
        const float* vvec = z ? v_p : v_a;
        const float* pp = parts + (size_t)(z * 4) * B_ * H_;
        const float4 b4 = *reinterpret_cast<const float4*>(bvec + colb);
        const float4 v4 = *reinterpret_cast<const float4*>(vvec + colb);
#pragma unroll
        for (int i = 0; i < 8; ++i) {
            const int row = m0 + 8 * tym + i;
            const int b = row & 31;
            float4 ha = b4;
#pragma unroll
            for (int ss = 0; ss < 4; ++ss) {
                const float4 p4 = *reinterpret_cast<const float4*>(&pp[((size_t)ss * B_ + b) * H_ + colb]);
                ha.x += p4.x; ha.y += p4.y; ha.z += p4.z; ha.w += p4.w;
            }
            float4 o;
            o.x = tanhf(acc[i][0] + ha.x) * v4.x;
            o.y = tanhf(acc[i][1] + ha.y) * v4.y;
            o.z = tanhf(acc[i][2] + ha.z) * v4.z;
            o.w = tanhf(acc[i][3] + ha.w) * v4.w;
            *reinterpret_cast<float4*>(C + (size_t)row * H_ + colb) = o;
        }
    } else {
        const float4 b4 = *reinterpret_cast<const float4*>(b_c2 + colb);
#pragma unroll
        for (int i = 0; i < 8; ++i) {
            const int row = m0 + 8 * tym + i;
            float4 o;
            o.x = tanhf(acc[i][0] + b4.x);
            o.y = tanhf(acc[i][1] + b4.y);
            o.z = tanhf(acc[i][2] + b4.z);
            o.w = tanhf(acc[i][3] + b4.w);
            *reinterpret_cast<float4*>(C + (size_t)row * H_ + colb) = o;
        }
    }
}

// ---------------------------------------------------------------------------
template <int T>
__device__ __forceinline__ void attn_body(const float* __restrict__ S,
                                          const float* __restrict__ enc,
                                          float* __restrict__ ctx, int b)
{
    const int tid  = threadIdx.x;
    const int wave = tid >> 6;
    const int lane = tid & 63;
    __shared__ float sc[64];
    __shared__ float aw[64];

    for (int t = wave; t < T; t += 8) {
        const float* e = S + ((size_t)t * B_ + b) * H_;
        float p = 0.f;
#pragma unroll
        for (int j = 0; j < H_ / 64; ++j) p += e[lane + 64 * j];
#pragma unroll
        for (int off = 32; off > 0; off >>= 1) p += __shfl_down(p, off);
        if (lane == 0) sc[t] = p;
    }
    __syncthreads();
    if (tid < 64) {
        const float x = (tid < T) ? sc[tid] : -3.4e38f;
        float mx = x;
#pragma unroll
        for (int off = 32; off > 0; off >>= 1) mx = fmaxf(mx, __shfl_xor(mx, off));
        const float ex = (tid < T) ? expf(x - mx) : 0.f;
        float sm = ex;
#pragma unroll
        for (int off = 32; off > 0; off >>= 1) sm += __shfl_xor(sm, off);
        aw[tid] = ex / sm;
    }
    __syncthreads();
    for (int k = tid; k < H_; k += 512) {
        float c = 0.f;
#pragma unroll 10
        for (int t = 0; t < T; ++t)
            c += aw[t] * enc[((size_t)t * B_ + b) * H_ + k];
        ctx[(size_t)b * H_ + k] = c;
    }
}

__global__ __launch_bounds__(512)
void attn_fused3(const float* __restrict__ SA, const float* __restrict__ SP,
                 const float* __restrict__ slot_enc, const float* __restrict__ pers_enc,
                 float* __restrict__ ctxa, float* __restrict__ ctxp)
{
    const int b = blockIdx.x;
    if (blockIdx.y == 0) attn_body<TS_>(SA, slot_enc, ctxa, b);
    else                 attn_body<TP_>(SP, pers_enc, ctxp, b);
}

// ---------------------------------------------------------------------------
// projh_uprep: proj hnew-slices (blocks 0..499) + u_prep/scatter (500..531,
// 256 threads, wave t-stride 4). Single m32v2 call site in its branch.
// ---------------------------------------------------------------------------
__global__ __launch_bounds__(256)
void projh_uprep(const float* __restrict__ hnew, const float* __restrict__ W_proj,
                 float* __restrict__ partsP,
                 const float* __restrict__ UCt, const int* __restrict__ slot_np,
                 float* __restrict__ mS, float* __restrict__ extra)
{
    if (blockIdx.x < 500) {
        const int y = blockIdx.x / 125, n0 = (blockIdx.x % 125) * 256;
        m32v2_tile(hnew + y * 256, H_, W_proj, H3, 2048 + y * 256, 256, n0,
                   partsP + (size_t)(8 + y) * B_ * V_, V_);
        return;
    }
    const int b    = blockIdx.x - 500;
    const int tid  = threadIdx.x;
    const int wave = tid >> 6;
    const int lane = tid & 63;
    __shared__ float su[64];
    __shared__ float eu_s[64];

    const float* h = hnew + (size_t)b * H_;
    for (int t = wave; t < TS_; t += 4) {
        const float* r = UCt + ((size_t)t * B_ + b) * H_;
        float p = 0.f;
#pragma unroll
        for (int j = 0; j < H_ / 64; ++j)
            p += r[lane + 64 * j] * h[lane + 64 * j];
#pragma unroll
        for (int off = 32; off > 0; off >>= 1) p += __shfl_down(p, off);
        if (lane == 0) su[t] = p;
    }
    __syncthreads();
    if (tid < 64) {
        const float x = (tid < TS_) ? su[tid] : -3.4e38f;
        float mx = x;
#pragma unroll
        for (int off = 32; off > 0; off >>= 1) mx = fmaxf(mx, __shfl_xor(mx, off));
        const float ex = (tid < TS_) ? expf(x - mx) : 0.f;
        float sm = ex;
#pragma unroll
        for (int off = 32; off > 0; off >>= 1) sm += __shfl_xor(sm, off);
        eu_s[tid] = ex;
        if (tid == 0) { mS[b * 2] = mx; mS[b * 2 + 1] = sm; }
    }
    __syncthreads();
    if (tid < TS_) {
        const int sv = slot_np[tid * B_ + b];
        const float e = eu_s[tid];
        const bool copy = (sv == 2) || (sv >= V_);
        const bool add  = (sv != 0) && !copy;
        if (add)  atomicAdd(&extra[(size_t)b * VTS + sv], e);
        if (copy) atomicAdd(&extra[(size_t)b * VTS + V_ + tid], 5.0f * e);
    }
}

// ---------------------------------------------------------------------------
__device__ __forceinline__ float blk_reduce(float v, float* red, int tid, bool ismax)
{
    red[tid] = v; __syncthreads();
    for (int s = 128; s > 0; s >>= 1) {
        if (tid < s) red[tid] = ismax ? fmaxf(red[tid], red[tid + s]) : (red[tid] + red[tid + s]);
        __syncthreads();
    }
    const float r = red[0]; __syncthreads();
    return r;
}

__global__ __launch_bounds__(256)
void ph_max2g(const float* __restrict__ parts, const float* __restrict__ b_proj,
              const float* __restrict__ extra,
              float* __restrict__ gen,
              float* __restrict__ pgm, float* __restrict__ pzs,
              float* __restrict__ pem, float* __restrict__ pes)
{
    const int b = blockIdx.x, s = blockIdx.y, tid = threadIdx.x;
    __shared__ float red[256];
    const int g0 = s * GSL;

    float gv[16];
    float gm = -3.4e38f;
#pragma unroll
    for (int u = 0; u < 16; ++u) {
        const int loc = tid + 256 * u;
        float val = -3.4e38f;
        if (loc < GSL) {
            const int idx = g0 + loc;
            float ssum = 0.f;
#pragma unroll
            for (int ss = 0; ss < PSK; ++ss)
                ssum += parts[((size_t)ss * B_ + b) * V_ + idx];
            val = ssum + b_proj[idx];
            gen[(size_t)b * V_ + idx] = val;
            gm = fmaxf(gm, val);
        }
        gv[u] = val;
    }
    gm = blk_reduce(gm, red, tid, true);
    float zs = 0.f;
#pragma unroll
    for (int u = 0; u < 16; ++u)
        zs += expf(gv[u] - gm);
    zs = blk_reduce(zs, red, tid, false);

    const float* ex = extra + (size_t)b * VTS;
    const int e0 = s * SLE;
    const int e1 = (e0 + SLE < VTS) ? e0 + SLE : VTS;
    float em = 0.f, es = 0.f;
    for (int i = e0 + tid; i < e1; i += 256) { const float v = ex[i]; em = fmaxf(em, v); es += v; }
    em = blk_reduce(em, red, tid, true);
    es = blk_reduce(es, red, tid, false);
    if (tid == 0) {
        pgm[b * NS + s] = gm; pzs[b * NS + s] = zs;
        pem[b * NS + s] = em; pes[b * NS + s] = es;
    }
}

__global__ __launch_bounds__(256)
void ph_write2(const float* __restrict__ gen, const float* __restrict__ extra,
               const float* __restrict__ pgm, const float* __restrict__ pzs,
               const float* __restrict__ pem, const float* __restrict__ pes,
               const float* __restrict__ mS, float* __restrict__ proba)
{
    const int b = blockIdx.x, s = blockIdx.y, tid = threadIdx.x;
    const float mb   = mS[b * 2];
    const float Sb   = mS[b * 2 + 1];
    const float base = 1e-10f * Sb;

    float gm = -3.4e38f, em = 0.f;
#pragma unroll
    for (int k = 0; k < NS; ++k) {
        gm = fmaxf(gm, pgm[b * NS + k]);
        em = fmaxf(em, pem[b * NS + k]);
    }
    const float M = fmaxf(gm, mb + logf(base + em));
    float s1 = 0.f, s2 = 0.f;
#pragma unroll
    for (int k = 0; k < NS; ++k) {
        s1 += pzs[b * NS + k] * expf(pgm[b * NS + k] - M);
        s2 += pes[b * NS + k];
    }
    const float cs  = expf(mb - M);
    const float inv = 1.f / (s1 + cs * (base * VTS + s2));

    const float* g  = gen + (size_t)b * V_;
    const float* ex = extra + (size_t)b * VTS;
    float* o = proba + (size_t)b * VTS;
    const int e0 = s * SLE;
    const int e1 = (e0 + SLE < VTS) ? e0 + SLE : VTS;
    for (int i = e0 + tid; i < e1; i += 256) {
        const float cp = cs * (base + ex[i]) * inv;
        o[i] = (i < V_) ? (expf(g[i] - M) * inv + cp) : cp;
    }
}

// ---------------------------------------------------------------------------
extern "C" void kernel_launch(void* const* d_in, const int* in_sizes, int n_in,
                              void* d_out, int out_size, void* d_ws, size_t ws_size,
                              hipStream_t stream)
{
    const float* slot_enc = (const float*)d_in[0];
    const float* pers_enc = (const float*)d_in[1];
    const float* hid      = (const float*)d_in[2];
    const int*   mt       = (const int*)d_in[3];
    const int*   slot_np  = (const int*)d_in[4];
    // d_in[5] sparse_u_input: reconstructed from slot_np (205 MB skipped)
    const float* emb      = (const float*)d_in[6];
    const float* W_attn_a = (const float*)d_in[7];
    const float* b_attn_a = (const float*)d_in[8];
    const float* v_a      = (const float*)d_in[9];
    const float* W_attn_p = (const float*)d_in[10];
    const float* b_attn_p = (const float*)d_in[11];
    const float* v_p      = (const float*)d_in[12];
    const float* W_ih     = (const float*)d_in[13];
    const float* W_hh     = (const float*)d_in[14];
    const float* b_ih     = (const float*)d_in[15];
    const float* b_hh     = (const float*)d_in[16];
    const float* W_proj   = (const float*)d_in[17];
    const float* b_proj   = (const float*)d_in[18];
    const float* W_c2     = (const float*)d_in[19];
    const float* b_c2     = (const float*)d_in[20];
    float* out = (float*)d_out;

    float* w = (float*)d_ws;
    size_t off = 0;
    auto alloc = [&](size_t n) { float* p = w + off; off += n; return p; };
    float* SA    = alloc((size_t)TS_ * B_ * H_);
    float* SP    = alloc((size_t)TP_ * B_ * H_);
    float* UCt   = alloc((size_t)TS_ * B_ * H_);
    float* ctxa  = alloc((size_t)B_ * H_);
    float* ctxp  = alloc((size_t)B_ * H_);
    float* gx    = alloc((size_t)B_ * E_);
    float* hnew  = alloc((size_t)B_ * H_);
    float* gen   = alloc((size_t)B_ * V_);
    float* mS    = alloc((size_t)2 * B_);
    float* extra = alloc((size_t)B_ * VTS);
    float* pgm   = alloc((size_t)B_ * NS);
    float* pzs   = alloc((size_t)B_ * NS);
    float* pem   = alloc((size_t)B_ * NS);
    float* pes   = alloc((size_t)B_ * NS);
    float* partsP  = alloc((size_t)PSK * B_ * V_);
    float* partsG  = alloc((size_t)14 * B_ * H3);
    float* partsHd = alloc((size_t)8 * B_ * H_);

    const int o2 = B_ * VTS;
    const int o3 = o2 + B_ * H_;

    // 1. zero extra + gather emb + hidden projections
    zg_hid<<<NZB + 32, 256, 0, stream>>>(extra, emb, mt, gx, hid, W_attn_a, W_attn_p, partsHd);

    // 2. encoder projections with fused ha-add/tanh epilogues
    gemm_tall84<<<dim3(25, 8, 3), 256, 0, stream>>>(
        slot_enc, pers_enc, W_attn_a, W_attn_p, W_c2,
        b_attn_a, b_attn_p, b_c2, v_a, v_p, partsHd, SA, SP, UCt);

    // 3. attention contexts
    attn_fused3<<<dim3(B_, 2), 512, 0, stream>>>(SA, SP, slot_enc, pers_enc, ctxa, ctxp);

    // 4. merged proj ctx-slices + GRU slices
    gemm_pcg<<<1168, 256, 0, stream>>>(ctxa, ctxp, hid, gx, W_proj, W_ih, W_hh, partsP, partsG);

    // 5. GRU reduce + elementwise
    reduce_gru<<<(B_ * H_ + 255) / 256, 256, 0, stream>>>(partsG, b_ih, b_hh, hid, hnew, out + o2, out + o3);

    // 6. proj hnew-slices + u_prep/scatter
    projh_uprep<<<532, 256, 0, stream>>>(hnew, W_proj, partsP, UCt, slot_np, mS, extra);

    // 7/8. joint softmax
    ph_max2g<<<dim3(B_, NS), 256, 0, stream>>>(partsP, b_proj, extra, gen, pgm, pzs, pem, pes);
    ph_write2<<<dim3(B_, NS), 256, 0, stream>>>(gen, extra, pgm, pzs, pem, pes, mS, out);
}

// Round 11
// 400.523 us; speedup vs baseline: 1.9122x; 1.0068x over previous
//
#include <hip/hip_runtime.h>
#include <math.h>

static constexpr int V_   = 32000;
static constexpr int E_   = 512;
static constexpr int H_   = 1024;
static constexpr int B_   = 32;
static constexpr int TS_  = 50;
static constexpr int TP_  = 32;
static constexpr int VTS  = V_ + TS_;     // 32050
static constexpr int H3   = 3 * H_;       // 3072
static constexpr int GIN_ = E_ + 2 * H_;  // 2560
static constexpr int NS   = 8;            // softmax slices
static constexpr int SLE  = (VTS + NS - 1) / NS;  // 4007
static constexpr int GSL  = V_ / NS;      // 4000
static constexpr int PSK  = 12;           // proj K-slices
static constexpr int NSC  = TS_ * B_ + TP_ * B_;  // 2624 score entries
static constexpr int NZB  = (B_ * VTS + 255) / 256;  // 4007 zero/gather blocks

// ---------------------------------------------------------------------------
// m32v2 tile core (R10): 32m x 256n, KC=32, 4 waves, reg double-buffer.
// A frag: 2x ds_read_b128 broadcast; W frag: 1x ds_read_b128 (2-way, free).
// ---------------------------------------------------------------------------
__device__ __forceinline__ void m32v2_tile(
    const float* __restrict__ A, int lda,
    const float* __restrict__ W, int ldw, int wko,
    int klen, int n0, float* __restrict__ po, int N)
{
    __shared__ float As[32][36];
    __shared__ float Ws[32][256];

    const int tid  = threadIdx.x;
    const int lane = tid & 63;
    const int wv   = tid >> 6;
    const int wq   = lane & 7;
    const int wg   = lane >> 3;
    const int am   = tid >> 3;
    const int aq   = tid & 7;

    float acc[8][4];
#pragma unroll
    for (int i = 0; i < 8; ++i)
#pragma unroll
        for (int j = 0; j < 4; ++j) acc[i][j] = 0.f;

    float4 a4 = *reinterpret_cast<const float4*>(A + (size_t)am * lda + 4 * aq);
    float4 w4[8];
#pragma unroll
    for (int i = 0; i < 8; ++i)
        w4[i] = *reinterpret_cast<const float4*>(
            W + (size_t)(n0 + wv * 64 + i * 8 + wg) * ldw + wko + 4 * wq);

    for (int kb = 0; kb < klen; kb += 32) {
        __syncthreads();
        As[4 * aq + 0][am] = a4.x; As[4 * aq + 1][am] = a4.y;
        As[4 * aq + 2][am] = a4.z; As[4 * aq + 3][am] = a4.w;
#pragma unroll
        for (int i = 0; i < 8; ++i) {
            const int col = wv * 64 + i * 8 + wg;
            Ws[4 * wq + 0][col] = w4[i].x; Ws[4 * wq + 1][col] = w4[i].y;
            Ws[4 * wq + 2][col] = w4[i].z; Ws[4 * wq + 3][col] = w4[i].w;
        }
        __syncthreads();
        if (kb + 32 < klen) {
            a4 = *reinterpret_cast<const float4*>(A + (size_t)am * lda + kb + 32 + 4 * aq);
#pragma unroll
            for (int i = 0; i < 8; ++i)
                w4[i] = *reinterpret_cast<const float4*>(
                    W + (size_t)(n0 + wv * 64 + i * 8 + wg) * ldw + wko + kb + 32 + 4 * wq);
        }
#pragma unroll 8
        for (int k = 0; k < 32; ++k) {
            const float4 a0 = *reinterpret_cast<const float4*>(&As[k][wv * 8]);
            const float4 a1 = *reinterpret_cast<const float4*>(&As[k][wv * 8 + 4]);
            const float av[8] = {a0.x, a0.y, a0.z, a0.w, a1.x, a1.y, a1.z, a1.w};
            const float4 wf = *reinterpret_cast<const float4*>(&Ws[k][4 * lane]);
            const float wvv[4] = {wf.x, wf.y, wf.z, wf.w};
#pragma unroll
            for (int i = 0; i < 8; ++i)
#pragma unroll
                for (int j = 0; j < 4; ++j)
                    acc[i][j] = fmaf(av[i], wvv[j], acc[i][j]);
        }
    }
#pragma unroll
    for (int i = 0; i < 8; ++i) {
        float4 o; o.x = acc[i][0]; o.y = acc[i][1]; o.z = acc[i][2]; o.w = acc[i][3];
        *reinterpret_cast<float4*>(po + (size_t)(wv * 8 + i) * N + n0 + 4 * lane) = o;
    }
}

// ---------------------------------------------------------------------------
// zg_hid: zero extra+scores + gather emb (blocks < NZB) + hidden projections.
// ---------------------------------------------------------------------------
__global__ __launch_bounds__(256)
void zg_hid(float* __restrict__ extra, float* __restrict__ scAll,
            const float* __restrict__ emb,
            const int* __restrict__ mt, float* __restrict__ gx,
            const float* __restrict__ hid,
            const float* __restrict__ Wa, const float* __restrict__ Wp,
            float* __restrict__ partsHd)
{
    const int bid = blockIdx.x;
    if (bid < NZB) {
        const int i = bid * 256 + threadIdx.x;
        if (i < B_ * VTS) extra[i] = 0.f;
        if (i < NSC) scAll[i] = 0.f;
        if (i < B_ * E_) gx[i] = emb[(size_t)mt[i >> 9] * E_ + (i & 511)];
        return;
    }
    const int idx = bid - NZB;              // 0..31
    const int z = idx >> 4, y = (idx >> 2) & 3, bx = idx & 3;
    m32v2_tile(hid + y * 256, H_, z ? Wp : Wa, 2 * H_, y * 256, 256, bx * 256,
               partsHd + (size_t)(z * 4 + y) * B_ * H_, H_);
}

// ---------------------------------------------------------------------------
// gemm_pcg: proj ctx-slices (1000 blocks) + GRU slices (168 blocks).
// ---------------------------------------------------------------------------
__global__ __launch_bounds__(256)
void gemm_pcg(const float* __restrict__ ctxa, const float* __restrict__ ctxp,
              const float* __restrict__ hid, const float* __restrict__ gx,
              const float* __restrict__ W_proj,
              const float* __restrict__ W_ih, const float* __restrict__ W_hh,
              float* __restrict__ partsP, float* __restrict__ partsG)
{
    const int bid = blockIdx.x;
    const float* A; int lda; const float* W; int ldw; int wko;
    float* po; int N; int n0;
    if (bid < 1000) {
        const int y = bid / 125; n0 = (bid % 125) * 256;
        const int slice = y >> 2, kq = y & 3;
        A = (slice ? ctxp : ctxa) + kq * 256; lda = H_;
        W = W_proj; ldw = H3; wko = slice * 1024 + kq * 256;
        po = partsP + (size_t)y * B_ * V_; N = V_;
    } else {
        const int idx = bid - 1000;
        const int y = idx / 12; n0 = (idx % 12) * 256;
        int klo;
        if (y < 2)       { klo = y * 256;        A = gx;   lda = E_; W = W_ih; ldw = GIN_; wko = klo; }
        else if (y < 6)  { klo = (y - 2) * 256;  A = ctxa; lda = H_; W = W_ih; ldw = GIN_; wko = 512 + klo; }
        else if (y < 10) { klo = (y - 6) * 256;  A = ctxp; lda = H_; W = W_ih; ldw = GIN_; wko = 1536 + klo; }
        else             { klo = (y - 10) * 256; A = hid;  lda = H_; W = W_hh; ldw = H_;   wko = klo; }
        A += klo;
        po = partsG + (size_t)y * B_ * H3; N = H3;
    }
    m32v2_tile(A, lda, W, ldw, wko, 256, n0, po, N);
}

__global__ void reduce_gru(const float* __restrict__ parts,
                           const float* __restrict__ b_ih, const float* __restrict__ b_hh,
                           const float* __restrict__ hid,
                           float* __restrict__ hnew,
                           float* __restrict__ o2, float* __restrict__ o3)
{
    const int i = blockIdx.x * 256 + threadIdx.x;
    if (i >= B_ * H_) return;
    const int b = i >> 10, j = i & 1023;
    float gi[3], gh[3];
#pragma unroll
    for (int c = 0; c < 3; ++c) {
        float s = b_ih[c * H_ + j];
        for (int y = 0; y < 10; ++y)
            s += parts[((size_t)y * B_ + b) * H3 + c * H_ + j];
        gi[c] = s;
        float t = b_hh[c * H_ + j];
        for (int y = 10; y < 14; ++y)
            t += parts[((size_t)y * B_ + b) * H3 + c * H_ + j];
        gh[c] = t;
    }
    const float r = 1.f / (1.f + expf(-(gi[0] + gh[0])));
    const float z = 1.f / (1.f + expf(-(gi[1] + gh[1])));
    const float n = tanhf(gi[2] + r * gh[2]);
    const float o = (1.f - z) * n + z * hid[i];
    hnew[i] = o; o2[i] = o; o3[i] = o;
}

// ---------------------------------------------------------------------------
// gemm_tall84 v3: z<2 epilogue folds the attention score row-sum in-register
// (4-col sum + shfl-tree over 32 lanes + one atomicAdd per row per col-block)
// -> SA/SP never materialized. z=2 stores UCt as before.
// ---------------------------------------------------------------------------
__global__ __launch_bounds__(256)
void gemm_tall84(const float* __restrict__ slot_enc, const float* __restrict__ pers_enc,
                 const float* __restrict__ W_attn_a, const float* __restrict__ W_attn_p,
                 const float* __restrict__ W_c2,
                 const float* __restrict__ b_attn_a, const float* __restrict__ b_attn_p,
                 const float* __restrict__ b_c2,
                 const float* __restrict__ v_a, const float* __restrict__ v_p,
                 const float* __restrict__ parts,
                 float* __restrict__ scA, float* __restrict__ scP,
                 float* __restrict__ UCt)
{
    __shared__ float As[32][68];
    __shared__ float Ws[32][128];
    const int z = blockIdx.z;
    const float* A; const float* W; int M, ldw;
    if (z == 0)      { A = slot_enc; W = W_attn_a + H_; M = TS_ * B_; ldw = 2 * H_; }
    else if (z == 1) { A = pers_enc; W = W_attn_p + H_; M = TP_ * B_; ldw = 2 * H_; }
    else             { A = slot_enc; W = W_c2;          M = TS_ * B_; ldw = H_; }
    const int m0 = blockIdx.x * 64;
    if (m0 >= M) return;
    const int n0 = blockIdx.y * 128;
    const int tid = threadIdx.x;
    const int tym = tid >> 5;
    const int txn = tid & 31;
    const int sr = tid & 63, sh = tid >> 6;
    const int wr = tid & 127, wh = tid >> 7;

    float acc[8][4];
#pragma unroll
    for (int i = 0; i < 8; ++i)
#pragma unroll
        for (int j = 0; j < 4; ++j) acc[i][j] = 0.f;

    float4 a4[2], w4[4];
#pragma unroll
    for (int q = 0; q < 2; ++q)
        a4[q] = *reinterpret_cast<const float4*>(A + (size_t)(m0 + sr) * H_ + 8 * sh + 4 * q);
#pragma unroll
    for (int q = 0; q < 4; ++q)
        w4[q] = *reinterpret_cast<const float4*>(W + (size_t)(n0 + wr) * ldw + 16 * wh + 4 * q);

    for (int kb = 0; kb < H_; kb += 32) {
        __syncthreads();
#pragma unroll
        for (int q = 0; q < 2; ++q) {
            As[8 * sh + 4 * q + 0][sr] = a4[q].x; As[8 * sh + 4 * q + 1][sr] = a4[q].y;
            As[8 * sh + 4 * q + 2][sr] = a4[q].z; As[8 * sh + 4 * q + 3][sr] = a4[q].w;
        }
#pragma unroll
        for (int q = 0; q < 4; ++q) {
            Ws[16 * wh + 4 * q + 0][wr] = w4[q].x; Ws[16 * wh + 4 * q + 1][wr] = w4[q].y;
            Ws[16 * wh + 4 * q + 2][wr] = w4[q].z; Ws[16 * wh + 4 * q + 3][wr] = w4[q].w;
        }
        __syncthreads();
        if (kb + 32 < H_) {
#pragma unroll
            for (int q = 0; q < 2; ++q)
                a4[q] = *reinterpret_cast<const float4*>(A + (size_t)(m0 + sr) * H_ + kb + 32 + 8 * sh + 4 * q);
#pragma unroll
            for (int q = 0; q < 4; ++q)
                w4[q] = *reinterpret_cast<const float4*>(W + (size_t)(n0 + wr) * ldw + kb + 32 + 16 * wh + 4 * q);
        }
#pragma unroll 8
        for (int k = 0; k < 32; ++k) {
            const float4 a0 = *reinterpret_cast<const float4*>(&As[k][8 * tym]);
            const float4 a1 = *reinterpret_cast<const float4*>(&As[k][8 * tym + 4]);
            const float av[8] = {a0.x, a0.y, a0.z, a0.w, a1.x, a1.y, a1.z, a1.w};
            const float4 wf = *reinterpret_cast<const float4*>(&Ws[k][4 * txn]);
            const float wvv[4] = {wf.x, wf.y, wf.z, wf.w};
#pragma unroll
            for (int i = 0; i < 8; ++i)
#pragma unroll
                for (int j = 0; j < 4; ++j)
                    acc[i][j] = fmaf(av[i], wvv[j], acc[i][j]);
        }
    }

    const int colb = n0 + 4 * txn;
    if (z < 2) {
        const float* bvec = z ? b_attn_p : b_attn_a;
        const float* vvec = z ? v_p : v_a;
        float* scores = z ? scP : scA;
        const float* pp = parts + (size_t)(z * 4) * B_ * H_;
        const float4 b4 = *reinterpret_cast<const float4*>(bvec + colb);
        const float4 v4 = *reinterpret_cast<const float4*>(vvec + colb);
#pragma unroll
        for (int i = 0; i < 8; ++i) {
            const int row = m0 + 8 * tym + i;
            const int b = row & 31;
            float4 ha = b4;
#pragma unroll
            for (int ss = 0; ss < 4; ++ss) {
                const float4 p4 = *reinterpret_cast<const float4*>(&pp[((size_t)ss * B_ + b) * H_ + colb]);
                ha.x += p4.x; ha.y += p4.y; ha.z += p4.z; ha.w += p4.w;
            }
            float ps = tanhf(acc[i][0] + ha.x) * v4.x
                     + tanhf(acc[i][1] + ha.y) * v4.y
                     + tanhf(acc[i][2] + ha.z) * v4.z
                     + tanhf(acc[i][3] + ha.w) * v4.w;
#pragma unroll
            for (int off = 16; off > 0; off >>= 1)
                ps += __shfl_down(ps, off, 32);
            if (txn == 0) atomicAdd(&scores[row], ps);
        }
    } else {
        const float4 b4 = *reinterpret_cast<const float4*>(b_c2 + colb);
#pragma unroll
        for (int i = 0; i < 8; ++i) {
            const int row = m0 + 8 * tym + i;
            float4 o;
            o.x = tanhf(acc[i][0] + b4.x);
            o.y = tanhf(acc[i][1] + b4.y);
            o.z = tanhf(acc[i][2] + b4.z);
            o.w = tanhf(acc[i][3] + b4.w);
            *reinterpret_cast<float4*>(UCt + (size_t)row * H_ + colb) = o;
        }
    }
}

// ---------------------------------------------------------------------------
// Attention from precomputed scores: softmax over T + ctx accumulation.
// ---------------------------------------------------------------------------
template <int T>
__device__ __forceinline__ void attn_body(const float* __restrict__ sc_g,
                                          const float* __restrict__ enc,
                                          float* __restrict__ ctx, int b)
{
    const int tid = threadIdx.x;
    __shared__ float aw[64];

    if (tid < 64) {
        const float x = (tid < T) ? sc_g[tid * B_ + b] : -3.4e38f;
        float mx = x;
#pragma unroll
        for (int off = 32; off > 0; off >>= 1) mx = fmaxf(mx, __shfl_xor(mx, off));
        const float ex = (tid < T) ? expf(x - mx) : 0.f;
        float sm = ex;
#pragma unroll
        for (int off = 32; off > 0; off >>= 1) sm += __shfl_xor(sm, off);
        aw[tid] = ex / sm;
    }
    __syncthreads();
    for (int k = tid; k < H_; k += 512) {
        float c = 0.f;
#pragma unroll 10
        for (int t = 0; t < T; ++t)
            c += aw[t] * enc[((size_t)t * B_ + b) * H_ + k];
        ctx[(size_t)b * H_ + k] = c;
    }
}

__global__ __launch_bounds__(512)
void attn_fused4(const float* __restrict__ scA, const float* __restrict__ scP,
                 const float* __restrict__ slot_enc, const float* __restrict__ pers_enc,
                 float* __restrict__ ctxa, float* __restrict__ ctxp)
{
    const int b = blockIdx.x;
    if (blockIdx.y == 0) attn_body<TS_>(scA, slot_enc, ctxa, b);
    else                 attn_body<TP_>(scP, pers_enc, ctxp, b);
}

// ---------------------------------------------------------------------------
// projh_uprep: proj hnew-slices (0..499) + u_prep/scatter (500..531).
// ---------------------------------------------------------------------------
__global__ __launch_bounds__(256)
void projh_uprep(const float* __restrict__ hnew, const float* __restrict__ W_proj,
                 float* __restrict__ partsP,
                 const float* __restrict__ UCt, const int* __restrict__ slot_np,
                 float* __restrict__ mS, float* __restrict__ extra)
{
    if (blockIdx.x < 500) {
        const int y = blockIdx.x / 125, n0 = (blockIdx.x % 125) * 256;
        m32v2_tile(hnew + y * 256, H_, W_proj, H3, 2048 + y * 256, 256, n0,
                   partsP + (size_t)(8 + y) * B_ * V_, V_);
        return;
    }
    const int b    = blockIdx.x - 500;
    const int tid  = threadIdx.x;
    const int wave = tid >> 6;
    const int lane = tid & 63;
    __shared__ float su[64];
    __shared__ float eu_s[64];

    const float* h = hnew + (size_t)b * H_;
    for (int t = wave; t < TS_; t += 4) {
        const float* r = UCt + ((size_t)t * B_ + b) * H_;
        float p = 0.f;
#pragma unroll
        for (int j = 0; j < H_ / 64; ++j)
            p += r[lane + 64 * j] * h[lane + 64 * j];
#pragma unroll
        for (int off = 32; off > 0; off >>= 1) p += __shfl_down(p, off);
        if (lane == 0) su[t] = p;
    }
    __syncthreads();
    if (tid < 64) {
        const float x = (tid < TS_) ? su[tid] : -3.4e38f;
        float mx = x;
#pragma unroll
        for (int off = 32; off > 0; off >>= 1) mx = fmaxf(mx, __shfl_xor(mx, off));
        const float ex = (tid < TS_) ? expf(x - mx) : 0.f;
        float sm = ex;
#pragma unroll
        for (int off = 32; off > 0; off >>= 1) sm += __shfl_xor(sm, off);
        eu_s[tid] = ex;
        if (tid == 0) { mS[b * 2] = mx; mS[b * 2 + 1] = sm; }
    }
    __syncthreads();
    if (tid < TS_) {
        const int sv = slot_np[tid * B_ + b];
        const float e = eu_s[tid];
        const bool copy = (sv == 2) || (sv >= V_);
        const bool add  = (sv != 0) && !copy;
        if (add)  atomicAdd(&extra[(size_t)b * VTS + sv], e);
        if (copy) atomicAdd(&extra[(size_t)b * VTS + V_ + tid], 5.0f * e);
    }
}

// ---------------------------------------------------------------------------
__device__ __forceinline__ float blk_reduce(float v, float* red, int tid, bool ismax)
{
    red[tid] = v; __syncthreads();
    for (int s = 128; s > 0; s >>= 1) {
        if (tid < s) red[tid] = ismax ? fmaxf(red[tid], red[tid + s]) : (red[tid] + red[tid + s]);
        __syncthreads();
    }
    const float r = red[0]; __syncthreads();
    return r;
}

__global__ __launch_bounds__(256)
void ph_max2g(const float* __restrict__ parts, const float* __restrict__ b_proj,
              const float* __restrict__ extra,
              float* __restrict__ gen,
              float* __restrict__ pgm, float* __restrict__ pzs,
              float* __restrict__ pem, float* __restrict__ pes)
{
    const int b = blockIdx.x, s = blockIdx.y, tid = threadIdx.x;
    __shared__ float red[256];
    const int g0 = s * GSL;

    float gv[16];
    float gm = -3.4e38f;
#pragma unroll
    for (int u = 0; u < 16; ++u) {
        const int loc = tid + 256 * u;
        float val = -3.4e38f;
        if (loc < GSL) {
            const int idx = g0 + loc;
            float ssum = 0.f;
#pragma unroll
            for (int ss = 0; ss < PSK; ++ss)
                ssum += parts[((size_t)ss * B_ + b) * V_ + idx];
            val = ssum + b_proj[idx];
            gen[(size_t)b * V_ + idx] = val;
            gm = fmaxf(gm, val);
        }
        gv[u] = val;
    }
    gm = blk_reduce(gm, red, tid, true);
    float zs = 0.f;
#pragma unroll
    for (int u = 0; u < 16; ++u)
        zs += expf(gv[u] - gm);
    zs = blk_reduce(zs, red, tid, false);

    const float* ex = extra + (size_t)b * VTS;
    const int e0 = s * SLE;
    const int e1 = (e0 + SLE < VTS) ? e0 + SLE : VTS;
    float em = 0.f, es = 0.f;
    for (int i = e0 + tid; i < e1; i += 256) { const float v = ex[i]; em = fmaxf(em, v); es += v; }
    em = blk_reduce(em, red, tid, true);
    es = blk_reduce(es, red, tid, false);
    if (tid == 0) {
        pgm[b * NS + s] = gm; pzs[b * NS + s] = zs;
        pem[b * NS + s] = em; pes[b * NS + s] = es;
    }
}

__global__ __launch_bounds__(256)
void ph_write2(const float* __restrict__ gen, const float* __restrict__ extra,
               const float* __restrict__ pgm, const float* __restrict__ pzs,
               const float* __restrict__ pem, const float* __restrict__ pes,
               const float* __restrict__ mS, float* __restrict__ proba)
{
    const int b = blockIdx.x, s = blockIdx.y, tid = threadIdx.x;
    const float mb   = mS[b * 2];
    const float Sb   = mS[b * 2 + 1];
    const float base = 1e-10f * Sb;

    float gm = -3.4e38f, em = 0.f;
#pragma unroll
    for (int k = 0; k < NS; ++k) {
        gm = fmaxf(gm, pgm[b * NS + k]);
        em = fmaxf(em, pem[b * NS + k]);
    }
    const float M = fmaxf(gm, mb + logf(base + em));
    float s1 = 0.f, s2 = 0.f;
#pragma unroll
    for (int k = 0; k < NS; ++k) {
        s1 += pzs[b * NS + k] * expf(pgm[b * NS + k] - M);
        s2 += pes[b * NS + k];
    }
    const float cs  = expf(mb - M);
    const float inv = 1.f / (s1 + cs * (base * VTS + s2));

    const float* g  = gen + (size_t)b * V_;
    const float* ex = extra + (size_t)b * VTS;
    float* o = proba + (size_t)b * VTS;
    const int e0 = s * SLE;
    const int e1 = (e0 + SLE < VTS) ? e0 + SLE : VTS;
    for (int i = e0 + tid; i < e1; i += 256) {
        const float cp = cs * (base + ex[i]) * inv;
        o[i] = (i < V_) ? (expf(g[i] - M) * inv + cp) : cp;
    }
}

// ---------------------------------------------------------------------------
extern "C" void kernel_launch(void* const* d_in, const int* in_sizes, int n_in,
                              void* d_out, int out_size, void* d_ws, size_t ws_size,
                              hipStream_t stream)
{
    const float* slot_enc = (const float*)d_in[0];
    const float* pers_enc = (const float*)d_in[1];
    const float* hid      = (const float*)d_in[2];
    const int*   mt       = (const int*)d_in[3];
    const int*   slot_np  = (const int*)d_in[4];
    // d_in[5] sparse_u_input: reconstructed from slot_np (205 MB skipped)
    const float* emb      = (const float*)d_in[6];
    const float* W_attn_a = (const float*)d_in[7];
    const float* b_attn_a = (const float*)d_in[8];
    const float* v_a      = (const float*)d_in[9];
    const float* W_attn_p = (const float*)d_in[10];
    const float* b_attn_p = (const float*)d_in[11];
    const float* v_p      = (const float*)d_in[12];
    const float* W_ih     = (const float*)d_in[13];
    const float* W_hh     = (const float*)d_in[14];
    const float* b_ih     = (const float*)d_in[15];
    const float* b_hh     = (const float*)d_in[16];
    const float* W_proj   = (const float*)d_in[17];
    const float* b_proj   = (const float*)d_in[18];
    const float* W_c2     = (const float*)d_in[19];
    const float* b_c2     = (const float*)d_in[20];
    float* out = (float*)d_out;

    float* w = (float*)d_ws;
    size_t off = 0;
    auto alloc = [&](size_t n) { float* p = w + off; off += n; return p; };
    float* UCt   = alloc((size_t)TS_ * B_ * H_);
    float* scAll = alloc((size_t)NSC);          // scA (1600) | scP (1024)
    float* ctxa  = alloc((size_t)B_ * H_);
    float* ctxp  = alloc((size_t)B_ * H_);
    float* gx    = alloc((size_t)B_ * E_);
    float* hnew  = alloc((size_t)B_ * H_);
    float* gen   = alloc((size_t)B_ * V_);
    float* mS    = alloc((size_t)2 * B_);
    float* extra = alloc((size_t)B_ * VTS);
    float* pgm   = alloc((size_t)B_ * NS);
    float* pzs   = alloc((size_t)B_ * NS);
    float* pem   = alloc((size_t)B_ * NS);
    float* pes   = alloc((size_t)B_ * NS);
    float* partsP  = alloc((size_t)PSK * B_ * V_);
    float* partsG  = alloc((size_t)14 * B_ * H3);
    float* partsHd = alloc((size_t)8 * B_ * H_);
    float* scA = scAll;
    float* scP = scAll + TS_ * B_;

    const int o2 = B_ * VTS;
    const int o3 = o2 + B_ * H_;

    // 1. zero extra+scores + gather emb + hidden projections
    zg_hid<<<NZB + 32, 256, 0, stream>>>(extra, scAll, emb, mt, gx, hid,
                                          W_attn_a, W_attn_p, partsHd);

    // 2. encoder projections; attn scores folded via atomics (SA/SP gone)
    gemm_tall84<<<dim3(25, 8, 3), 256, 0, stream>>>(
        slot_enc, pers_enc, W_attn_a, W_attn_p, W_c2,
        b_attn_a, b_attn_p, b_c2, v_a, v_p, partsHd, scA, scP, UCt);

    // 3. attention: softmax from precomputed scores + ctx
    attn_fused4<<<dim3(B_, 2), 512, 0, stream>>>(scA, scP, slot_enc, pers_enc, ctxa, ctxp);

    // 4. merged proj ctx-slices + GRU slices
    gemm_pcg<<<1168, 256, 0, stream>>>(ctxa, ctxp, hid, gx, W_proj, W_ih, W_hh, partsP, partsG);

    // 5. GRU reduce + elementwise
    reduce_gru<<<(B_ * H_ + 255) / 256, 256, 0, stream>>>(partsG, b_ih, b_hh, hid, hnew, out + o2, out + o3);

    // 6. proj hnew-slices + u_prep/scatter
    projh_uprep<<<532, 256, 0, stream>>>(hnew, W_proj, partsP, UCt, slot_np, mS, extra);

    // 7/8. joint softmax
    ph_max2g<<<dim3(B_, NS), 256, 0, stream>>>(partsP, b_proj, extra, gen, pgm, pzs, pem, pes);
    ph_write2<<<dim3(B_, NS), 256, 0, stream>>>(gen, extra, pgm, pzs, pem, pes, mS, out);
}

// Round 12
// 395.941 us; speedup vs baseline: 1.9343x; 1.0116x over previous
//
#include <hip/hip_runtime.h>
#include <math.h>

static constexpr int V_   = 32000;
static constexpr int E_   = 512;
static constexpr int H_   = 1024;
static constexpr int B_   = 32;
static constexpr int TS_  = 50;
static constexpr int TP_  = 32;
static constexpr int VTS  = V_ + TS_;     // 32050
static constexpr int H3   = 3 * H_;       // 3072
static constexpr int GIN_ = E_ + 2 * H_;  // 2560
static constexpr int NS   = 8;            // softmax slices
static constexpr int SLE  = (VTS + NS - 1) / NS;  // 4007
static constexpr int GSL  = V_ / NS;      // 4000
static constexpr int PSK  = 12;           // proj K-slices
static constexpr int NSC  = TS_ * B_ + TP_ * B_;  // 2624 score entries
static constexpr int NZB  = (B_ * VTS + 255) / 256;  // 4007 extra-zero blocks
static constexpr int NPCG = 1168 + NZB;   // pcg grid incl. zero-tail

// ---------------------------------------------------------------------------
// m32v2 tile core (R10): 32m x 256n, KC=32, 4 waves, reg double-buffer.
// A frag: 2x ds_read_b128 broadcast; W frag: 1x ds_read_b128 (2-way, free).
// ---------------------------------------------------------------------------
__device__ __forceinline__ void m32v2_tile(
    const float* __restrict__ A, int lda,
    const float* __restrict__ W, int ldw, int wko,
    int klen, int n0, float* __restrict__ po, int N)
{
    __shared__ float As[32][36];
    __shared__ float Ws[32][256];

    const int tid  = threadIdx.x;
    const int lane = tid & 63;
    const int wv   = tid >> 6;
    const int wq   = lane & 7;
    const int wg   = lane >> 3;
    const int am   = tid >> 3;
    const int aq   = tid & 7;

    float acc[8][4];
#pragma unroll
    for (int i = 0; i < 8; ++i)
#pragma unroll
        for (int j = 0; j < 4; ++j) acc[i][j] = 0.f;

    float4 a4 = *reinterpret_cast<const float4*>(A + (size_t)am * lda + 4 * aq);
    float4 w4[8];
#pragma unroll
    for (int i = 0; i < 8; ++i)
        w4[i] = *reinterpret_cast<const float4*>(
            W + (size_t)(n0 + wv * 64 + i * 8 + wg) * ldw + wko + 4 * wq);

    for (int kb = 0; kb < klen; kb += 32) {
        __syncthreads();
        As[4 * aq + 0][am] = a4.x; As[4 * aq + 1][am] = a4.y;
        As[4 * aq + 2][am] = a4.z; As[4 * aq + 3][am] = a4.w;
#pragma unroll
        for (int i = 0; i < 8; ++i) {
            const int col = wv * 64 + i * 8 + wg;
            Ws[4 * wq + 0][col] = w4[i].x; Ws[4 * wq + 1][col] = w4[i].y;
            Ws[4 * wq + 2][col] = w4[i].z; Ws[4 * wq + 3][col] = w4[i].w;
        }
        __syncthreads();
        if (kb + 32 < klen) {
            a4 = *reinterpret_cast<const float4*>(A + (size_t)am * lda + kb + 32 + 4 * aq);
#pragma unroll
            for (int i = 0; i < 8; ++i)
                w4[i] = *reinterpret_cast<const float4*>(
                    W + (size_t)(n0 + wv * 64 + i * 8 + wg) * ldw + wko + kb + 32 + 4 * wq);
        }
#pragma unroll 8
        for (int k = 0; k < 32; ++k) {
            const float4 a0 = *reinterpret_cast<const float4*>(&As[k][wv * 8]);
            const float4 a1 = *reinterpret_cast<const float4*>(&As[k][wv * 8 + 4]);
            const float av[8] = {a0.x, a0.y, a0.z, a0.w, a1.x, a1.y, a1.z, a1.w};
            const float4 wf = *reinterpret_cast<const float4*>(&Ws[k][4 * lane]);
            const float wvv[4] = {wf.x, wf.y, wf.z, wf.w};
#pragma unroll
            for (int i = 0; i < 8; ++i)
#pragma unroll
                for (int j = 0; j < 4; ++j)
                    acc[i][j] = fmaf(av[i], wvv[j], acc[i][j]);
        }
    }
#pragma unroll
    for (int i = 0; i < 8; ++i) {
        float4 o; o.x = acc[i][0]; o.y = acc[i][1]; o.z = acc[i][2]; o.w = acc[i][3];
        *reinterpret_cast<float4*>(po + (size_t)(wv * 8 + i) * N + n0 + 4 * lane) = o;
    }
}

// ---------------------------------------------------------------------------
// zg_hid (slim): zero scores + gather emb (blocks 0..63) + hidden projections
// (blocks 64..95). The 4 MB extra-zeroing moved into gemm_pcg's tail.
// ---------------------------------------------------------------------------
__global__ __launch_bounds__(256)
void zg_hid(float* __restrict__ scAll,
            const float* __restrict__ emb,
            const int* __restrict__ mt, float* __restrict__ gx,
            const float* __restrict__ hid,
            const float* __restrict__ Wa, const float* __restrict__ Wp,
            float* __restrict__ partsHd)
{
    const int bid = blockIdx.x;
    if (bid < 64) {
        const int i = bid * 256 + threadIdx.x;   // i < 16384 = B_*E_
        if (i < NSC) scAll[i] = 0.f;
        gx[i] = emb[(size_t)mt[i >> 9] * E_ + (i & 511)];
        return;
    }
    const int idx = bid - 64;               // 0..31
    const int z = idx >> 4, y = (idx >> 2) & 3, bx = idx & 3;
    m32v2_tile(hid + y * 256, H_, z ? Wp : Wa, 2 * H_, y * 256, 256, bx * 256,
               partsHd + (size_t)(z * 4 + y) * B_ * H_, H_);
}

// ---------------------------------------------------------------------------
// gemm_pcg: proj ctx-slices (1000) + GRU slices (168) + extra-zero tail
// (4007 trivial blocks that mop up tail-idle CUs; extra is consumed two
// dispatches later by u_prep).
// ---------------------------------------------------------------------------
__global__ __launch_bounds__(256)
void gemm_pcg(const float* __restrict__ ctxa, const float* __restrict__ ctxp,
              const float* __restrict__ hid, const float* __restrict__ gx,
              const float* __restrict__ W_proj,
              const float* __restrict__ W_ih, const float* __restrict__ W_hh,
              float* __restrict__ partsP, float* __restrict__ partsG,
              float* __restrict__ extra)
{
    const int bid = blockIdx.x;
    if (bid >= 1168) {
        const int i = (bid - 1168) * 256 + threadIdx.x;
        if (i < B_ * VTS) extra[i] = 0.f;
        return;
    }
    const float* A; int lda; const float* W; int ldw; int wko;
    float* po; int N; int n0;
    if (bid < 1000) {
        const int y = bid / 125; n0 = (bid % 125) * 256;
        const int slice = y >> 2, kq = y & 3;
        A = (slice ? ctxp : ctxa) + kq * 256; lda = H_;
        W = W_proj; ldw = H3; wko = slice * 1024 + kq * 256;
        po = partsP + (size_t)y * B_ * V_; N = V_;
    } else {
        const int idx = bid - 1000;
        const int y = idx / 12; n0 = (idx % 12) * 256;
        int klo;
        if (y < 2)       { klo = y * 256;        A = gx;   lda = E_; W = W_ih; ldw = GIN_; wko = klo; }
        else if (y < 6)  { klo = (y - 2) * 256;  A = ctxa; lda = H_; W = W_ih; ldw = GIN_; wko = 512 + klo; }
        else if (y < 10) { klo = (y - 6) * 256;  A = ctxp; lda = H_; W = W_ih; ldw = GIN_; wko = 1536 + klo; }
        else             { klo = (y - 10) * 256; A = hid;  lda = H_; W = W_hh; ldw = H_;   wko = klo; }
        A += klo;
        po = partsG + (size_t)y * B_ * H3; N = H3;
    }
    m32v2_tile(A, lda, W, ldw, wko, 256, n0, po, N);
}

__global__ void reduce_gru(const float* __restrict__ parts,
                           const float* __restrict__ b_ih, const float* __restrict__ b_hh,
                           const float* __restrict__ hid,
                           float* __restrict__ hnew,
                           float* __restrict__ o2, float* __restrict__ o3)
{
    const int i = blockIdx.x * 256 + threadIdx.x;
    if (i >= B_ * H_) return;
    const int b = i >> 10, j = i & 1023;
    float gi[3], gh[3];
#pragma unroll
    for (int c = 0; c < 3; ++c) {
        float s = b_ih[c * H_ + j];
        for (int y = 0; y < 10; ++y)
            s += parts[((size_t)y * B_ + b) * H3 + c * H_ + j];
        gi[c] = s;
        float t = b_hh[c * H_ + j];
        for (int y = 10; y < 14; ++y)
            t += parts[((size_t)y * B_ + b) * H3 + c * H_ + j];
        gh[c] = t;
    }
    const float r = 1.f / (1.f + expf(-(gi[0] + gh[0])));
    const float z = 1.f / (1.f + expf(-(gi[1] + gh[1])));
    const float n = tanhf(gi[2] + r * gh[2]);
    const float o = (1.f - z) * n + z * hid[i];
    hnew[i] = o; o2[i] = o; o3[i] = o;
}

// ---------------------------------------------------------------------------
// gemm_tall84 v3 (R11): score row-sums folded via shfl-tree + atomicAdd.
// ---------------------------------------------------------------------------
__global__ __launch_bounds__(256)
void gemm_tall84(const float* __restrict__ slot_enc, const float* __restrict__ pers_enc,
                 const float* __restrict__ W_attn_a, const float* __restrict__ W_attn_p,
                 const float* __restrict__ W_c2,
                 const float* __restrict__ b_attn_a, const float* __restrict__ b_attn_p,
                 const float* __restrict__ b_c2,
                 const float* __restrict__ v_a, const float* __restrict__ v_p,
                 const float* __restrict__ parts,
                 float* __restrict__ scA, float* __restrict__ scP,
                 float* __restrict__ UCt)
{
    __shared__ float As[32][68];
    __shared__ float Ws[32][128];
    const int z = blockIdx.z;
    const float* A; const float* W; int M, ldw;
    if (z == 0)      { A = slot_enc; W = W_attn_a + H_; M = TS_ * B_; ldw = 2 * H_; }
    else if (z == 1) { A = pers_enc; W = W_attn_p + H_; M = TP_ * B_; ldw = 2 * H_; }
    else             { A = slot_enc; W = W_c2;          M = TS_ * B_; ldw = H_; }
    const int m0 = blockIdx.x * 64;
    if (m0 >= M) return;
    const int n0 = blockIdx.y * 128;
    const int tid = threadIdx.x;
    const int tym = tid >> 5;
    const int txn = tid & 31;
    const int sr = tid & 63, sh = tid >> 6;
    const int wr = tid & 127, wh = tid >> 7;

    float acc[8][4];
#pragma unroll
    for (int i = 0; i < 8; ++i)
#pragma unroll
        for (int j = 0; j < 4; ++j) acc[i][j] = 0.f;

    float4 a4[2], w4[4];
#pragma unroll
    for (int q = 0; q < 2; ++q)
        a4[q] = *reinterpret_cast<const float4*>(A + (size_t)(m0 + sr) * H_ + 8 * sh + 4 * q);
#pragma unroll
    for (int q = 0; q < 4; ++q)
        w4[q] = *reinterpret_cast<const float4*>(W + (size_t)(n0 + wr) * ldw + 16 * wh + 4 * q);

    for (int kb = 0; kb < H_; kb += 32) {
        __syncthreads();
#pragma unroll
        for (int q = 0; q < 2; ++q) {
            As[8 * sh + 4 * q + 0][sr] = a4[q].x; As[8 * sh + 4 * q + 1][sr] = a4[q].y;
            As[8 * sh + 4 * q + 2][sr] = a4[q].z; As[8 * sh + 4 * q + 3][sr] = a4[q].w;
        }
#pragma unroll
        for (int q = 0; q < 4; ++q) {
            Ws[16 * wh + 4 * q + 0][wr] = w4[q].x; Ws[16 * wh + 4 * q + 1][wr] = w4[q].y;
            Ws[16 * wh + 4 * q + 2][wr] = w4[q].z; Ws[16 * wh + 4 * q + 3][wr] = w4[q].w;
        }
        __syncthreads();
        if (kb + 32 < H_) {
#pragma unroll
            for (int q = 0; q < 2; ++q)
                a4[q] = *reinterpret_cast<const float4*>(A + (size_t)(m0 + sr) * H_ + kb + 32 + 8 * sh + 4 * q);
#pragma unroll
            for (int q = 0; q < 4; ++q)
                w4[q] = *reinterpret_cast<const float4*>(W + (size_t)(n0 + wr) * ldw + kb + 32 + 16 * wh + 4 * q);
        }
#pragma unroll 8
        for (int k = 0; k < 32; ++k) {
            const float4 a0 = *reinterpret_cast<const float4*>(&As[k][8 * tym]);
            const float4 a1 = *reinterpret_cast<const float4*>(&As[k][8 * tym + 4]);
            const float av[8] = {a0.x, a0.y, a0.z, a0.w, a1.x, a1.y, a1.z, a1.w};
            const float4 wf = *reinterpret_cast<const float4*>(&Ws[k][4 * txn]);
            const float wvv[4] = {wf.x, wf.y, wf.z, wf.w};
#pragma unroll
            for (int i = 0; i < 8; ++i)
#pragma unroll
                for (int j = 0; j < 4; ++j)
                    acc[i][j] = fmaf(av[i], wvv[j], acc[i][j]);
        }
    }

    const int colb = n0 + 4 * txn;
    if (z < 2) {
        const float* bvec = z ? b_attn_p : b_attn_a;
        const float* vvec = z ? v_p : v_a;
        float* scores = z ? scP : scA;
        const float* pp = parts + (size_t)(z * 4) * B_ * H_;
        const float4 b4 = *reinterpret_cast<const float4*>(bvec + colb);
        const float4 v4 = *reinterpret_cast<const float4*>(vvec + colb);
#pragma unroll
        for (int i = 0; i < 8; ++i) {
            const int row = m0 + 8 * tym + i;
            const int b = row & 31;
            float4 ha = b4;
#pragma unroll
            for (int ss = 0; ss < 4; ++ss) {
                const float4 p4 = *reinterpret_cast<const float4*>(&pp[((size_t)ss * B_ + b) * H_ + colb]);
                ha.x += p4.x; ha.y += p4.y; ha.z += p4.z; ha.w += p4.w;
            }
            float ps = tanhf(acc[i][0] + ha.x) * v4.x
                     + tanhf(acc[i][1] + ha.y) * v4.y
                     + tanhf(acc[i][2] + ha.z) * v4.z
                     + tanhf(acc[i][3] + ha.w) * v4.w;
#pragma unroll
            for (int off = 16; off > 0; off >>= 1)
                ps += __shfl_down(ps, off, 32);
            if (txn == 0) atomicAdd(&scores[row], ps);
        }
    } else {
        const float4 b4 = *reinterpret_cast<const float4*>(b_c2 + colb);
#pragma unroll
        for (int i = 0; i < 8; ++i) {
            const int row = m0 + 8 * tym + i;
            float4 o;
            o.x = tanhf(acc[i][0] + b4.x);
            o.y = tanhf(acc[i][1] + b4.y);
            o.z = tanhf(acc[i][2] + b4.z);
            o.w = tanhf(acc[i][3] + b4.w);
            *reinterpret_cast<float4*>(UCt + (size_t)row * H_ + colb) = o;
        }
    }
}

// ---------------------------------------------------------------------------
// Attention: 4-way column split per (b, path) -> 256 blocks of 256 threads.
// Softmax recomputed per block (50 flops, free); ctx one col per thread.
// ---------------------------------------------------------------------------
template <int T>
__device__ __forceinline__ void attn_body(const float* __restrict__ sc_g,
                                          const float* __restrict__ enc,
                                          float* __restrict__ ctx, int b, int q)
{
    const int tid = threadIdx.x;
    __shared__ float aw[64];

    if (tid < 64) {
        const float x = (tid < T) ? sc_g[tid * B_ + b] : -3.4e38f;
        float mx = x;
#pragma unroll
        for (int off = 32; off > 0; off >>= 1) mx = fmaxf(mx, __shfl_xor(mx, off));
        const float ex = (tid < T) ? expf(x - mx) : 0.f;
        float sm = ex;
#pragma unroll
        for (int off = 32; off > 0; off >>= 1) sm += __shfl_xor(sm, off);
        aw[tid] = ex / sm;
    }
    __syncthreads();
    const int k = q * 256 + tid;
    float c = 0.f;
#pragma unroll 10
    for (int t = 0; t < T; ++t)
        c += aw[t] * enc[((size_t)t * B_ + b) * H_ + k];
    ctx[(size_t)b * H_ + k] = c;
}

__global__ __launch_bounds__(256)
void attn_fused5(const float* __restrict__ scA, const float* __restrict__ scP,
                 const float* __restrict__ slot_enc, const float* __restrict__ pers_enc,
                 float* __restrict__ ctxa, float* __restrict__ ctxp)
{
    const int b = blockIdx.x, y = blockIdx.y, q = y & 3;
    if (y < 4) attn_body<TS_>(scA, slot_enc, ctxa, b, q);
    else       attn_body<TP_>(scP, pers_enc, ctxp, b, q);
}

// ---------------------------------------------------------------------------
// projh_uprep: proj hnew-slices (0..499) + u_prep/scatter (500..531).
// ---------------------------------------------------------------------------
__global__ __launch_bounds__(256)
void projh_uprep(const float* __restrict__ hnew, const float* __restrict__ W_proj,
                 float* __restrict__ partsP,
                 const float* __restrict__ UCt, const int* __restrict__ slot_np,
                 float* __restrict__ mS, float* __restrict__ extra)
{
    if (blockIdx.x < 500) {
        const int y = blockIdx.x / 125, n0 = (blockIdx.x % 125) * 256;
        m32v2_tile(hnew + y * 256, H_, W_proj, H3, 2048 + y * 256, 256, n0,
                   partsP + (size_t)(8 + y) * B_ * V_, V_);
        return;
    }
    const int b    = blockIdx.x - 500;
    const int tid  = threadIdx.x;
    const int wave = tid >> 6;
    const int lane = tid & 63;
    __shared__ float su[64];
    __shared__ float eu_s[64];

    const float* h = hnew + (size_t)b * H_;
    for (int t = wave; t < TS_; t += 4) {
        const float* r = UCt + ((size_t)t * B_ + b) * H_;
        float p = 0.f;
#pragma unroll
        for (int j = 0; j < H_ / 64; ++j)
            p += r[lane + 64 * j] * h[lane + 64 * j];
#pragma unroll
        for (int off = 32; off > 0; off >>= 1) p += __shfl_down(p, off);
        if (lane == 0) su[t] = p;
    }
    __syncthreads();
    if (tid < 64) {
        const float x = (tid < TS_) ? su[tid] : -3.4e38f;
        float mx = x;
#pragma unroll
        for (int off = 32; off > 0; off >>= 1) mx = fmaxf(mx, __shfl_xor(mx, off));
        const float ex = (tid < TS_) ? expf(x - mx) : 0.f;
        float sm = ex;
#pragma unroll
        for (int off = 32; off > 0; off >>= 1) sm += __shfl_xor(sm, off);
        eu_s[tid] = ex;
        if (tid == 0) { mS[b * 2] = mx; mS[b * 2 + 1] = sm; }
    }
    __syncthreads();
    if (tid < TS_) {
        const int sv = slot_np[tid * B_ + b];
        const float e = eu_s[tid];
        const bool copy = (sv == 2) || (sv >= V_);
        const bool add  = (sv != 0) && !copy;
        if (add)  atomicAdd(&extra[(size_t)b * VTS + sv], e);
        if (copy) atomicAdd(&extra[(size_t)b * VTS + V_ + tid], 5.0f * e);
    }
}

// ---------------------------------------------------------------------------
__device__ __forceinline__ float blk_reduce(float v, float* red, int tid, bool ismax)
{
    red[tid] = v; __syncthreads();
    for (int s = 128; s > 0; s >>= 1) {
        if (tid < s) red[tid] = ismax ? fmaxf(red[tid], red[tid + s]) : (red[tid] + red[tid + s]);
        __syncthreads();
    }
    const float r = red[0]; __syncthreads();
    return r;
}

__global__ __launch_bounds__(256)
void ph_max2g(const float* __restrict__ parts, const float* __restrict__ b_proj,
              const float* __restrict__ extra,
              float* __restrict__ gen,
              float* __restrict__ pgm, float* __restrict__ pzs,
              float* __restrict__ pem, float* __restrict__ pes)
{
    const int b = blockIdx.x, s = blockIdx.y, tid = threadIdx.x;
    __shared__ float red[256];
    const int g0 = s * GSL;

    float gv[16];
    float gm = -3.4e38f;
#pragma unroll
    for (int u = 0; u < 16; ++u) {
        const int loc = tid + 256 * u;
        float val = -3.4e38f;
        if (loc < GSL) {
            const int idx = g0 + loc;
            float ssum = 0.f;
#pragma unroll
            for (int ss = 0; ss < PSK; ++ss)
                ssum += parts[((size_t)ss * B_ + b) * V_ + idx];
            val = ssum + b_proj[idx];
            gen[(size_t)b * V_ + idx] = val;
            gm = fmaxf(gm, val);
        }
        gv[u] = val;
    }
    gm = blk_reduce(gm, red, tid, true);
    float zs = 0.f;
#pragma unroll
    for (int u = 0; u < 16; ++u)
        zs += expf(gv[u] - gm);
    zs = blk_reduce(zs, red, tid, false);

    const float* ex = extra + (size_t)b * VTS;
    const int e0 = s * SLE;
    const int e1 = (e0 + SLE < VTS) ? e0 + SLE : VTS;
    float em = 0.f, es = 0.f;
    for (int i = e0 + tid; i < e1; i += 256) { const float v = ex[i]; em = fmaxf(em, v); es += v; }
    em = blk_reduce(em, red, tid, true);
    es = blk_reduce(es, red, tid, false);
    if (tid == 0) {
        pgm[b * NS + s] = gm; pzs[b * NS + s] = zs;
        pem[b * NS + s] = em; pes[b * NS + s] = es;
    }
}

__global__ __launch_bounds__(256)
void ph_write2(const float* __restrict__ gen, const float* __restrict__ extra,
               const float* __restrict__ pgm, const float* __restrict__ pzs,
               const float* __restrict__ pem, const float* __restrict__ pes,
               const float* __restrict__ mS, float* __restrict__ proba)
{
    const int b = blockIdx.x, s = blockIdx.y, tid = threadIdx.x;
    const float mb   = mS[b * 2];
    const float Sb   = mS[b * 2 + 1];
    const float base = 1e-10f * Sb;

    float gm = -3.4e38f, em = 0.f;
#pragma unroll
    for (int k = 0; k < NS; ++k) {
        gm = fmaxf(gm, pgm[b * NS + k]);
        em = fmaxf(em, pem[b * NS + k]);
    }
    const float M = fmaxf(gm, mb + logf(base + em));
    float s1 = 0.f, s2 = 0.f;
#pragma unroll
    for (int k = 0; k < NS; ++k) {
        s1 += pzs[b * NS + k] * expf(pgm[b * NS + k] - M);
        s2 += pes[b * NS + k];
    }
    const float cs  = expf(mb - M);
    const float inv = 1.f / (s1 + cs * (base * VTS + s2));

    const float* g  = gen + (size_t)b * V_;
    const float* ex = extra + (size_t)b * VTS;
    float* o = proba + (size_t)b * VTS;
    const int e0 = s * SLE;
    const int e1 = (e0 + SLE < VTS) ? e0 + SLE : VTS;
    for (int i = e0 + tid; i < e1; i += 256) {
        const float cp = cs * (base + ex[i]) * inv;
        o[i] = (i < V_) ? (expf(g[i] - M) * inv + cp) : cp;
    }
}

// ---------------------------------------------------------------------------
extern "C" void kernel_launch(void* const* d_in, const int* in_sizes, int n_in,
                              void* d_out, int out_size, void* d_ws, size_t ws_size,
                              hipStream_t stream)
{
    const float* slot_enc = (const float*)d_in[0];
    const float* pers_enc = (const float*)d_in[1];
    const float* hid      = (const float*)d_in[2];
    const int*   mt       = (const int*)d_in[3];
    const int*   slot_np  = (const int*)d_in[4];
    // d_in[5] sparse_u_input: reconstructed from slot_np (205 MB skipped)
    const float* emb      = (const float*)d_in[6];
    const float* W_attn_a = (const float*)d_in[7];
    const float* b_attn_a = (const float*)d_in[8];
    const float* v_a      = (const float*)d_in[9];
    const float* W_attn_p = (const float*)d_in[10];
    const float* b_attn_p = (const float*)d_in[11];
    const float* v_p      = (const float*)d_in[12];
    const float* W_ih     = (const float*)d_in[13];
    const float* W_hh     = (const float*)d_in[14];
    const float* b_ih     = (const float*)d_in[15];
    const float* b_hh     = (const float*)d_in[16];
    const float* W_proj   = (const float*)d_in[17];
    const float* b_proj   = (const float*)d_in[18];
    const float* W_c2     = (const float*)d_in[19];
    const float* b_c2     = (const float*)d_in[20];
    float* out = (float*)d_out;

    float* w = (float*)d_ws;
    size_t off = 0;
    auto alloc = [&](size_t n) { float* p = w + off; off += n; return p; };
    float* UCt   = alloc((size_t)TS_ * B_ * H_);
    float* scAll = alloc((size_t)NSC);          // scA (1600) | scP (1024)
    float* ctxa  = alloc((size_t)B_ * H_);
    float* ctxp  = alloc((size_t)B_ * H_);
    float* gx    = alloc((size_t)B_ * E_);
    float* hnew  = alloc((size_t)B_ * H_);
    float* gen   = alloc((size_t)B_ * V_);
    float* mS    = alloc((size_t)2 * B_);
    float* extra = alloc((size_t)B_ * VTS);
    float* pgm   = alloc((size_t)B_ * NS);
    float* pzs   = alloc((size_t)B_ * NS);
    float* pem   = alloc((size_t)B_ * NS);
    float* pes   = alloc((size_t)B_ * NS);
    float* partsP  = alloc((size_t)PSK * B_ * V_);
    float* partsG  = alloc((size_t)14 * B_ * H3);
    float* partsHd = alloc((size_t)8 * B_ * H_);
    float* scA = scAll;
    float* scP = scAll + TS_ * B_;

    const int o2 = B_ * VTS;
    const int o3 = o2 + B_ * H_;

    // 1. zero scores + gather emb + hidden projections (96 blocks)
    zg_hid<<<96, 256, 0, stream>>>(scAll, emb, mt, gx, hid,
                                   W_attn_a, W_attn_p, partsHd);

    // 2. encoder projections; attn scores folded via atomics
    gemm_tall84<<<dim3(25, 8, 3), 256, 0, stream>>>(
        slot_enc, pers_enc, W_attn_a, W_attn_p, W_c2,
        b_attn_a, b_attn_p, b_c2, v_a, v_p, partsHd, scA, scP, UCt);

    // 3. attention: softmax from scores + ctx (4-way col split)
    attn_fused5<<<dim3(B_, 8), 256, 0, stream>>>(scA, scP, slot_enc, pers_enc, ctxa, ctxp);

    // 4. merged proj ctx-slices + GRU slices + extra-zero tail
    gemm_pcg<<<NPCG, 256, 0, stream>>>(ctxa, ctxp, hid, gx, W_proj, W_ih, W_hh,
                                       partsP, partsG, extra);

    // 5. GRU reduce + elementwise
    reduce_gru<<<(B_ * H_ + 255) / 256, 256, 0, stream>>>(partsG, b_ih, b_hh, hid, hnew, out + o2, out + o3);

    // 6. proj hnew-slices + u_prep/scatter
    projh_uprep<<<532, 256, 0, stream>>>(hnew, W_proj, partsP, UCt, slot_np, mS, extra);

    // 7/8. joint softmax
    ph_max2g<<<dim3(B_, NS), 256, 0, stream>>>(partsP, b_proj, extra, gen, pgm, pzs, pem, pes);
    ph_write2<<<dim3(B_, NS), 256, 0, stream>>>(gen, extra, pgm, pzs, pem, pes, mS, out);
}